// Round 6
// baseline (246.152 us; speedup 1.0000x reference)
//
#include <hip/hip_runtime.h>
#include <cstddef>
#include <cstdint>

#define B_DIM 8
#define L_DIM 2048
#define H_DIM 512
#define N_DIM 64
#define HN (H_DIM * N_DIM)          // 32768
#define BLH (B_DIM * L_DIM * H_DIM) // 8388608
#define M_DIM (B_DIM * L_DIM)       // 16384

typedef unsigned short u16;
typedef short bf16x8 __attribute__((ext_vector_type(8)));
typedef float floatx4 __attribute__((ext_vector_type(4)));

__device__ __forceinline__ float sigmoidf_(float v) {
    return 1.0f / (1.0f + __expf(-v));
}

// jax.nn.gelu default: approximate=True (tanh form)
__device__ __forceinline__ float gelu_tanh_(float x) {
    float x3 = x * x * x;
    float z = 0.7978845608028654f * fmaf(0.044715f, x3, x);
    float e = __expf(-2.0f * fabsf(z));
    float th = (1.0f - e) / (1.0f + e);
    th = copysignf(th, z);
    return 0.5f * x * (1.0f + th);
}

__device__ __forceinline__ u16 f2b(float f) {
    unsigned u = __float_as_uint(f);
    unsigned r = (u + 0x7fffu + ((u >> 16) & 1u)) >> 16;
    return (u16)r;
}
__device__ __forceinline__ float b2f(u16 u) {
    return __uint_as_float(((unsigned)u) << 16);
}
__device__ __forceinline__ void unpack2(unsigned u, float& a, float& b) {
    a = __uint_as_float(u << 16);
    b = __uint_as_float(u & 0xffff0000u);
}
__device__ __forceinline__ unsigned pack2(float a, float b) {
    return (unsigned)f2b(a) | ((unsigned)f2b(b) << 16);
}

// complex helpers
__device__ __forceinline__ void csq(float& r, float& i) {
    float nr = r * r - i * i;
    i = 2.0f * r * i;
    r = nr;
}

// ---------------------------------------------------------------------------
// 0) SETUP (one launch, block-partitioned):
//    [0,8192)     xtrans: x (B,L,H) fp32 -> XT (B,H,L) bf16
//    [8192,9216)  weight casts: Wo->bf16, W1*g1->bf16 (LN1 fold), W2->bf16
//    [9216,9344)  SSM params P + Ktab(LDS) + Toeplitz fill
//    [9344,9472)  LN1-fold column sums: c1[f]=sum_n W1[f][n]g1[n], c2=..beta1
// ---------------------------------------------------------------------------
__global__ __launch_bounds__(256) void setup_kernel(
    const float* __restrict__ x, const float* __restrict__ W_out,
    const float* __restrict__ W1, const float* __restrict__ W2,
    const float* __restrict__ log_dt, const float* __restrict__ A_re,
    const float* __restrict__ A_im, const float* __restrict__ C_re,
    const float* __restrict__ C_im, const float* __restrict__ g1,
    const float* __restrict__ beta1,
    u16* __restrict__ XT, u16* __restrict__ Wobf, u16* __restrict__ W1gbf,
    u16* __restrict__ W2bf, float* __restrict__ P, u16* __restrict__ Toep_bf,
    float* __restrict__ c1, float* __restrict__ c2)
{
    __shared__ float tile[32][33];
    __shared__ float ktab_s[4][64];
    const int bid = blockIdx.x;
    const int t   = threadIdx.x;

    if (bid < 8192) {
        // ---- xtrans
        int b  = bid >> 10;
        int hy = (bid >> 6) & 15;
        int lx = bid & 63;
        int l0 = lx * 32, h0 = hy * 32;
        int tx = t & 31, ty = t >> 5;
        #pragma unroll
        for (int r = 0; r < 4; ++r)
            tile[ty + r * 8][tx] = x[((size_t)b * L_DIM + l0 + ty + r * 8) * H_DIM + h0 + tx];
        __syncthreads();
        #pragma unroll
        for (int r = 0; r < 4; ++r)
            XT[(((size_t)b * H_DIM + h0 + ty + r * 8) << 11) + l0 + tx] = f2b(tile[tx][ty + r * 8]);
    } else if (bid < 9216) {
        // ---- weight casts
        int off = bid - 8192;
        if (off < 512) {
            int i = off * 256 + t;
            float4 v = *(const float4*)(W_out + (size_t)i * 4);
            uint2 p; p.x = pack2(v.x, v.y); p.y = pack2(v.z, v.w);
            *(uint2*)(Wobf + (size_t)i * 4) = p;
        } else if (off < 768) {
            int i = (off - 512) * 256 + t;
            float4 v = *(const float4*)(W1 + (size_t)i * 4);
            int n = (i * 4) & 511;
            float4 g = *(const float4*)(g1 + n);
            uint2 p; p.x = pack2(v.x * g.x, v.y * g.y);
            p.y = pack2(v.z * g.z, v.w * g.w);
            *(uint2*)(W1gbf + (size_t)i * 4) = p;
        } else {
            int i = (off - 768) * 256 + t;
            float4 v = *(const float4*)(W2 + (size_t)i * 4);
            uint2 p; p.x = pack2(v.x, v.y); p.y = pack2(v.z, v.w);
            *(uint2*)(W2bf + (size_t)i * 4) = p;
        }
    } else if (bid < 9344) {
        // ---- SSM params + Ktab + Toeplitz
        const int wv = t >> 6, lane = t & 63;
        const int i = (bid - 9216) * 256 + t;
        const int h = i >> 6;
        float dt = expf(log_dt[h]);
        float Ar = A_re[i], Ai = A_im[i];
        float ar = dt * Ar, ai = dt * Ai;
        float e = expf(ar);
        float wr = e * cosf(ai);
        float wi = e * sinf(ai);
        float em1r = wr - 1.0f, em1i = wi;
        float inv = 1.0f / fmaf(Ar, Ar, Ai * Ai);
        float qr = fmaf(em1r, Ar, em1i * Ai) * inv;
        float qi = fmaf(em1i, Ar, -(em1r * Ai)) * inv;
        float Cr = C_re[i], Ci = C_im[i];
        float c2r = 2.0f * (Cr * qr - Ci * qi);
        float c2i = 2.0f * (Cr * qi + Ci * qr);
        P[i]          = wr;
        P[HN + i]     = wi;
        P[2 * HN + i] = c2r;
        P[3 * HN + i] = c2i;

        float pr = 1.0f, pi = 0.0f;
        for (int tau = 0; tau < 64; ++tau) {
            float term = c2r * pr - c2i * pi;
            #pragma unroll
            for (int m = 32; m > 0; m >>= 1) term += __shfl_xor(term, m, 64);
            if (lane == 0) ktab_s[wv][tau] = term;
            float nr = pr * wr - pi * wi, ni = pr * wi + pi * wr;
            pr = nr; pi = ni;
        }
        __syncthreads();

        const int h0 = (bid - 9216) * 4;
        #pragma unroll
        for (int r = 0; r < 8; ++r) {
            int c = t + r * 256;
            int hh = c >> 9, rem = c & 511;
            int tt = rem >> 3, j0 = (rem & 7) * 8;
            u16 vv[8];
            #pragma unroll
            for (int jj = 0; jj < 8; ++jj) {
                int j = j0 + jj;
                vv[jj] = (j <= tt) ? f2b(ktab_s[hh][tt - j]) : (u16)0;
            }
            *(uint4*)&Toep_bf[((size_t)(h0 + hh) << 12) + (tt << 6) + j0] = *(uint4*)vv;
        }
    } else {
        // ---- LN1-fold column sums over n for W1 row f
        int f = (bid - 9344) * 4 + (t >> 6);
        int lane = t & 63;
        int n = lane * 8;
        float4 w0 = *(const float4*)(W1 + (size_t)f * 512 + n);
        float4 w1v = *(const float4*)(W1 + (size_t)f * 512 + n + 4);
        float4 ga = *(const float4*)(g1 + n);
        float4 gb = *(const float4*)(g1 + n + 4);
        float4 b0 = *(const float4*)(beta1 + n);
        float4 b1 = *(const float4*)(beta1 + n + 4);
        float s1 = w0.x * ga.x + w0.y * ga.y + w0.z * ga.z + w0.w * ga.w
                 + w1v.x * gb.x + w1v.y * gb.y + w1v.z * gb.z + w1v.w * gb.w;
        float s2 = w0.x * b0.x + w0.y * b0.y + w0.z * b0.z + w0.w * b0.w
                 + w1v.x * b1.x + w1v.y * b1.y + w1v.z * b1.z + w1v.w * b1.w;
        #pragma unroll
        for (int m = 32; m > 0; m >>= 1) {
            s1 += __shfl_xor(s1, m, 64);
            s2 += __shfl_xor(s2, m, 64);
        }
        if (lane == 0) { c1[f] = s1; c2[f] = s2; }
    }
}

// ---------------------------------------------------------------------------
// 3) Chunked SSM via MFMA. One workgroup = (h, half of b). T=64, 32 chunks.
// ---------------------------------------------------------------------------
__global__ __launch_bounds__(256) void ssm_chunk_kernel(
    const u16* __restrict__ XT, const float* __restrict__ P,
    const u16* __restrict__ Toep_bf, const float* __restrict__ D_skip,
    u16* __restrict__ YT)
{
    __shared__ u16 U[128 * 72];      // [ncol][j], pad 72
    __shared__ u16 S[128 * 136];     // [ncol][2n], pad 136
    __shared__ u16 EVT[13312];       // union: E[128*72]=9216 | Toep[64*72]=4608 + V[64*136]=8704
    u16* E  = EVT;
    u16* Tp = EVT;
    u16* V  = EVT + 4608;

    const int h    = blockIdx.x;
    const int b0   = blockIdx.y * 4;
    const int t    = threadIdx.x;
    const int lane = t & 63;
    const int wv   = t >> 6;
    const int lm   = lane & 15, lq = lane >> 4;

    const int pidx = (h << 6) + lane;
    const float wr  = P[pidx],          wi  = P[HN + pidx];
    const float c2r = P[2 * HN + pidx], c2i = P[3 * HN + pidx];

    // stage U: 128 rows x 64 bf16, 16B chunks (coalesced), padded LDS rows
    #pragma unroll
    for (int r = 0; r < 4; ++r) {
        int idx = t + r * 256;
        int row = idx >> 3, ch = idx & 7;
        const u16* gp = XT + (((size_t)(b0 + (row >> 5)) * H_DIM + h) << 11)
                           + ((row & 31) << 6) + (ch << 3);
        *(uint4*)&U[row * 72 + ch * 8] = *(const uint4*)gp;
    }

    // base power w^(16*wv) for this wave
    float bwr, bwi;
    {
        float g16r = wr, g16i = wi;
        csq(g16r, g16i); csq(g16r, g16i); csq(g16r, g16i); csq(g16r, g16i); // w^16
        if (wv == 0)      { bwr = 1.0f; bwi = 0.0f; }
        else if (wv == 1) { bwr = g16r; bwi = g16i; }
        else if (wv == 2) { bwr = g16r; bwi = g16i; csq(bwr, bwi); }
        else {
            float g32r = g16r, g32i = g16i; csq(g32r, g32i);
            bwr = g32r * g16r - g32i * g16i;
            bwi = g32r * g16i + g32i * g16r;
        }
    }

    // fill E: E[2n][j]=Re(w^(63-j)), E[2n+1][j]=Im(w^(63-j))
    {
        float pr = bwr, pi = bwi;
        #pragma unroll
        for (int jk = 0; jk < 16; ++jk) {
            int k = (wv << 4) + jk;
            int j = 63 - k;
            E[(2 * lane) * 72 + j]     = f2b(pr);
            E[(2 * lane + 1) * 72 + j] = f2b(pi);
            float nr = pr * wr - pi * wi, ni = pr * wi + pi * wr;
            pr = nr; pi = ni;
        }
    }
    __syncthreads();

    // Phase A
    {
        const int wm = wv >> 1, wn = wv & 1;
        floatx4 acc[4][4] = {};
        #pragma unroll
        for (int ks = 0; ks < 2; ++ks) {
            bf16x8 af[4], bfv[4];
            #pragma unroll
            for (int i = 0; i < 4; ++i)
                af[i] = *(const bf16x8*)&E[(wm * 64 + i * 16 + lm) * 72 + ks * 32 + lq * 8];
            #pragma unroll
            for (int j = 0; j < 4; ++j)
                bfv[j] = *(const bf16x8*)&U[(wn * 64 + j * 16 + lm) * 72 + ks * 32 + lq * 8];
            #pragma unroll
            for (int i = 0; i < 4; ++i) {
                #pragma unroll
                for (int j = 0; j < 4; ++j)
                    acc[i][j] = __builtin_amdgcn_mfma_f32_16x16x32_bf16(af[i], bfv[j], acc[i][j], 0, 0, 0);
            }
        }
        #pragma unroll
        for (int i = 0; i < 4; ++i) {
            #pragma unroll
            for (int j = 0; j < 4; ++j) {
                int ncol = wn * 64 + j * 16 + lm;
                int m0   = wm * 64 + i * 16 + lq * 4;
                u16 pk[4];
                #pragma unroll
                for (int r = 0; r < 4; ++r) pk[r] = f2b(acc[i][j][r]);
                *(uint2*)&S[ncol * 136 + m0] = *(uint2*)pk;
            }
        }
    }
    __syncthreads();

    // fill V + stage Toep + chunk scan
    {
        float pr = bwr, pi = bwi;
        {
            float nr = pr * wr - pi * wi, ni = pr * wi + pi * wr;
            pr = nr; pi = ni;
        }
        #pragma unroll
        for (int jk = 1; jk <= 16; ++jk) {
            int tr = (wv << 4) + jk - 1;
            float qr = c2r * pr - c2i * pi;
            float qi = c2r * pi + c2i * pr;
            V[tr * 136 + 2 * lane]     = f2b(qr);
            V[tr * 136 + 2 * lane + 1] = f2b(-qi);
            float nr = pr * wr - pi * wi, ni = pr * wi + pi * wr;
            pr = nr; pi = ni;
        }
        #pragma unroll
        for (int r = 0; r < 2; ++r) {
            int idx = t + r * 256;
            int row = idx >> 3, ch = idx & 7;
            *(uint4*)&Tp[row * 72 + ch * 8] =
                *(const uint4*)&Toep_bf[((size_t)h << 12) + (row << 6) + (ch << 3)];
        }
        float wTr = wr, wTi = wi;
        csq(wTr, wTi); csq(wTr, wTi); csq(wTr, wTi);
        csq(wTr, wTi); csq(wTr, wTi); csq(wTr, wTi);   // w^64
        float Sr = 0.0f, Si = 0.0f;
        const int n2 = lane * 2;
        for (int c = 0; c < 32; ++c) {
            int base = (wv * 32 + c) * 136 + n2;
            unsigned lv = *(unsigned*)&S[base];
            float lr, li;
            unpack2(lv, lr, li);
            *(unsigned*)&S[base] = pack2(Sr, Si);
            float nSr = wTr * Sr - wTi * Si + lr;
            Si = wTr * Si + wTi * Sr + li;
            Sr = nSr;
        }
    }
    __syncthreads();

    // Phase C
    {
        const float Dh = D_skip[h];
        floatx4 acc[4][2] = {};
        #pragma unroll
        for (int ks = 0; ks < 6; ++ks) {
            bf16x8 af[4], bfv[2];
            if (ks < 2) {
                #pragma unroll
                for (int i = 0; i < 4; ++i)
                    af[i] = *(const bf16x8*)&Tp[(i * 16 + lm) * 72 + ks * 32 + lq * 8];
                #pragma unroll
                for (int j = 0; j < 2; ++j)
                    bfv[j] = *(const bf16x8*)&U[(wv * 32 + j * 16 + lm) * 72 + ks * 32 + lq * 8];
            } else {
                #pragma unroll
                for (int i = 0; i < 4; ++i)
                    af[i] = *(const bf16x8*)&V[(i * 16 + lm) * 136 + (ks - 2) * 32 + lq * 8];
                #pragma unroll
                for (int j = 0; j < 2; ++j)
                    bfv[j] = *(const bf16x8*)&S[(wv * 32 + j * 16 + lm) * 136 + (ks - 2) * 32 + lq * 8];
            }
            #pragma unroll
            for (int i = 0; i < 4; ++i) {
                #pragma unroll
                for (int j = 0; j < 2; ++j)
                    acc[i][j] = __builtin_amdgcn_mfma_f32_16x16x32_bf16(af[i], bfv[j], acc[i][j], 0, 0, 0);
            }
        }
        #pragma unroll
        for (int j = 0; j < 2; ++j) {
            int ncol = wv * 32 + j * 16 + lm;
            int bloc = ncol >> 5, c = ncol & 31;
            size_t gbase = (((size_t)(b0 + bloc) * H_DIM + h) << 11) + (c << 6);
            #pragma unroll
            for (int i = 0; i < 4; ++i) {
                int t0 = i * 16 + lq * 4;
                u16 upk[4];
                *(uint2*)upk = *(const uint2*)&U[ncol * 72 + t0];
                u16 opk[4];
                #pragma unroll
                for (int r = 0; r < 4; ++r) {
                    float uvv = b2f(upk[r]);
                    float yv = gelu_tanh_(fmaf(Dh, uvv, acc[i][j][r]));
                    opk[r] = f2b(yv);
                }
                *(uint2*)&YT[gbase + t0] = *(uint2*)opk;
            }
        }
    }
}

// ---------------------------------------------------------------------------
// stage a 128x32 bf16 tile into LDS via global_load_lds, 512 threads.
// LDS dest LINEAR; bank-swizzle via permuted GLOBAL source chunk
// (chunk' = chunk ^ ((row>>1)&3)); readers XOR the same way.
// ---------------------------------------------------------------------------
__device__ __forceinline__ void stage_tile_512(
    const u16* __restrict__ g, u16* lds, int row0, int k0)
{
    const int t = threadIdx.x;           // 0..511, one 16B chunk each
    const int row  = t >> 2;             // 0..127
    const int csrc = (t & 3) ^ ((t >> 3) & 3);
    const u16* gp = g + (size_t)(row0 + row) * 512 + k0 + csrc * 8;
    __builtin_amdgcn_global_load_lds(
        (const __attribute__((address_space(1))) unsigned int*)gp,
        (__attribute__((address_space(3))) unsigned int*)(lds + (size_t)t * 8),
        16, 0, 0);
}

// A-tile from YT (B,H,L): thread reads 8 consecutive l for one h(=k), then
// transposes into As[l][k] via 8 offset-immediate ds_write_b16.
// Swizzle on chunk: c_store = kc ^ ((row>>3)&3)  (row>>3 == lc here).
__device__ __forceinline__ uint4 ldA_yt(
    const u16* __restrict__ YT, int b, int l0, int k0)
{
    const int k  = threadIdx.x >> 4;
    const int lc = threadIdx.x & 15;
    return *(const uint4*)(YT + (((size_t)(b * 512 + k0 + k)) << 11) + l0 + lc * 8);
}
__device__ __forceinline__ void dswA(u16* lds, uint4 av)
{
    const int k  = threadIdx.x >> 4;
    const int lc = threadIdx.x & 15;
    u16* p = lds + (lc * 8) * 32 + (((k >> 3) ^ (lc & 3)) << 3) + (k & 7);
    const u16* s = (const u16*)&av;
    #pragma unroll
    for (int j = 0; j < 8; ++j) p[j * 32] = s[j];
}

// ---------------------------------------------------------------------------
// 5) GEMM1 + GLU + residual (dual-B) reading A DIRECTLY from YT (ytrans
//    eliminated), plus LN1 row-stats (sum, sumsq) side-output per n0-block.
//    512 threads (8 waves, 2m x 4n), double-buffered 2-phase pipeline.
// ---------------------------------------------------------------------------
__global__ __launch_bounds__(512) void gemm1_glu_kernel(
    const u16* __restrict__ YT, const u16* __restrict__ Wo,
    const float* __restrict__ bo, const float* __restrict__ x,
    u16* __restrict__ out, float2* __restrict__ Pstats)
{
    __shared__ u16 As[2][128 * 32];
    __shared__ u16 Ba[2][128 * 32];
    __shared__ u16 Bg[2][128 * 32];
    __shared__ float2 red1[128][4];
    const int t    = threadIdx.x;
    const int lane = t & 63;
    const int wv   = t >> 6;             // 0..7
    const int wm   = wv >> 2, wn = wv & 3;
    const int lm   = lane & 15, lq = lane >> 4;
    const int sw   = (lq ^ ((lm >> 1) & 3)) * 8;   // B-side read swizzle
    const int m0   = blockIdx.x * 128, n0 = blockIdx.y * 128;
    const int b    = m0 >> 11;
    const int l0   = m0 & 2047;
    floatx4 accA[4][2] = {};
    floatx4 accG[4][2] = {};

    // A-side read swizzle per i (row>>3 bits reduce to lane bits)
    int swA[4];
    #pragma unroll
    for (int i = 0; i < 4; ++i)
        swA[i] = (lq ^ ((i * 2 + (lm >> 3)) & 3)) * 8;

    // prologue: tile 0
    uint4 av = ldA_yt(YT, b, l0, 0);
    stage_tile_512(Wo, Ba[0], n0, 0);
    stage_tile_512(Wo, Bg[0], 512 + n0, 0);
    dswA(As[0], av);
    __syncthreads();

    int cur = 0;
    for (int k0 = 32; k0 < 512; k0 += 32) {
        const int nx = cur ^ 1;
        uint4 avn = ldA_yt(YT, b, l0, k0);            // issue early (T14)
        stage_tile_512(Wo, Ba[nx], n0, k0);
        stage_tile_512(Wo, Bg[nx], 512 + n0, k0);

        bf16x8 af[4], ba[2], bg[2];
        #pragma unroll
        for (int i = 0; i < 4; ++i)
            af[i] = *(const bf16x8*)&As[cur][(wm * 64 + i * 16 + lm) * 32 + swA[i]];
        #pragma unroll
        for (int j = 0; j < 2; ++j) {
            ba[j] = *(const bf16x8*)&Ba[cur][(wn * 32 + j * 16 + lm) * 32 + sw];
            bg[j] = *(const bf16x8*)&Bg[cur][(wn * 32 + j * 16 + lm) * 32 + sw];
        }
        #pragma unroll
        for (int i = 0; i < 4; ++i) {
            #pragma unroll
            for (int j = 0; j < 2; ++j) {
                accA[i][j] = __builtin_amdgcn_mfma_f32_16x16x32_bf16(af[i], ba[j], accA[i][j], 0, 0, 0);
                accG[i][j] = __builtin_amdgcn_mfma_f32_16x16x32_bf16(af[i], bg[j], accG[i][j], 0, 0, 0);
            }
        }
        dswA(As[nx], avn);                            // write late, under MFMA-covered latency
        __syncthreads();
        cur = nx;
    }
    // final K-tile (no prefetch)
    {
        bf16x8 af[4], ba[2], bg[2];
        #pragma unroll
        for (int i = 0; i < 4; ++i)
            af[i] = *(const bf16x8*)&As[cur][(wm * 64 + i * 16 + lm) * 32 + swA[i]];
        #pragma unroll
        for (int j = 0; j < 2; ++j) {
            ba[j] = *(const bf16x8*)&Ba[cur][(wn * 32 + j * 16 + lm) * 32 + sw];
            bg[j] = *(const bf16x8*)&Bg[cur][(wn * 32 + j * 16 + lm) * 32 + sw];
        }
        #pragma unroll
        for (int i = 0; i < 4; ++i) {
            #pragma unroll
            for (int j = 0; j < 2; ++j) {
                accA[i][j] = __builtin_amdgcn_mfma_f32_16x16x32_bf16(af[i], ba[j], accA[i][j], 0, 0, 0);
                accG[i][j] = __builtin_amdgcn_mfma_f32_16x16x32_bf16(af[i], bg[j], accG[i][j], 0, 0, 0);
            }
        }
    }

    // epilogue: GLU + residual, accumulate LN1 row partials
    float bav[2], bgv[2];
    #pragma unroll
    for (int j = 0; j < 2; ++j) {
        int n = n0 + wn * 32 + j * 16 + lm;
        bav[j] = bo[n]; bgv[j] = bo[512 + n];
    }
    #pragma unroll
    for (int i = 0; i < 4; ++i) {
        #pragma unroll
        for (int r = 0; r < 4; ++r) {
            int row = wm * 64 + i * 16 + lq * 4 + r;
            int m = m0 + row;
            float s = 0.0f, sq = 0.0f;
            #pragma unroll
            for (int j = 0; j < 2; ++j) {
                int n = n0 + wn * 32 + j * 16 + lm;
                float a_ = accA[i][j][r] + bav[j];
                float g_ = accG[i][j][r] + bgv[j];
                float xv = x[(size_t)m * 512 + n];
                float ov = fmaf(a_, sigmoidf_(g_), xv);
                out[(size_t)m * 512 + n] = f2b(ov);
                s += ov; sq = fmaf(ov, ov, sq);
            }
            #pragma unroll
            for (int msk = 1; msk < 16; msk <<= 1) {
                s  += __shfl_xor(s, msk, 64);
                sq += __shfl_xor(sq, msk, 64);
            }
            if (lm == 0) { float2 p; p.x = s; p.y = sq; red1[row][wn] = p; }
        }
    }
    __syncthreads();
    if (t < 128) {
        float s = 0.0f, sq = 0.0f;
        #pragma unroll
        for (int w = 0; w < 4; ++w) { float2 p = red1[t][w]; s += p.x; sq += p.y; }
        float2 o; o.x = s; o.y = sq;
        Pstats[(size_t)(m0 + t) * 4 + blockIdx.y] = o;
    }
}

// ---------------------------------------------------------------------------
// 6) GEMM (W1*g1 folded) + LN1 epilogue + ReLU:
//    h1 = relu( rs_m*(W1g·z)[f] - rs_m*mu_m*c1[f] + c2[f] + bc1[f] )
//    Structure identical to proven gemm kernel; only epilogue differs.
// ---------------------------------------------------------------------------
__global__ __launch_bounds__(512) void gemm_relu_kernel(
    const u16* __restrict__ A, const u16* __restrict__ Bw,
    const float* __restrict__ bias, const float2* __restrict__ Pstats,
    const float* __restrict__ c1, const float* __restrict__ c2,
    u16* __restrict__ C)
{
    __shared__ u16 As[2][128 * 32];
    __shared__ u16 Bs[2][128 * 32];
    __shared__ float musig[128][2];
    const int t    = threadIdx.x;
    const int lane = t & 63;
    const int wv   = t >> 6;
    const int wm   = wv >> 2, wn = wv & 3;
    const int lm   = lane & 15, lq = lane >> 4;
    const int sw   = (lq ^ ((lm >> 1) & 3)) * 8;
    const int m0   = blockIdx.x * 128, n0 = blockIdx.y * 128;
    floatx4 acc[4][2] = {};

    if (t < 128) {
        float s = 0.0f, sq = 0.0f;
        #pragma unroll
        for (int w = 0; w < 4; ++w) {
            float2 p = Pstats[(size_t)(m0 + t) * 4 + w];
            s += p.x; sq += p.y;
        }
        float mu  = s * (1.0f / 512.0f);
        float var = sq * (1.0f / 512.0f) - mu * mu;
        musig[t][0] = mu;
        musig[t][1] = rsqrtf(var + 1e-5f);
    }
    stage_tile_512(A, As[0], m0, 0);
    stage_tile_512(Bw, Bs[0], n0, 0);
    __syncthreads();

    int cur = 0;
    for (int k0 = 32; k0 < 512; k0 += 32) {
        const int nx = cur ^ 1;
        stage_tile_512(A, As[nx], m0, k0);
        stage_tile_512(Bw, Bs[nx], n0, k0);

        bf16x8 af[4], bfr[2];
        #pragma unroll
        for (int i = 0; i < 4; ++i)
            af[i] = *(const bf16x8*)&As[cur][(wm * 64 + i * 16 + lm) * 32 + sw];
        #pragma unroll
        for (int j = 0; j < 2; ++j)
            bfr[j] = *(const bf16x8*)&Bs[cur][(wn * 32 + j * 16 + lm) * 32 + sw];
        #pragma unroll
        for (int i = 0; i < 4; ++i) {
            #pragma unroll
            for (int j = 0; j < 2; ++j)
                acc[i][j] = __builtin_amdgcn_mfma_f32_16x16x32_bf16(af[i], bfr[j], acc[i][j], 0, 0, 0);
        }
        __syncthreads();
        cur = nx;
    }
    {
        bf16x8 af[4], bfr[2];
        #pragma unroll
        for (int i = 0; i < 4; ++i)
            af[i] = *(const bf16x8*)&As[cur][(wm * 64 + i * 16 + lm) * 32 + sw];
        #pragma unroll
        for (int j = 0; j < 2; ++j)
            bfr[j] = *(const bf16x8*)&Bs[cur][(wn * 32 + j * 16 + lm) * 32 + sw];
        #pragma unroll
        for (int i = 0; i < 4; ++i) {
            #pragma unroll
            for (int j = 0; j < 2; ++j)
                acc[i][j] = __builtin_amdgcn_mfma_f32_16x16x32_bf16(af[i], bfr[j], acc[i][j], 0, 0, 0);
        }
    }
    float c1v[2], c2v[2];
    #pragma unroll
    for (int j = 0; j < 2; ++j) {
        int n = n0 + wn * 32 + j * 16 + lm;
        c1v[j] = c1[n];
        c2v[j] = c2[n] + bias[n];
    }
    #pragma unroll
    for (int i = 0; i < 4; ++i) {
        #pragma unroll
        for (int r = 0; r < 4; ++r) {
            int row = wm * 64 + i * 16 + lq * 4 + r;
            float mu = musig[row][0], rs = musig[row][1];
            float nmr = -rs * mu;
            #pragma unroll
            for (int j = 0; j < 2; ++j) {
                int n = n0 + wn * 32 + j * 16 + lm;
                float v = fmaf(rs, acc[i][j][r], fmaf(nmr, c1v[j], c2v[j]));
                C[(size_t)(m0 + row) * 512 + n] = f2b(fmaxf(v, 0.0f));
            }
        }
    }
}

// ---------------------------------------------------------------------------
// 7) FUSED GEMM2 + LN1'd residual + LayerNorm2 -> fp32 out.
//    M=64 x N=512 stripe, 1024 threads (16 waves, n-stripe 32 each).
//    Halves per-CU B-staging vs the M=32/512t version (same waves/CU).
//    LDS: A 2x4K + B 2x32K + 8K epi union = 80 KB.
// ---------------------------------------------------------------------------
__global__ __launch_bounds__(1024) void gemm2_ln_kernel(
    const u16* __restrict__ A, const u16* __restrict__ Bw,
    const float* __restrict__ bias, const u16* __restrict__ res,
    const float2* __restrict__ Pstats,
    const float* __restrict__ g1, const float* __restrict__ beta1,
    const float* __restrict__ gamma, const float* __restrict__ beta,
    float* __restrict__ out)
{
    __shared__ u16 As[2][64 * 32];       // 8 KB
    __shared__ u16 Bs[2][512 * 32];      // 64 KB
    __shared__ float epi[2048];          // 8 KB union: musig2[64][2] | lnred[64][16]f2
    float*  musig2 = epi;                // phase 1 (barrier-separated from lnred)
    float2* lnred  = (float2*)epi;       // phase 2
    const int t    = threadIdx.x;
    const int lane = t & 63;
    const int wv   = t >> 6;             // 0..15, n-stripe wv*32
    const int lm   = lane & 15, lq = lane >> 4;
    const int sw   = (lq ^ ((lm >> 1) & 3)) * 8;
    const int m0   = blockIdx.x * 64;
    floatx4 acc[4][2] = {};

    if (t < 64) {
        float s = 0.0f, sq = 0.0f;
        #pragma unroll
        for (int w = 0; w < 4; ++w) {
            float2 p = Pstats[(size_t)(m0 + t) * 4 + w];
            s += p.x; sq += p.y;
        }
        float mu  = s * (1.0f / 512.0f);
        float var = sq * (1.0f / 512.0f) - mu * mu;
        musig2[t * 2]     = mu;
        musig2[t * 2 + 1] = rsqrtf(var + 1e-5f);
    }
    // staging helpers (inline): B = 512x32 (2048 chunks / 1024 thr = 2 each),
    // A = 64x32 (256 chunks, t<256). Source-chunk swizzle as stage_tile_512.
    {
        #pragma unroll
        for (int r = 0; r < 2; ++r) {
            int c = t + r * 1024;
            int row = c >> 2;
            int csrc = (c & 3) ^ ((row >> 1) & 3);
            const u16* gp = Bw + (size_t)row * 512 + csrc * 8;
            __builtin_amdgcn_global_load_lds(
                (const __attribute__((address_space(1))) unsigned int*)gp,
                (__attribute__((address_space(3))) unsigned int*)(&Bs[0][0] + (size_t)c * 8),
                16, 0, 0);
        }
        if (t < 256) {
            int row = t >> 2;
            int csrc = (t & 3) ^ ((row >> 1) & 3);
            const u16* gp = A + (size_t)(m0 + row) * 512 + csrc * 8;
            __builtin_amdgcn_global_load_lds(
                (const __attribute__((address_space(1))) unsigned int*)gp,
                (__attribute__((address_space(3))) unsigned int*)(&As[0][0] + (size_t)t * 8),
                16, 0, 0);
        }
    }
    __syncthreads();

    int cur = 0;
    for (int k0 = 32; k0 < 512; k0 += 32) {
        const int nx = cur ^ 1;
        #pragma unroll
        for (int r = 0; r < 2; ++r) {
            int c = t + r * 1024;
            int row = c >> 2;
            int csrc = (c & 3) ^ ((row >> 1) & 3);
            const u16* gp = Bw + (size_t)row * 512 + k0 + csrc * 8;
            __builtin_amdgcn_global_load_lds(
                (const __attribute__((address_space(1))) unsigned int*)gp,
                (__attribute__((address_space(3))) unsigned int*)(&Bs[nx][0] + (size_t)c * 8),
                16, 0, 0);
        }
        if (t < 256) {
            int row = t >> 2;
            int csrc = (t & 3) ^ ((row >> 1) & 3);
            const u16* gp = A + (size_t)(m0 + row) * 512 + k0 + csrc * 8;
            __builtin_amdgcn_global_load_lds(
                (const __attribute__((address_space(1))) unsigned int*)gp,
                (__attribute__((address_space(3))) unsigned int*)(&As[nx][0] + (size_t)t * 8),
                16, 0, 0);
        }

        bf16x8 af[4], bfr[2];
        #pragma unroll
        for (int i = 0; i < 4; ++i)
            af[i] = *(const bf16x8*)&As[cur][(i * 16 + lm) * 32 + sw];
        #pragma unroll
        for (int j = 0; j < 2; ++j)
            bfr[j] = *(const bf16x8*)&Bs[cur][(wv * 32 + j * 16 + lm) * 32 + sw];
        #pragma unroll
        for (int i = 0; i < 4; ++i) {
            #pragma unroll
            for (int j = 0; j < 2; ++j)
                acc[i][j] = __builtin_amdgcn_mfma_f32_16x16x32_bf16(af[i], bfr[j], acc[i][j], 0, 0, 0);
        }
        __syncthreads();
        cur = nx;
    }
    // final K-tile
    {
        bf16x8 af[4], bfr[2];
        #pragma unroll
        for (int i = 0; i < 4; ++i)
            af[i] = *(const bf16x8*)&As[cur][(i * 16 + lm) * 32 + sw];
        #pragma unroll
        for (int j = 0; j < 2; ++j)
            bfr[j] = *(const bf16x8*)&Bs[cur][(wv * 32 + j * 16 + lm) * 32 + sw];
        #pragma unroll
        for (int i = 0; i < 4; ++i) {
            #pragma unroll
            for (int j = 0; j < 2; ++j)
                acc[i][j] = __builtin_amdgcn_mfma_f32_16x16x32_bf16(af[i], bfr[j], acc[i][j], 0, 0, 0);
        }
    }

    // epilogue phase 1: z = acc + bias + LN1(res)  (reads musig2)
    float bv[2], gv1[2], bt1[2], gv[2], btv[2];
    #pragma unroll
    for (int j = 0; j < 2; ++j) {
        int n = wv * 32 + j * 16 + lm;
        bv[j]  = bias[n];
        gv1[j] = g1[n];
        bt1[j] = beta1[n];
        gv[j]  = gamma[n];
        btv[j] = beta[n];
    }
    #pragma unroll
    for (int i = 0; i < 4; ++i) {
        #pragma unroll
        for (int r = 0; r < 4; ++r) {
            int row = i * 16 + lq * 4 + r;
            float mu1 = musig2[row * 2], rs1 = musig2[row * 2 + 1];
            int m = m0 + row;
            #pragma unroll
            for (int j = 0; j < 2; ++j) {
                int n = wv * 32 + j * 16 + lm;
                float zl = fmaf((b2f(res[(size_t)m * 512 + n]) - mu1) * rs1, gv1[j], bt1[j]);
                acc[i][j][r] += bv[j] + zl;
            }
        }
    }
    __syncthreads();   // musig2 dead; lnred may now reuse the union

    // epilogue phase 2: rowwise LN2 partials over this wave's 32-n slice
    #pragma unroll
    for (int i = 0; i < 4; ++i) {
        #pragma unroll
        for (int r = 0; r < 4; ++r) {
            float s  = acc[i][0][r] + acc[i][1][r];
            float sq = acc[i][0][r] * acc[i][0][r] + acc[i][1][r] * acc[i][1][r];
            #pragma unroll
            for (int msk = 1; msk < 16; msk <<= 1) {
                s  += __shfl_xor(s, msk, 64);
                sq += __shfl_xor(sq, msk, 64);
            }
            if (lm == 0) {
                float2 p; p.x = s; p.y = sq;
                lnred[(i * 16 + lq * 4 + r) * 16 + wv] = p;
            }
        }
    }
    __syncthreads();
    #pragma unroll
    for (int i = 0; i < 4; ++i) {
        #pragma unroll
        for (int r = 0; r < 4; ++r) {
            int row = i * 16 + lq * 4 + r;
            float s = 0.0f, sq = 0.0f;
            #pragma unroll
            for (int w = 0; w < 16; ++w) {
                float2 p = lnred[row * 16 + w];
                s += p.x; sq += p.y;
            }
            float mu  = s * (1.0f / 512.0f);
            float var = sq * (1.0f / 512.0f) - mu * mu;
            float rs  = rsqrtf(var + 1e-5f);
            #pragma unroll
            for (int j = 0; j < 2; ++j) {
                int n = wv * 32 + j * 16 + lm;
                out[(size_t)(m0 + row) * 512 + n] = fmaf((acc[i][j][r] - mu) * rs, gv[j], btv[j]);
            }
        }
    }
}

// ---------------------------------------------------------------------------
extern "C" void kernel_launch(void* const* d_in, const int* in_sizes, int n_in,
                              void* d_out, int out_size, void* d_ws, size_t ws_size,
                              hipStream_t stream)
{
    (void)in_sizes; (void)n_in; (void)out_size; (void)ws_size;
    const float* x      = (const float*)d_in[0];
    const float* log_dt = (const float*)d_in[1];
    const float* A_re   = (const float*)d_in[2];
    const float* A_im   = (const float*)d_in[3];
    const float* C_re   = (const float*)d_in[4];
    const float* C_im   = (const float*)d_in[5];
    const float* D_skip = (const float*)d_in[6];
    const float* W_out  = (const float*)d_in[7];
    const float* b_out  = (const float*)d_in[8];
    const float* g1     = (const float*)d_in[9];
    const float* beta1  = (const float*)d_in[10];
    const float* g2     = (const float*)d_in[11];
    const float* beta2  = (const float*)d_in[12];
    const float* W1     = (const float*)d_in[13];
    const float* bc1    = (const float*)d_in[14];
    const float* W2     = (const float*)d_in[15];
    const float* bc2    = (const float*)d_in[16];
    float* out = (float*)d_out;

    // workspace: P 512K | hole | Toep 4M | weights 2M | r1/r2/r3 | Pstats | c1 c2
    char*   wsb    = (char*)d_ws;
    float*  P      = (float*)wsb;
    u16*    Toep   = (u16*)(wsb + 4 * HN * 4 + 512 * 64 * 4);
    u16*    Wobf   = Toep + 512 * 4096;
    u16*    W1bf   = Wobf + 1024 * 512;
    u16*    W2bf   = W1bf + 512 * 512;
    u16*    r1     = W2bf + 512 * 512;   // XT -> h1_bf
    u16*    r2     = r1 + BLH;           // YT
    u16*    r3     = r2 + BLH;           // x1pre_bf
    float2* Pstats = (float2*)(r3 + BLH);
    float*  c1     = (float*)(Pstats + (size_t)M_DIM * 4);
    float*  c2     = c1 + 512;

    setup_kernel<<<9472, 256, 0, stream>>>(x, W_out, W1, W2, log_dt, A_re, A_im,
                                           C_re, C_im, g1, beta1,
                                           r1, Wobf, W1bf, W2bf, P, Toep, c1, c2);
    ssm_chunk_kernel<<<dim3(H_DIM, 2), 256, 0, stream>>>(r1, P, Toep, D_skip, r2);
    gemm1_glu_kernel<<<dim3(M_DIM / 128, 4), 512, 0, stream>>>(r2, Wobf, b_out, x, r3, Pstats);
    gemm_relu_kernel<<<dim3(M_DIM / 128, 4), 512, 0, stream>>>(r3, W1bf, bc1, Pstats, c1, c2, r1);
    gemm2_ln_kernel<<<M_DIM / 64, 1024, 0, stream>>>(r1, W2bf, bc2, r3, Pstats, g1, beta1, g2, beta2, out);
}

// Round 7
// 236.743 us; speedup vs baseline: 1.0397x; 1.0397x over previous
//
#include <hip/hip_runtime.h>
#include <cstddef>
#include <cstdint>

#define B_DIM 8
#define L_DIM 2048
#define H_DIM 512
#define N_DIM 64
#define HN (H_DIM * N_DIM)          // 32768
#define BLH (B_DIM * L_DIM * H_DIM) // 8388608
#define M_DIM (B_DIM * L_DIM)       // 16384

typedef unsigned short u16;
typedef short bf16x8 __attribute__((ext_vector_type(8)));
typedef float floatx4 __attribute__((ext_vector_type(4)));

__device__ __forceinline__ float sigmoidf_(float v) {
    return 1.0f / (1.0f + __expf(-v));
}

// jax.nn.gelu default: approximate=True (tanh form)
__device__ __forceinline__ float gelu_tanh_(float x) {
    float x3 = x * x * x;
    float z = 0.7978845608028654f * fmaf(0.044715f, x3, x);
    float e = __expf(-2.0f * fabsf(z));
    float th = (1.0f - e) / (1.0f + e);
    th = copysignf(th, z);
    return 0.5f * x * (1.0f + th);
}

__device__ __forceinline__ u16 f2b(float f) {
    unsigned u = __float_as_uint(f);
    unsigned r = (u + 0x7fffu + ((u >> 16) & 1u)) >> 16;
    return (u16)r;
}
__device__ __forceinline__ float b2f(u16 u) {
    return __uint_as_float(((unsigned)u) << 16);
}
__device__ __forceinline__ void unpack2(unsigned u, float& a, float& b) {
    a = __uint_as_float(u << 16);
    b = __uint_as_float(u & 0xffff0000u);
}
__device__ __forceinline__ unsigned pack2(float a, float b) {
    return (unsigned)f2b(a) | ((unsigned)f2b(b) << 16);
}

// complex helpers
__device__ __forceinline__ void csq(float& r, float& i) {
    float nr = r * r - i * i;
    i = 2.0f * r * i;
    r = nr;
}

// ---------------------------------------------------------------------------
// 0) SETUP (one launch, block-partitioned):
//    [0,8192)     xtrans: x (B,L,H) fp32 -> XT (B,H,L) bf16
//    [8192,9216)  weight casts: Wo->bf16, W1*g1->bf16 (LN1 fold), W2->bf16
//    [9216,9344)  SSM params P + Ktab(LDS) + Toeplitz fill
//    [9344,9472)  LN1-fold column sums: c1[f]=sum_n W1[f][n]g1[n], c2=..beta1
// ---------------------------------------------------------------------------
__global__ __launch_bounds__(256) void setup_kernel(
    const float* __restrict__ x, const float* __restrict__ W_out,
    const float* __restrict__ W1, const float* __restrict__ W2,
    const float* __restrict__ log_dt, const float* __restrict__ A_re,
    const float* __restrict__ A_im, const float* __restrict__ C_re,
    const float* __restrict__ C_im, const float* __restrict__ g1,
    const float* __restrict__ beta1,
    u16* __restrict__ XT, u16* __restrict__ Wobf, u16* __restrict__ W1gbf,
    u16* __restrict__ W2bf, float* __restrict__ P, u16* __restrict__ Toep_bf,
    float* __restrict__ c1, float* __restrict__ c2)
{
    __shared__ float tile[32][33];
    __shared__ float ktab_s[4][64];
    const int bid = blockIdx.x;
    const int t   = threadIdx.x;

    if (bid < 8192) {
        // ---- xtrans
        int b  = bid >> 10;
        int hy = (bid >> 6) & 15;
        int lx = bid & 63;
        int l0 = lx * 32, h0 = hy * 32;
        int tx = t & 31, ty = t >> 5;
        #pragma unroll
        for (int r = 0; r < 4; ++r)
            tile[ty + r * 8][tx] = x[((size_t)b * L_DIM + l0 + ty + r * 8) * H_DIM + h0 + tx];
        __syncthreads();
        #pragma unroll
        for (int r = 0; r < 4; ++r)
            XT[(((size_t)b * H_DIM + h0 + ty + r * 8) << 11) + l0 + tx] = f2b(tile[tx][ty + r * 8]);
    } else if (bid < 9216) {
        // ---- weight casts
        int off = bid - 8192;
        if (off < 512) {
            int i = off * 256 + t;
            float4 v = *(const float4*)(W_out + (size_t)i * 4);
            uint2 p; p.x = pack2(v.x, v.y); p.y = pack2(v.z, v.w);
            *(uint2*)(Wobf + (size_t)i * 4) = p;
        } else if (off < 768) {
            int i = (off - 512) * 256 + t;
            float4 v = *(const float4*)(W1 + (size_t)i * 4);
            int n = (i * 4) & 511;
            float4 g = *(const float4*)(g1 + n);
            uint2 p; p.x = pack2(v.x * g.x, v.y * g.y);
            p.y = pack2(v.z * g.z, v.w * g.w);
            *(uint2*)(W1gbf + (size_t)i * 4) = p;
        } else {
            int i = (off - 768) * 256 + t;
            float4 v = *(const float4*)(W2 + (size_t)i * 4);
            uint2 p; p.x = pack2(v.x, v.y); p.y = pack2(v.z, v.w);
            *(uint2*)(W2bf + (size_t)i * 4) = p;
        }
    } else if (bid < 9344) {
        // ---- SSM params + Ktab + Toeplitz
        const int wv = t >> 6, lane = t & 63;
        const int i = (bid - 9216) * 256 + t;
        const int h = i >> 6;
        float dt = expf(log_dt[h]);
        float Ar = A_re[i], Ai = A_im[i];
        float ar = dt * Ar, ai = dt * Ai;
        float e = expf(ar);
        float wr = e * cosf(ai);
        float wi = e * sinf(ai);
        float em1r = wr - 1.0f, em1i = wi;
        float inv = 1.0f / fmaf(Ar, Ar, Ai * Ai);
        float qr = fmaf(em1r, Ar, em1i * Ai) * inv;
        float qi = fmaf(em1i, Ar, -(em1r * Ai)) * inv;
        float Cr = C_re[i], Ci = C_im[i];
        float c2r = 2.0f * (Cr * qr - Ci * qi);
        float c2i = 2.0f * (Cr * qi + Ci * qr);
        P[i]          = wr;
        P[HN + i]     = wi;
        P[2 * HN + i] = c2r;
        P[3 * HN + i] = c2i;

        float pr = 1.0f, pi = 0.0f;
        for (int tau = 0; tau < 64; ++tau) {
            float term = c2r * pr - c2i * pi;
            #pragma unroll
            for (int m = 32; m > 0; m >>= 1) term += __shfl_xor(term, m, 64);
            if (lane == 0) ktab_s[wv][tau] = term;
            float nr = pr * wr - pi * wi, ni = pr * wi + pi * wr;
            pr = nr; pi = ni;
        }
        __syncthreads();

        const int h0 = (bid - 9216) * 4;
        #pragma unroll
        for (int r = 0; r < 8; ++r) {
            int c = t + r * 256;
            int hh = c >> 9, rem = c & 511;
            int tt = rem >> 3, j0 = (rem & 7) * 8;
            u16 vv[8];
            #pragma unroll
            for (int jj = 0; jj < 8; ++jj) {
                int j = j0 + jj;
                vv[jj] = (j <= tt) ? f2b(ktab_s[hh][tt - j]) : (u16)0;
            }
            *(uint4*)&Toep_bf[((size_t)(h0 + hh) << 12) + (tt << 6) + j0] = *(uint4*)vv;
        }
    } else {
        // ---- LN1-fold column sums over n for W1 row f
        int f = (bid - 9344) * 4 + (t >> 6);
        int lane = t & 63;
        int n = lane * 8;
        float4 w0 = *(const float4*)(W1 + (size_t)f * 512 + n);
        float4 w1v = *(const float4*)(W1 + (size_t)f * 512 + n + 4);
        float4 ga = *(const float4*)(g1 + n);
        float4 gb = *(const float4*)(g1 + n + 4);
        float4 b0 = *(const float4*)(beta1 + n);
        float4 b1 = *(const float4*)(beta1 + n + 4);
        float s1 = w0.x * ga.x + w0.y * ga.y + w0.z * ga.z + w0.w * ga.w
                 + w1v.x * gb.x + w1v.y * gb.y + w1v.z * gb.z + w1v.w * gb.w;
        float s2 = w0.x * b0.x + w0.y * b0.y + w0.z * b0.z + w0.w * b0.w
                 + w1v.x * b1.x + w1v.y * b1.y + w1v.z * b1.z + w1v.w * b1.w;
        #pragma unroll
        for (int m = 32; m > 0; m >>= 1) {
            s1 += __shfl_xor(s1, m, 64);
            s2 += __shfl_xor(s2, m, 64);
        }
        if (lane == 0) { c1[f] = s1; c2[f] = s2; }
    }
}

// ---------------------------------------------------------------------------
// 3) Chunked SSM via MFMA. One workgroup = (h, half of b). T=64, 32 chunks.
// ---------------------------------------------------------------------------
__global__ __launch_bounds__(256) void ssm_chunk_kernel(
    const u16* __restrict__ XT, const float* __restrict__ P,
    const u16* __restrict__ Toep_bf, const float* __restrict__ D_skip,
    u16* __restrict__ YT)
{
    __shared__ u16 U[128 * 72];      // [ncol][j], pad 72
    __shared__ u16 S[128 * 136];     // [ncol][2n], pad 136
    __shared__ u16 EVT[13312];       // union: E[128*72]=9216 | Toep[64*72]=4608 + V[64*136]=8704
    u16* E  = EVT;
    u16* Tp = EVT;
    u16* V  = EVT + 4608;

    const int h    = blockIdx.x;
    const int b0   = blockIdx.y * 4;
    const int t    = threadIdx.x;
    const int lane = t & 63;
    const int wv   = t >> 6;
    const int lm   = lane & 15, lq = lane >> 4;

    const int pidx = (h << 6) + lane;
    const float wr  = P[pidx],          wi  = P[HN + pidx];
    const float c2r = P[2 * HN + pidx], c2i = P[3 * HN + pidx];

    // stage U: 128 rows x 64 bf16, 16B chunks (coalesced), padded LDS rows
    #pragma unroll
    for (int r = 0; r < 4; ++r) {
        int idx = t + r * 256;
        int row = idx >> 3, ch = idx & 7;
        const u16* gp = XT + (((size_t)(b0 + (row >> 5)) * H_DIM + h) << 11)
                           + ((row & 31) << 6) + (ch << 3);
        *(uint4*)&U[row * 72 + ch * 8] = *(const uint4*)gp;
    }

    // base power w^(16*wv) for this wave
    float bwr, bwi;
    {
        float g16r = wr, g16i = wi;
        csq(g16r, g16i); csq(g16r, g16i); csq(g16r, g16i); csq(g16r, g16i); // w^16
        if (wv == 0)      { bwr = 1.0f; bwi = 0.0f; }
        else if (wv == 1) { bwr = g16r; bwi = g16i; }
        else if (wv == 2) { bwr = g16r; bwi = g16i; csq(bwr, bwi); }
        else {
            float g32r = g16r, g32i = g16i; csq(g32r, g32i);
            bwr = g32r * g16r - g32i * g16i;
            bwi = g32r * g16i + g32i * g16r;
        }
    }

    // fill E: E[2n][j]=Re(w^(63-j)), E[2n+1][j]=Im(w^(63-j))
    {
        float pr = bwr, pi = bwi;
        #pragma unroll
        for (int jk = 0; jk < 16; ++jk) {
            int k = (wv << 4) + jk;
            int j = 63 - k;
            E[(2 * lane) * 72 + j]     = f2b(pr);
            E[(2 * lane + 1) * 72 + j] = f2b(pi);
            float nr = pr * wr - pi * wi, ni = pr * wi + pi * wr;
            pr = nr; pi = ni;
        }
    }
    __syncthreads();

    // Phase A
    {
        const int wm = wv >> 1, wn = wv & 1;
        floatx4 acc[4][4] = {};
        #pragma unroll
        for (int ks = 0; ks < 2; ++ks) {
            bf16x8 af[4], bfv[4];
            #pragma unroll
            for (int i = 0; i < 4; ++i)
                af[i] = *(const bf16x8*)&E[(wm * 64 + i * 16 + lm) * 72 + ks * 32 + lq * 8];
            #pragma unroll
            for (int j = 0; j < 4; ++j)
                bfv[j] = *(const bf16x8*)&U[(wn * 64 + j * 16 + lm) * 72 + ks * 32 + lq * 8];
            #pragma unroll
            for (int i = 0; i < 4; ++i) {
                #pragma unroll
                for (int j = 0; j < 4; ++j)
                    acc[i][j] = __builtin_amdgcn_mfma_f32_16x16x32_bf16(af[i], bfv[j], acc[i][j], 0, 0, 0);
            }
        }
        #pragma unroll
        for (int i = 0; i < 4; ++i) {
            #pragma unroll
            for (int j = 0; j < 4; ++j) {
                int ncol = wn * 64 + j * 16 + lm;
                int m0   = wm * 64 + i * 16 + lq * 4;
                u16 pk[4];
                #pragma unroll
                for (int r = 0; r < 4; ++r) pk[r] = f2b(acc[i][j][r]);
                *(uint2*)&S[ncol * 136 + m0] = *(uint2*)pk;
            }
        }
    }
    __syncthreads();

    // fill V + stage Toep + chunk scan
    {
        float pr = bwr, pi = bwi;
        {
            float nr = pr * wr - pi * wi, ni = pr * wi + pi * wr;
            pr = nr; pi = ni;
        }
        #pragma unroll
        for (int jk = 1; jk <= 16; ++jk) {
            int tr = (wv << 4) + jk - 1;
            float qr = c2r * pr - c2i * pi;
            float qi = c2r * pi + c2i * pr;
            V[tr * 136 + 2 * lane]     = f2b(qr);
            V[tr * 136 + 2 * lane + 1] = f2b(-qi);
            float nr = pr * wr - pi * wi, ni = pr * wi + pi * wr;
            pr = nr; pi = ni;
        }
        #pragma unroll
        for (int r = 0; r < 2; ++r) {
            int idx = t + r * 256;
            int row = idx >> 3, ch = idx & 7;
            *(uint4*)&Tp[row * 72 + ch * 8] =
                *(const uint4*)&Toep_bf[((size_t)h << 12) + (row << 6) + (ch << 3)];
        }
        float wTr = wr, wTi = wi;
        csq(wTr, wTi); csq(wTr, wTi); csq(wTr, wTi);
        csq(wTr, wTi); csq(wTr, wTi); csq(wTr, wTi);   // w^64
        float Sr = 0.0f, Si = 0.0f;
        const int n2 = lane * 2;
        for (int c = 0; c < 32; ++c) {
            int base = (wv * 32 + c) * 136 + n2;
            unsigned lv = *(unsigned*)&S[base];
            float lr, li;
            unpack2(lv, lr, li);
            *(unsigned*)&S[base] = pack2(Sr, Si);
            float nSr = wTr * Sr - wTi * Si + lr;
            Si = wTr * Si + wTi * Sr + li;
            Sr = nSr;
        }
    }
    __syncthreads();

    // Phase C
    {
        const float Dh = D_skip[h];
        floatx4 acc[4][2] = {};
        #pragma unroll
        for (int ks = 0; ks < 6; ++ks) {
            bf16x8 af[4], bfv[2];
            if (ks < 2) {
                #pragma unroll
                for (int i = 0; i < 4; ++i)
                    af[i] = *(const bf16x8*)&Tp[(i * 16 + lm) * 72 + ks * 32 + lq * 8];
                #pragma unroll
                for (int j = 0; j < 2; ++j)
                    bfv[j] = *(const bf16x8*)&U[(wv * 32 + j * 16 + lm) * 72 + ks * 32 + lq * 8];
            } else {
                #pragma unroll
                for (int i = 0; i < 4; ++i)
                    af[i] = *(const bf16x8*)&V[(i * 16 + lm) * 136 + (ks - 2) * 32 + lq * 8];
                #pragma unroll
                for (int j = 0; j < 2; ++j)
                    bfv[j] = *(const bf16x8*)&S[(wv * 32 + j * 16 + lm) * 136 + (ks - 2) * 32 + lq * 8];
            }
            #pragma unroll
            for (int i = 0; i < 4; ++i) {
                #pragma unroll
                for (int j = 0; j < 2; ++j)
                    acc[i][j] = __builtin_amdgcn_mfma_f32_16x16x32_bf16(af[i], bfv[j], acc[i][j], 0, 0, 0);
            }
        }
        #pragma unroll
        for (int j = 0; j < 2; ++j) {
            int ncol = wv * 32 + j * 16 + lm;
            int bloc = ncol >> 5, c = ncol & 31;
            size_t gbase = (((size_t)(b0 + bloc) * H_DIM + h) << 11) + (c << 6);
            #pragma unroll
            for (int i = 0; i < 4; ++i) {
                int t0 = i * 16 + lq * 4;
                u16 upk[4];
                *(uint2*)upk = *(const uint2*)&U[ncol * 72 + t0];
                u16 opk[4];
                #pragma unroll
                for (int r = 0; r < 4; ++r) {
                    float uvv = b2f(upk[r]);
                    float yv = gelu_tanh_(fmaf(Dh, uvv, acc[i][j][r]));
                    opk[r] = f2b(yv);
                }
                *(uint2*)&YT[gbase + t0] = *(uint2*)opk;
            }
        }
    }
}

// ---------------------------------------------------------------------------
// stage a 128x32 bf16 tile into LDS via global_load_lds, 512 threads.
// LDS dest LINEAR; bank-swizzle via permuted GLOBAL source chunk
// (chunk' = chunk ^ ((row>>1)&3)); readers XOR the same way.
// ---------------------------------------------------------------------------
__device__ __forceinline__ void stage_tile_512(
    const u16* __restrict__ g, u16* lds, int row0, int k0)
{
    const int t = threadIdx.x;           // 0..511, one 16B chunk each
    const int row  = t >> 2;             // 0..127
    const int csrc = (t & 3) ^ ((t >> 3) & 3);
    const u16* gp = g + (size_t)(row0 + row) * 512 + k0 + csrc * 8;
    __builtin_amdgcn_global_load_lds(
        (const __attribute__((address_space(1))) unsigned int*)gp,
        (__attribute__((address_space(3))) unsigned int*)(lds + (size_t)t * 8),
        16, 0, 0);
}

// A-tile from YT (B,H,L): thread reads 8 consecutive l for one h(=k), then
// transposes into As[l][k] via 8 offset-immediate ds_write_b16.
// Swizzle on chunk: c_store = kc ^ ((row>>3)&3)  (row>>3 == lc here).
__device__ __forceinline__ uint4 ldA_yt(
    const u16* __restrict__ YT, int b, int l0, int k0)
{
    const int k  = threadIdx.x >> 4;
    const int lc = threadIdx.x & 15;
    return *(const uint4*)(YT + (((size_t)(b * 512 + k0 + k)) << 11) + l0 + lc * 8);
}
__device__ __forceinline__ void dswA(u16* lds, uint4 av)
{
    const int k  = threadIdx.x >> 4;
    const int lc = threadIdx.x & 15;
    u16* p = lds + (lc * 8) * 32 + (((k >> 3) ^ (lc & 3)) << 3) + (k & 7);
    const u16* s = (const u16*)&av;
    #pragma unroll
    for (int j = 0; j < 8; ++j) p[j * 32] = s[j];
}

// ---------------------------------------------------------------------------
// 5) GEMM1 + GLU + residual (dual-B) reading A DIRECTLY from YT (ytrans
//    eliminated), plus LN1 row-stats (sum, sumsq) side-output per n0-block.
//    512 threads (8 waves, 2m x 4n), double-buffered 2-phase pipeline.
// ---------------------------------------------------------------------------
__global__ __launch_bounds__(512) void gemm1_glu_kernel(
    const u16* __restrict__ YT, const u16* __restrict__ Wo,
    const float* __restrict__ bo, const float* __restrict__ x,
    u16* __restrict__ out, float2* __restrict__ Pstats)
{
    __shared__ u16 As[2][128 * 32];
    __shared__ u16 Ba[2][128 * 32];
    __shared__ u16 Bg[2][128 * 32];
    __shared__ float2 red1[128][4];
    const int t    = threadIdx.x;
    const int lane = t & 63;
    const int wv   = t >> 6;             // 0..7
    const int wm   = wv >> 2, wn = wv & 3;
    const int lm   = lane & 15, lq = lane >> 4;
    const int sw   = (lq ^ ((lm >> 1) & 3)) * 8;   // B-side read swizzle
    const int m0   = blockIdx.x * 128, n0 = blockIdx.y * 128;
    const int b    = m0 >> 11;
    const int l0   = m0 & 2047;
    floatx4 accA[4][2] = {};
    floatx4 accG[4][2] = {};

    // A-side read swizzle per i (row>>3 bits reduce to lane bits)
    int swA[4];
    #pragma unroll
    for (int i = 0; i < 4; ++i)
        swA[i] = (lq ^ ((i * 2 + (lm >> 3)) & 3)) * 8;

    // prologue: tile 0
    uint4 av = ldA_yt(YT, b, l0, 0);
    stage_tile_512(Wo, Ba[0], n0, 0);
    stage_tile_512(Wo, Bg[0], 512 + n0, 0);
    dswA(As[0], av);
    __syncthreads();

    int cur = 0;
    for (int k0 = 32; k0 < 512; k0 += 32) {
        const int nx = cur ^ 1;
        uint4 avn = ldA_yt(YT, b, l0, k0);            // issue early (T14)
        stage_tile_512(Wo, Ba[nx], n0, k0);
        stage_tile_512(Wo, Bg[nx], 512 + n0, k0);

        bf16x8 af[4], ba[2], bg[2];
        #pragma unroll
        for (int i = 0; i < 4; ++i)
            af[i] = *(const bf16x8*)&As[cur][(wm * 64 + i * 16 + lm) * 32 + swA[i]];
        #pragma unroll
        for (int j = 0; j < 2; ++j) {
            ba[j] = *(const bf16x8*)&Ba[cur][(wn * 32 + j * 16 + lm) * 32 + sw];
            bg[j] = *(const bf16x8*)&Bg[cur][(wn * 32 + j * 16 + lm) * 32 + sw];
        }
        #pragma unroll
        for (int i = 0; i < 4; ++i) {
            #pragma unroll
            for (int j = 0; j < 2; ++j) {
                accA[i][j] = __builtin_amdgcn_mfma_f32_16x16x32_bf16(af[i], ba[j], accA[i][j], 0, 0, 0);
                accG[i][j] = __builtin_amdgcn_mfma_f32_16x16x32_bf16(af[i], bg[j], accG[i][j], 0, 0, 0);
            }
        }
        dswA(As[nx], avn);                            // write late, under MFMA-covered latency
        __syncthreads();
        cur = nx;
    }
    // final K-tile (no prefetch)
    {
        bf16x8 af[4], ba[2], bg[2];
        #pragma unroll
        for (int i = 0; i < 4; ++i)
            af[i] = *(const bf16x8*)&As[cur][(wm * 64 + i * 16 + lm) * 32 + swA[i]];
        #pragma unroll
        for (int j = 0; j < 2; ++j) {
            ba[j] = *(const bf16x8*)&Ba[cur][(wn * 32 + j * 16 + lm) * 32 + sw];
            bg[j] = *(const bf16x8*)&Bg[cur][(wn * 32 + j * 16 + lm) * 32 + sw];
        }
        #pragma unroll
        for (int i = 0; i < 4; ++i) {
            #pragma unroll
            for (int j = 0; j < 2; ++j) {
                accA[i][j] = __builtin_amdgcn_mfma_f32_16x16x32_bf16(af[i], ba[j], accA[i][j], 0, 0, 0);
                accG[i][j] = __builtin_amdgcn_mfma_f32_16x16x32_bf16(af[i], bg[j], accG[i][j], 0, 0, 0);
            }
        }
    }

    // epilogue: GLU + residual, accumulate LN1 row partials
    float bav[2], bgv[2];
    #pragma unroll
    for (int j = 0; j < 2; ++j) {
        int n = n0 + wn * 32 + j * 16 + lm;
        bav[j] = bo[n]; bgv[j] = bo[512 + n];
    }
    #pragma unroll
    for (int i = 0; i < 4; ++i) {
        #pragma unroll
        for (int r = 0; r < 4; ++r) {
            int row = wm * 64 + i * 16 + lq * 4 + r;
            int m = m0 + row;
            float s = 0.0f, sq = 0.0f;
            #pragma unroll
            for (int j = 0; j < 2; ++j) {
                int n = n0 + wn * 32 + j * 16 + lm;
                float a_ = accA[i][j][r] + bav[j];
                float g_ = accG[i][j][r] + bgv[j];
                float xv = x[(size_t)m * 512 + n];
                float ov = fmaf(a_, sigmoidf_(g_), xv);
                out[(size_t)m * 512 + n] = f2b(ov);
                s += ov; sq = fmaf(ov, ov, sq);
            }
            #pragma unroll
            for (int msk = 1; msk < 16; msk <<= 1) {
                s  += __shfl_xor(s, msk, 64);
                sq += __shfl_xor(sq, msk, 64);
            }
            if (lm == 0) { float2 p; p.x = s; p.y = sq; red1[row][wn] = p; }
        }
    }
    __syncthreads();
    if (t < 128) {
        float s = 0.0f, sq = 0.0f;
        #pragma unroll
        for (int w = 0; w < 4; ++w) { float2 p = red1[t][w]; s += p.x; sq += p.y; }
        float2 o; o.x = s; o.y = sq;
        Pstats[(size_t)(m0 + t) * 4 + blockIdx.y] = o;
    }
}

// ---------------------------------------------------------------------------
// 6) GEMM (W1*g1 folded) + LN1 epilogue + ReLU:
//    h1 = relu( rs_m*(W1g·z)[f] - rs_m*mu_m*c1[f] + c2[f] + bc1[f] )
//    Structure identical to proven gemm kernel; only epilogue differs.
// ---------------------------------------------------------------------------
__global__ __launch_bounds__(512) void gemm_relu_kernel(
    const u16* __restrict__ A, const u16* __restrict__ Bw,
    const float* __restrict__ bias, const float2* __restrict__ Pstats,
    const float* __restrict__ c1, const float* __restrict__ c2,
    u16* __restrict__ C)
{
    __shared__ u16 As[2][128 * 32];
    __shared__ u16 Bs[2][128 * 32];
    __shared__ float musig[128][2];
    const int t    = threadIdx.x;
    const int lane = t & 63;
    const int wv   = t >> 6;
    const int wm   = wv >> 2, wn = wv & 3;
    const int lm   = lane & 15, lq = lane >> 4;
    const int sw   = (lq ^ ((lm >> 1) & 3)) * 8;
    const int m0   = blockIdx.x * 128, n0 = blockIdx.y * 128;
    floatx4 acc[4][2] = {};

    if (t < 128) {
        float s = 0.0f, sq = 0.0f;
        #pragma unroll
        for (int w = 0; w < 4; ++w) {
            float2 p = Pstats[(size_t)(m0 + t) * 4 + w];
            s += p.x; sq += p.y;
        }
        float mu  = s * (1.0f / 512.0f);
        float var = sq * (1.0f / 512.0f) - mu * mu;
        musig[t][0] = mu;
        musig[t][1] = rsqrtf(var + 1e-5f);
    }
    stage_tile_512(A, As[0], m0, 0);
    stage_tile_512(Bw, Bs[0], n0, 0);
    __syncthreads();

    int cur = 0;
    for (int k0 = 32; k0 < 512; k0 += 32) {
        const int nx = cur ^ 1;
        stage_tile_512(A, As[nx], m0, k0);
        stage_tile_512(Bw, Bs[nx], n0, k0);

        bf16x8 af[4], bfr[2];
        #pragma unroll
        for (int i = 0; i < 4; ++i)
            af[i] = *(const bf16x8*)&As[cur][(wm * 64 + i * 16 + lm) * 32 + sw];
        #pragma unroll
        for (int j = 0; j < 2; ++j)
            bfr[j] = *(const bf16x8*)&Bs[cur][(wn * 32 + j * 16 + lm) * 32 + sw];
        #pragma unroll
        for (int i = 0; i < 4; ++i) {
            #pragma unroll
            for (int j = 0; j < 2; ++j)
                acc[i][j] = __builtin_amdgcn_mfma_f32_16x16x32_bf16(af[i], bfr[j], acc[i][j], 0, 0, 0);
        }
        __syncthreads();
        cur = nx;
    }
    {
        bf16x8 af[4], bfr[2];
        #pragma unroll
        for (int i = 0; i < 4; ++i)
            af[i] = *(const bf16x8*)&As[cur][(wm * 64 + i * 16 + lm) * 32 + sw];
        #pragma unroll
        for (int j = 0; j < 2; ++j)
            bfr[j] = *(const bf16x8*)&Bs[cur][(wn * 32 + j * 16 + lm) * 32 + sw];
        #pragma unroll
        for (int i = 0; i < 4; ++i) {
            #pragma unroll
            for (int j = 0; j < 2; ++j)
                acc[i][j] = __builtin_amdgcn_mfma_f32_16x16x32_bf16(af[i], bfr[j], acc[i][j], 0, 0, 0);
        }
    }
    float c1v[2], c2v[2];
    #pragma unroll
    for (int j = 0; j < 2; ++j) {
        int n = n0 + wn * 32 + j * 16 + lm;
        c1v[j] = c1[n];
        c2v[j] = c2[n] + bias[n];
    }
    #pragma unroll
    for (int i = 0; i < 4; ++i) {
        #pragma unroll
        for (int r = 0; r < 4; ++r) {
            int row = wm * 64 + i * 16 + lq * 4 + r;
            float mu = musig[row][0], rs = musig[row][1];
            float nmr = -rs * mu;
            #pragma unroll
            for (int j = 0; j < 2; ++j) {
                int n = n0 + wn * 32 + j * 16 + lm;
                float v = fmaf(rs, acc[i][j][r], fmaf(nmr, c1v[j], c2v[j]));
                C[(size_t)(m0 + row) * 512 + n] = f2b(fmaxf(v, 0.0f));
            }
        }
    }
}

// ---------------------------------------------------------------------------
// 7) GEMM2 (128x128 tile, proven shape) + LN1'd residual epilogue.
//    z = W2·h1 + bc2 + LN1(res);  writes z bf16 + LN2 row-partials
//    (sum, sumsq) per n0-block into Pstats2[m][4] (single writer/cell).
// ---------------------------------------------------------------------------
__global__ __launch_bounds__(512) void gemm2_tile_kernel(
    const u16* __restrict__ A, const u16* __restrict__ Bw,
    const float* __restrict__ bias, const u16* __restrict__ res,
    const float2* __restrict__ Pstats,
    const float* __restrict__ g1, const float* __restrict__ beta1,
    u16* __restrict__ Z, float2* __restrict__ Pstats2)
{
    __shared__ u16 As[2][128 * 32];
    __shared__ u16 Bs[2][128 * 32];
    __shared__ float musig[128][2];
    __shared__ float2 red2[128][4];
    const int t    = threadIdx.x;
    const int lane = t & 63;
    const int wv   = t >> 6;
    const int wm   = wv >> 2, wn = wv & 3;
    const int lm   = lane & 15, lq = lane >> 4;
    const int sw   = (lq ^ ((lm >> 1) & 3)) * 8;
    const int m0   = blockIdx.x * 128, n0 = blockIdx.y * 128;
    floatx4 acc[4][2] = {};

    if (t < 128) {
        float s = 0.0f, sq = 0.0f;
        #pragma unroll
        for (int w = 0; w < 4; ++w) {
            float2 p = Pstats[(size_t)(m0 + t) * 4 + w];
            s += p.x; sq += p.y;
        }
        float mu  = s * (1.0f / 512.0f);
        float var = sq * (1.0f / 512.0f) - mu * mu;
        musig[t][0] = mu;
        musig[t][1] = rsqrtf(var + 1e-5f);
    }
    stage_tile_512(A, As[0], m0, 0);
    stage_tile_512(Bw, Bs[0], n0, 0);
    __syncthreads();

    int cur = 0;
    for (int k0 = 32; k0 < 512; k0 += 32) {
        const int nx = cur ^ 1;
        stage_tile_512(A, As[nx], m0, k0);
        stage_tile_512(Bw, Bs[nx], n0, k0);

        bf16x8 af[4], bfr[2];
        #pragma unroll
        for (int i = 0; i < 4; ++i)
            af[i] = *(const bf16x8*)&As[cur][(wm * 64 + i * 16 + lm) * 32 + sw];
        #pragma unroll
        for (int j = 0; j < 2; ++j)
            bfr[j] = *(const bf16x8*)&Bs[cur][(wn * 32 + j * 16 + lm) * 32 + sw];
        #pragma unroll
        for (int i = 0; i < 4; ++i) {
            #pragma unroll
            for (int j = 0; j < 2; ++j)
                acc[i][j] = __builtin_amdgcn_mfma_f32_16x16x32_bf16(af[i], bfr[j], acc[i][j], 0, 0, 0);
        }
        __syncthreads();
        cur = nx;
    }
    {
        bf16x8 af[4], bfr[2];
        #pragma unroll
        for (int i = 0; i < 4; ++i)
            af[i] = *(const bf16x8*)&As[cur][(wm * 64 + i * 16 + lm) * 32 + sw];
        #pragma unroll
        for (int j = 0; j < 2; ++j)
            bfr[j] = *(const bf16x8*)&Bs[cur][(wn * 32 + j * 16 + lm) * 32 + sw];
        #pragma unroll
        for (int i = 0; i < 4; ++i) {
            #pragma unroll
            for (int j = 0; j < 2; ++j)
                acc[i][j] = __builtin_amdgcn_mfma_f32_16x16x32_bf16(af[i], bfr[j], acc[i][j], 0, 0, 0);
        }
    }

    // epilogue: z = acc + bias + LN1(res); write z bf16; LN2 row partials
    float bv[2], gv1[2], bt1[2];
    #pragma unroll
    for (int j = 0; j < 2; ++j) {
        int n = n0 + wn * 32 + j * 16 + lm;
        bv[j]  = bias[n];
        gv1[j] = g1[n];
        bt1[j] = beta1[n];
    }
    #pragma unroll
    for (int i = 0; i < 4; ++i) {
        #pragma unroll
        for (int r = 0; r < 4; ++r) {
            int row = wm * 64 + i * 16 + lq * 4 + r;
            int m = m0 + row;
            float mu1 = musig[row][0], rs1 = musig[row][1];
            float s = 0.0f, sq = 0.0f;
            #pragma unroll
            for (int j = 0; j < 2; ++j) {
                int n = n0 + wn * 32 + j * 16 + lm;
                float zl = fmaf((b2f(res[(size_t)m * 512 + n]) - mu1) * rs1, gv1[j], bt1[j]);
                float v = acc[i][j][r] + bv[j] + zl;
                Z[(size_t)m * 512 + n] = f2b(v);
                s += v; sq = fmaf(v, v, sq);
            }
            #pragma unroll
            for (int msk = 1; msk < 16; msk <<= 1) {
                s  += __shfl_xor(s, msk, 64);
                sq += __shfl_xor(sq, msk, 64);
            }
            if (lm == 0) { float2 p; p.x = s; p.y = sq; red2[row][wn] = p; }
        }
    }
    __syncthreads();
    if (t < 128) {
        float s = 0.0f, sq = 0.0f;
        #pragma unroll
        for (int w = 0; w < 4; ++w) { float2 p = red2[t][w]; s += p.x; sq += p.y; }
        float2 o; o.x = s; o.y = sq;
        Pstats2[(size_t)(m0 + t) * 4 + blockIdx.y] = o;
    }
}

// ---------------------------------------------------------------------------
// 8) LN2 finish: out = (z - mu)*rs*g2 + b2, fp32. Memory-bound streaming.
// ---------------------------------------------------------------------------
__global__ __launch_bounds__(256) void ln2_finish_kernel(
    const u16* __restrict__ Z, const float2* __restrict__ Pstats2,
    const float* __restrict__ gamma, const float* __restrict__ beta,
    float* __restrict__ out)
{
    int w    = threadIdx.x >> 6;
    int lane = threadIdx.x & 63;
    size_t row  = (size_t)blockIdx.x * 4 + w;
    float s = 0.0f, sq = 0.0f;
    #pragma unroll
    for (int w4 = 0; w4 < 4; ++w4) {
        float2 p = Pstats2[row * 4 + w4];
        s += p.x; sq += p.y;
    }
    float mu  = s * (1.0f / 512.0f);
    float var = sq * (1.0f / 512.0f) - mu * mu;
    float rs  = rsqrtf(var + 1e-5f);
    size_t base = row * 512 + lane * 8;
    uint4 raw = *(const uint4*)(Z + base);
    float v[8];
    unpack2(raw.x, v[0], v[1]); unpack2(raw.y, v[2], v[3]);
    unpack2(raw.z, v[4], v[5]); unpack2(raw.w, v[6], v[7]);
    float g[8], bt[8];
    *(float4*)&g[0]  = *(const float4*)(gamma + lane * 8);
    *(float4*)&g[4]  = *(const float4*)(gamma + lane * 8 + 4);
    *(float4*)&bt[0] = *(const float4*)(beta + lane * 8);
    *(float4*)&bt[4] = *(const float4*)(beta + lane * 8 + 4);
    float o[8];
    #pragma unroll
    for (int i = 0; i < 8; ++i)
        o[i] = fmaf((v[i] - mu) * rs, g[i], bt[i]);
    *(float4*)(out + base)     = *(float4*)&o[0];
    *(float4*)(out + base + 4) = *(float4*)&o[4];
}

// ---------------------------------------------------------------------------
extern "C" void kernel_launch(void* const* d_in, const int* in_sizes, int n_in,
                              void* d_out, int out_size, void* d_ws, size_t ws_size,
                              hipStream_t stream)
{
    (void)in_sizes; (void)n_in; (void)out_size; (void)ws_size;
    const float* x      = (const float*)d_in[0];
    const float* log_dt = (const float*)d_in[1];
    const float* A_re   = (const float*)d_in[2];
    const float* A_im   = (const float*)d_in[3];
    const float* C_re   = (const float*)d_in[4];
    const float* C_im   = (const float*)d_in[5];
    const float* D_skip = (const float*)d_in[6];
    const float* W_out  = (const float*)d_in[7];
    const float* b_out  = (const float*)d_in[8];
    const float* g1     = (const float*)d_in[9];
    const float* beta1  = (const float*)d_in[10];
    const float* g2     = (const float*)d_in[11];
    const float* beta2  = (const float*)d_in[12];
    const float* W1     = (const float*)d_in[13];
    const float* bc1    = (const float*)d_in[14];
    const float* W2     = (const float*)d_in[15];
    const float* bc2    = (const float*)d_in[16];
    float* out = (float*)d_out;

    // workspace: P 512K | hole | Toep 4M | weights 2M | r1/r2/r3 | Pstats | c1 c2 | Pstats2
    char*   wsb    = (char*)d_ws;
    float*  P      = (float*)wsb;
    u16*    Toep   = (u16*)(wsb + 4 * HN * 4 + 512 * 64 * 4);
    u16*    Wobf   = Toep + 512 * 4096;
    u16*    W1bf   = Wobf + 1024 * 512;
    u16*    W2bf   = W1bf + 512 * 512;
    u16*    r1     = W2bf + 512 * 512;   // XT -> h1_bf
    u16*    r2     = r1 + BLH;           // YT -> z2_bf
    u16*    r3     = r2 + BLH;           // x1pre_bf
    float2* Pstats = (float2*)(r3 + BLH);
    float*  c1     = (float*)(Pstats + (size_t)M_DIM * 4);
    float*  c2     = c1 + 512;
    float2* Pstats2 = (float2*)(c2 + 512);

    setup_kernel<<<9472, 256, 0, stream>>>(x, W_out, W1, W2, log_dt, A_re, A_im,
                                           C_re, C_im, g1, beta1,
                                           r1, Wobf, W1bf, W2bf, P, Toep, c1, c2);
    ssm_chunk_kernel<<<dim3(H_DIM, 2), 256, 0, stream>>>(r1, P, Toep, D_skip, r2);
    gemm1_glu_kernel<<<dim3(M_DIM / 128, 4), 512, 0, stream>>>(r2, Wobf, b_out, x, r3, Pstats);
    gemm_relu_kernel<<<dim3(M_DIM / 128, 4), 512, 0, stream>>>(r3, W1bf, bc1, Pstats, c1, c2, r1);
    gemm2_tile_kernel<<<dim3(M_DIM / 128, 4), 512, 0, stream>>>(r1, W2bf, bc2, r3, Pstats, g1, beta1, r2, Pstats2);
    ln2_finish_kernel<<<M_DIM / 4, 256, 0, stream>>>(r2, Pstats2, g2, beta2, out);
}

// Round 8
// 234.490 us; speedup vs baseline: 1.0497x; 1.0096x over previous
//
#include <hip/hip_runtime.h>
#include <cstddef>
#include <cstdint>

#define B_DIM 8
#define L_DIM 2048
#define H_DIM 512
#define N_DIM 64
#define HN (H_DIM * N_DIM)          // 32768
#define BLH (B_DIM * L_DIM * H_DIM) // 8388608
#define M_DIM (B_DIM * L_DIM)       // 16384

typedef unsigned short u16;
typedef short bf16x8 __attribute__((ext_vector_type(8)));
typedef float floatx4 __attribute__((ext_vector_type(4)));

__device__ __forceinline__ float sigmoidf_(float v) {
    return 1.0f / (1.0f + __expf(-v));
}

// jax.nn.gelu default: approximate=True (tanh form)
__device__ __forceinline__ float gelu_tanh_(float x) {
    float x3 = x * x * x;
    float z = 0.7978845608028654f * fmaf(0.044715f, x3, x);
    float e = __expf(-2.0f * fabsf(z));
    float th = (1.0f - e) / (1.0f + e);
    th = copysignf(th, z);
    return 0.5f * x * (1.0f + th);
}

__device__ __forceinline__ u16 f2b(float f) {
    unsigned u = __float_as_uint(f);
    unsigned r = (u + 0x7fffu + ((u >> 16) & 1u)) >> 16;
    return (u16)r;
}
__device__ __forceinline__ float b2f(u16 u) {
    return __uint_as_float(((unsigned)u) << 16);
}
__device__ __forceinline__ void unpack2(unsigned u, float& a, float& b) {
    a = __uint_as_float(u << 16);
    b = __uint_as_float(u & 0xffff0000u);
}
__device__ __forceinline__ unsigned pack2(float a, float b) {
    return (unsigned)f2b(a) | ((unsigned)f2b(b) << 16);
}

// complex helpers
__device__ __forceinline__ void csq(float& r, float& i) {
    float nr = r * r - i * i;
    i = 2.0f * r * i;
    r = nr;
}

// ---------------------------------------------------------------------------
// 0) SETUP (one launch, block-partitioned):
//    [0,8192)     xtrans: x (B,L,H) fp32 -> XT (B,H,L) bf16
//    [8192,9216)  weight casts: Wo->bf16, W1*g1->bf16 (LN1 fold), W2->bf16
//    [9216,9344)  SSM params P + Ktab(LDS) + Toeplitz fill
//    [9344,9472)  LN1-fold column sums: c1[f]=sum_n W1[f][n]g1[n], c2=..beta1
// ---------------------------------------------------------------------------
__global__ __launch_bounds__(256) void setup_kernel(
    const float* __restrict__ x, const float* __restrict__ W_out,
    const float* __restrict__ W1, const float* __restrict__ W2,
    const float* __restrict__ log_dt, const float* __restrict__ A_re,
    const float* __restrict__ A_im, const float* __restrict__ C_re,
    const float* __restrict__ C_im, const float* __restrict__ g1,
    const float* __restrict__ beta1,
    u16* __restrict__ XT, u16* __restrict__ Wobf, u16* __restrict__ W1gbf,
    u16* __restrict__ W2bf, float* __restrict__ P, u16* __restrict__ Toep_bf,
    float* __restrict__ c1, float* __restrict__ c2)
{
    __shared__ float tile[32][33];
    __shared__ float ktab_s[4][64];
    const int bid = blockIdx.x;
    const int t   = threadIdx.x;

    if (bid < 8192) {
        // ---- xtrans
        int b  = bid >> 10;
        int hy = (bid >> 6) & 15;
        int lx = bid & 63;
        int l0 = lx * 32, h0 = hy * 32;
        int tx = t & 31, ty = t >> 5;
        #pragma unroll
        for (int r = 0; r < 4; ++r)
            tile[ty + r * 8][tx] = x[((size_t)b * L_DIM + l0 + ty + r * 8) * H_DIM + h0 + tx];
        __syncthreads();
        #pragma unroll
        for (int r = 0; r < 4; ++r)
            XT[(((size_t)b * H_DIM + h0 + ty + r * 8) << 11) + l0 + tx] = f2b(tile[tx][ty + r * 8]);
    } else if (bid < 9216) {
        // ---- weight casts
        int off = bid - 8192;
        if (off < 512) {
            int i = off * 256 + t;
            float4 v = *(const float4*)(W_out + (size_t)i * 4);
            uint2 p; p.x = pack2(v.x, v.y); p.y = pack2(v.z, v.w);
            *(uint2*)(Wobf + (size_t)i * 4) = p;
        } else if (off < 768) {
            int i = (off - 512) * 256 + t;
            float4 v = *(const float4*)(W1 + (size_t)i * 4);
            int n = (i * 4) & 511;
            float4 g = *(const float4*)(g1 + n);
            uint2 p; p.x = pack2(v.x * g.x, v.y * g.y);
            p.y = pack2(v.z * g.z, v.w * g.w);
            *(uint2*)(W1gbf + (size_t)i * 4) = p;
        } else {
            int i = (off - 768) * 256 + t;
            float4 v = *(const float4*)(W2 + (size_t)i * 4);
            uint2 p; p.x = pack2(v.x, v.y); p.y = pack2(v.z, v.w);
            *(uint2*)(W2bf + (size_t)i * 4) = p;
        }
    } else if (bid < 9344) {
        // ---- SSM params + Ktab + Toeplitz
        const int wv = t >> 6, lane = t & 63;
        const int i = (bid - 9216) * 256 + t;
        const int h = i >> 6;
        float dt = expf(log_dt[h]);
        float Ar = A_re[i], Ai = A_im[i];
        float ar = dt * Ar, ai = dt * Ai;
        float e = expf(ar);
        float wr = e * cosf(ai);
        float wi = e * sinf(ai);
        float em1r = wr - 1.0f, em1i = wi;
        float inv = 1.0f / fmaf(Ar, Ar, Ai * Ai);
        float qr = fmaf(em1r, Ar, em1i * Ai) * inv;
        float qi = fmaf(em1i, Ar, -(em1r * Ai)) * inv;
        float Cr = C_re[i], Ci = C_im[i];
        float c2r = 2.0f * (Cr * qr - Ci * qi);
        float c2i = 2.0f * (Cr * qi + Ci * qr);
        P[i]          = wr;
        P[HN + i]     = wi;
        P[2 * HN + i] = c2r;
        P[3 * HN + i] = c2i;

        float pr = 1.0f, pi = 0.0f;
        for (int tau = 0; tau < 64; ++tau) {
            float term = c2r * pr - c2i * pi;
            #pragma unroll
            for (int m = 32; m > 0; m >>= 1) term += __shfl_xor(term, m, 64);
            if (lane == 0) ktab_s[wv][tau] = term;
            float nr = pr * wr - pi * wi, ni = pr * wi + pi * wr;
            pr = nr; pi = ni;
        }
        __syncthreads();

        const int h0 = (bid - 9216) * 4;
        #pragma unroll
        for (int r = 0; r < 8; ++r) {
            int c = t + r * 256;
            int hh = c >> 9, rem = c & 511;
            int tt = rem >> 3, j0 = (rem & 7) * 8;
            u16 vv[8];
            #pragma unroll
            for (int jj = 0; jj < 8; ++jj) {
                int j = j0 + jj;
                vv[jj] = (j <= tt) ? f2b(ktab_s[hh][tt - j]) : (u16)0;
            }
            *(uint4*)&Toep_bf[((size_t)(h0 + hh) << 12) + (tt << 6) + j0] = *(uint4*)vv;
        }
    } else {
        // ---- LN1-fold column sums over n for W1 row f
        int f = (bid - 9344) * 4 + (t >> 6);
        int lane = t & 63;
        int n = lane * 8;
        float4 w0 = *(const float4*)(W1 + (size_t)f * 512 + n);
        float4 w1v = *(const float4*)(W1 + (size_t)f * 512 + n + 4);
        float4 ga = *(const float4*)(g1 + n);
        float4 gb = *(const float4*)(g1 + n + 4);
        float4 b0 = *(const float4*)(beta1 + n);
        float4 b1 = *(const float4*)(beta1 + n + 4);
        float s1 = w0.x * ga.x + w0.y * ga.y + w0.z * ga.z + w0.w * ga.w
                 + w1v.x * gb.x + w1v.y * gb.y + w1v.z * gb.z + w1v.w * gb.w;
        float s2 = w0.x * b0.x + w0.y * b0.y + w0.z * b0.z + w0.w * b0.w
                 + w1v.x * b1.x + w1v.y * b1.y + w1v.z * b1.z + w1v.w * b1.w;
        #pragma unroll
        for (int m = 32; m > 0; m >>= 1) {
            s1 += __shfl_xor(s1, m, 64);
            s2 += __shfl_xor(s2, m, 64);
        }
        if (lane == 0) { c1[f] = s1; c2[f] = s2; }
    }
}

// ---------------------------------------------------------------------------
// 3) Chunked SSM via MFMA. One workgroup = (h, half of b). T=64, 32 chunks.
// ---------------------------------------------------------------------------
__global__ __launch_bounds__(256) void ssm_chunk_kernel(
    const u16* __restrict__ XT, const float* __restrict__ P,
    const u16* __restrict__ Toep_bf, const float* __restrict__ D_skip,
    u16* __restrict__ YT)
{
    __shared__ u16 U[128 * 72];      // [ncol][j], pad 72
    __shared__ u16 S[128 * 136];     // [ncol][2n], pad 136
    __shared__ u16 EVT[13312];       // union: E[128*72]=9216 | Toep[64*72]=4608 + V[64*136]=8704
    u16* E  = EVT;
    u16* Tp = EVT;
    u16* V  = EVT + 4608;

    const int h    = blockIdx.x;
    const int b0   = blockIdx.y * 4;
    const int t    = threadIdx.x;
    const int lane = t & 63;
    const int wv   = t >> 6;
    const int lm   = lane & 15, lq = lane >> 4;

    const int pidx = (h << 6) + lane;
    const float wr  = P[pidx],          wi  = P[HN + pidx];
    const float c2r = P[2 * HN + pidx], c2i = P[3 * HN + pidx];

    // stage U: 128 rows x 64 bf16, 16B chunks (coalesced), padded LDS rows
    #pragma unroll
    for (int r = 0; r < 4; ++r) {
        int idx = t + r * 256;
        int row = idx >> 3, ch = idx & 7;
        const u16* gp = XT + (((size_t)(b0 + (row >> 5)) * H_DIM + h) << 11)
                           + ((row & 31) << 6) + (ch << 3);
        *(uint4*)&U[row * 72 + ch * 8] = *(const uint4*)gp;
    }

    // base power w^(16*wv) for this wave
    float bwr, bwi;
    {
        float g16r = wr, g16i = wi;
        csq(g16r, g16i); csq(g16r, g16i); csq(g16r, g16i); csq(g16r, g16i); // w^16
        if (wv == 0)      { bwr = 1.0f; bwi = 0.0f; }
        else if (wv == 1) { bwr = g16r; bwi = g16i; }
        else if (wv == 2) { bwr = g16r; bwi = g16i; csq(bwr, bwi); }
        else {
            float g32r = g16r, g32i = g16i; csq(g32r, g32i);
            bwr = g32r * g16r - g32i * g16i;
            bwi = g32r * g16i + g32i * g16r;
        }
    }

    // fill E: E[2n][j]=Re(w^(63-j)), E[2n+1][j]=Im(w^(63-j))
    {
        float pr = bwr, pi = bwi;
        #pragma unroll
        for (int jk = 0; jk < 16; ++jk) {
            int k = (wv << 4) + jk;
            int j = 63 - k;
            E[(2 * lane) * 72 + j]     = f2b(pr);
            E[(2 * lane + 1) * 72 + j] = f2b(pi);
            float nr = pr * wr - pi * wi, ni = pr * wi + pi * wr;
            pr = nr; pi = ni;
        }
    }
    __syncthreads();

    // Phase A
    {
        const int wm = wv >> 1, wn = wv & 1;
        floatx4 acc[4][4] = {};
        #pragma unroll
        for (int ks = 0; ks < 2; ++ks) {
            bf16x8 af[4], bfv[4];
            #pragma unroll
            for (int i = 0; i < 4; ++i)
                af[i] = *(const bf16x8*)&E[(wm * 64 + i * 16 + lm) * 72 + ks * 32 + lq * 8];
            #pragma unroll
            for (int j = 0; j < 4; ++j)
                bfv[j] = *(const bf16x8*)&U[(wn * 64 + j * 16 + lm) * 72 + ks * 32 + lq * 8];
            #pragma unroll
            for (int i = 0; i < 4; ++i) {
                #pragma unroll
                for (int j = 0; j < 4; ++j)
                    acc[i][j] = __builtin_amdgcn_mfma_f32_16x16x32_bf16(af[i], bfv[j], acc[i][j], 0, 0, 0);
            }
        }
        #pragma unroll
        for (int i = 0; i < 4; ++i) {
            #pragma unroll
            for (int j = 0; j < 4; ++j) {
                int ncol = wn * 64 + j * 16 + lm;
                int m0   = wm * 64 + i * 16 + lq * 4;
                u16 pk[4];
                #pragma unroll
                for (int r = 0; r < 4; ++r) pk[r] = f2b(acc[i][j][r]);
                *(uint2*)&S[ncol * 136 + m0] = *(uint2*)pk;
            }
        }
    }
    __syncthreads();

    // fill V + stage Toep + chunk scan
    {
        float pr = bwr, pi = bwi;
        {
            float nr = pr * wr - pi * wi, ni = pr * wi + pi * wr;
            pr = nr; pi = ni;
        }
        #pragma unroll
        for (int jk = 1; jk <= 16; ++jk) {
            int tr = (wv << 4) + jk - 1;
            float qr = c2r * pr - c2i * pi;
            float qi = c2r * pi + c2i * pr;
            V[tr * 136 + 2 * lane]     = f2b(qr);
            V[tr * 136 + 2 * lane + 1] = f2b(-qi);
            float nr = pr * wr - pi * wi, ni = pr * wi + pi * wr;
            pr = nr; pi = ni;
        }
        #pragma unroll
        for (int r = 0; r < 2; ++r) {
            int idx = t + r * 256;
            int row = idx >> 3, ch = idx & 7;
            *(uint4*)&Tp[row * 72 + ch * 8] =
                *(const uint4*)&Toep_bf[((size_t)h << 12) + (row << 6) + (ch << 3)];
        }
        float wTr = wr, wTi = wi;
        csq(wTr, wTi); csq(wTr, wTi); csq(wTr, wTi);
        csq(wTr, wTi); csq(wTr, wTi); csq(wTr, wTi);   // w^64
        float Sr = 0.0f, Si = 0.0f;
        const int n2 = lane * 2;
        for (int c = 0; c < 32; ++c) {
            int base = (wv * 32 + c) * 136 + n2;
            unsigned lv = *(unsigned*)&S[base];
            float lr, li;
            unpack2(lv, lr, li);
            *(unsigned*)&S[base] = pack2(Sr, Si);
            float nSr = wTr * Sr - wTi * Si + lr;
            Si = wTr * Si + wTi * Sr + li;
            Sr = nSr;
        }
    }
    __syncthreads();

    // Phase C
    {
        const float Dh = D_skip[h];
        floatx4 acc[4][2] = {};
        #pragma unroll
        for (int ks = 0; ks < 6; ++ks) {
            bf16x8 af[4], bfv[2];
            if (ks < 2) {
                #pragma unroll
                for (int i = 0; i < 4; ++i)
                    af[i] = *(const bf16x8*)&Tp[(i * 16 + lm) * 72 + ks * 32 + lq * 8];
                #pragma unroll
                for (int j = 0; j < 2; ++j)
                    bfv[j] = *(const bf16x8*)&U[(wv * 32 + j * 16 + lm) * 72 + ks * 32 + lq * 8];
            } else {
                #pragma unroll
                for (int i = 0; i < 4; ++i)
                    af[i] = *(const bf16x8*)&V[(i * 16 + lm) * 136 + (ks - 2) * 32 + lq * 8];
                #pragma unroll
                for (int j = 0; j < 2; ++j)
                    bfv[j] = *(const bf16x8*)&S[(wv * 32 + j * 16 + lm) * 136 + (ks - 2) * 32 + lq * 8];
            }
            #pragma unroll
            for (int i = 0; i < 4; ++i) {
                #pragma unroll
                for (int j = 0; j < 2; ++j)
                    acc[i][j] = __builtin_amdgcn_mfma_f32_16x16x32_bf16(af[i], bfv[j], acc[i][j], 0, 0, 0);
            }
        }
        #pragma unroll
        for (int j = 0; j < 2; ++j) {
            int ncol = wv * 32 + j * 16 + lm;
            int bloc = ncol >> 5, c = ncol & 31;
            size_t gbase = (((size_t)(b0 + bloc) * H_DIM + h) << 11) + (c << 6);
            #pragma unroll
            for (int i = 0; i < 4; ++i) {
                int t0 = i * 16 + lq * 4;
                u16 upk[4];
                *(uint2*)upk = *(const uint2*)&U[ncol * 72 + t0];
                u16 opk[4];
                #pragma unroll
                for (int r = 0; r < 4; ++r) {
                    float uvv = b2f(upk[r]);
                    float yv = gelu_tanh_(fmaf(Dh, uvv, acc[i][j][r]));
                    opk[r] = f2b(yv);
                }
                *(uint2*)&YT[gbase + t0] = *(uint2*)opk;
            }
        }
    }
}

// ---------------------------------------------------------------------------
// stage a 128x32 bf16 tile into LDS via global_load_lds, 512 threads.
// LDS dest LINEAR; bank-swizzle via permuted GLOBAL source chunk
// (chunk' = chunk ^ ((row>>1)&3)); readers XOR the same way.
// ---------------------------------------------------------------------------
__device__ __forceinline__ void stage_tile_512(
    const u16* __restrict__ g, u16* lds, int row0, int k0)
{
    const int t = threadIdx.x;           // 0..511, one 16B chunk each
    const int row  = t >> 2;             // 0..127
    const int csrc = (t & 3) ^ ((t >> 3) & 3);
    const u16* gp = g + (size_t)(row0 + row) * 512 + k0 + csrc * 8;
    __builtin_amdgcn_global_load_lds(
        (const __attribute__((address_space(1))) unsigned int*)gp,
        (__attribute__((address_space(3))) unsigned int*)(lds + (size_t)t * 8),
        16, 0, 0);
}

// stage a 128x64 bf16 tile (BK=64) into LDS, 512 threads x 2 chunks.
// Row = 8 chunks of 16B; bank = chunk-only at 128B row stride, so swizzle
// chunk' = chunk ^ (row&7) on the GLOBAL source; readers XOR identically.
__device__ __forceinline__ void stage_tile64_512(
    const u16* __restrict__ g, u16* lds, int row0, int k0)
{
    const int t = threadIdx.x;
    #pragma unroll
    for (int r = 0; r < 2; ++r) {
        int c   = t + r * 512;           // chunk id 0..1023
        int row = c >> 3, cc = c & 7;
        int csrc = cc ^ (row & 7);
        const u16* gp = g + (size_t)(row0 + row) * 512 + k0 + csrc * 8;
        __builtin_amdgcn_global_load_lds(
            (const __attribute__((address_space(1))) unsigned int*)gp,
            (__attribute__((address_space(3))) unsigned int*)(lds + (size_t)c * 8),
            16, 0, 0);
    }
}

// A-tile from YT (B,H,L): thread reads 8 consecutive l for one h(=k), then
// transposes into As[l][k] via 8 offset-immediate ds_write_b16.
// Swizzle on chunk: c_store = kc ^ ((row>>3)&3)  (row>>3 == lc here).
__device__ __forceinline__ uint4 ldA_yt(
    const u16* __restrict__ YT, int b, int l0, int k0)
{
    const int k  = threadIdx.x >> 4;
    const int lc = threadIdx.x & 15;
    return *(const uint4*)(YT + (((size_t)(b * 512 + k0 + k)) << 11) + l0 + lc * 8);
}
__device__ __forceinline__ void dswA(u16* lds, uint4 av)
{
    const int k  = threadIdx.x >> 4;
    const int lc = threadIdx.x & 15;
    u16* p = lds + (lc * 8) * 32 + (((k >> 3) ^ (lc & 3)) << 3) + (k & 7);
    const u16* s = (const u16*)&av;
    #pragma unroll
    for (int j = 0; j < 8; ++j) p[j * 32] = s[j];
}

// ---------------------------------------------------------------------------
// 5) GEMM1 + GLU + residual (dual-B) reading A DIRECTLY from YT (ytrans
//    eliminated), plus LN1 row-stats (sum, sumsq) side-output per n0-block.
//    512 threads (8 waves, 2m x 4n), double-buffered 2-phase pipeline.
// ---------------------------------------------------------------------------
__global__ __launch_bounds__(512) void gemm1_glu_kernel(
    const u16* __restrict__ YT, const u16* __restrict__ Wo,
    const float* __restrict__ bo, const float* __restrict__ x,
    u16* __restrict__ out, float2* __restrict__ Pstats)
{
    __shared__ u16 As[2][128 * 32];
    __shared__ u16 Ba[2][128 * 32];
    __shared__ u16 Bg[2][128 * 32];
    __shared__ float2 red1[128][4];
    const int t    = threadIdx.x;
    const int lane = t & 63;
    const int wv   = t >> 6;             // 0..7
    const int wm   = wv >> 2, wn = wv & 3;
    const int lm   = lane & 15, lq = lane >> 4;
    const int sw   = (lq ^ ((lm >> 1) & 3)) * 8;   // B-side read swizzle
    const int m0   = blockIdx.x * 128, n0 = blockIdx.y * 128;
    const int b    = m0 >> 11;
    const int l0   = m0 & 2047;
    floatx4 accA[4][2] = {};
    floatx4 accG[4][2] = {};

    // A-side read swizzle per i (row>>3 bits reduce to lane bits)
    int swA[4];
    #pragma unroll
    for (int i = 0; i < 4; ++i)
        swA[i] = (lq ^ ((i * 2 + (lm >> 3)) & 3)) * 8;

    // prologue: tile 0
    uint4 av = ldA_yt(YT, b, l0, 0);
    stage_tile_512(Wo, Ba[0], n0, 0);
    stage_tile_512(Wo, Bg[0], 512 + n0, 0);
    dswA(As[0], av);
    __syncthreads();

    int cur = 0;
    for (int k0 = 32; k0 < 512; k0 += 32) {
        const int nx = cur ^ 1;
        uint4 avn = ldA_yt(YT, b, l0, k0);            // issue early (T14)
        stage_tile_512(Wo, Ba[nx], n0, k0);
        stage_tile_512(Wo, Bg[nx], 512 + n0, k0);

        bf16x8 af[4], ba[2], bg[2];
        #pragma unroll
        for (int i = 0; i < 4; ++i)
            af[i] = *(const bf16x8*)&As[cur][(wm * 64 + i * 16 + lm) * 32 + swA[i]];
        #pragma unroll
        for (int j = 0; j < 2; ++j) {
            ba[j] = *(const bf16x8*)&Ba[cur][(wn * 32 + j * 16 + lm) * 32 + sw];
            bg[j] = *(const bf16x8*)&Bg[cur][(wn * 32 + j * 16 + lm) * 32 + sw];
        }
        #pragma unroll
        for (int i = 0; i < 4; ++i) {
            #pragma unroll
            for (int j = 0; j < 2; ++j) {
                accA[i][j] = __builtin_amdgcn_mfma_f32_16x16x32_bf16(af[i], ba[j], accA[i][j], 0, 0, 0);
                accG[i][j] = __builtin_amdgcn_mfma_f32_16x16x32_bf16(af[i], bg[j], accG[i][j], 0, 0, 0);
            }
        }
        dswA(As[nx], avn);                            // write late, under MFMA-covered latency
        __syncthreads();
        cur = nx;
    }
    // final K-tile (no prefetch)
    {
        bf16x8 af[4], ba[2], bg[2];
        #pragma unroll
        for (int i = 0; i < 4; ++i)
            af[i] = *(const bf16x8*)&As[cur][(wm * 64 + i * 16 + lm) * 32 + swA[i]];
        #pragma unroll
        for (int j = 0; j < 2; ++j) {
            ba[j] = *(const bf16x8*)&Ba[cur][(wn * 32 + j * 16 + lm) * 32 + sw];
            bg[j] = *(const bf16x8*)&Bg[cur][(wn * 32 + j * 16 + lm) * 32 + sw];
        }
        #pragma unroll
        for (int i = 0; i < 4; ++i) {
            #pragma unroll
            for (int j = 0; j < 2; ++j) {
                accA[i][j] = __builtin_amdgcn_mfma_f32_16x16x32_bf16(af[i], ba[j], accA[i][j], 0, 0, 0);
                accG[i][j] = __builtin_amdgcn_mfma_f32_16x16x32_bf16(af[i], bg[j], accG[i][j], 0, 0, 0);
            }
        }
    }

    // epilogue: GLU + residual, accumulate LN1 row partials
    float bav[2], bgv[2];
    #pragma unroll
    for (int j = 0; j < 2; ++j) {
        int n = n0 + wn * 32 + j * 16 + lm;
        bav[j] = bo[n]; bgv[j] = bo[512 + n];
    }
    #pragma unroll
    for (int i = 0; i < 4; ++i) {
        #pragma unroll
        for (int r = 0; r < 4; ++r) {
            int row = wm * 64 + i * 16 + lq * 4 + r;
            int m = m0 + row;
            float s = 0.0f, sq = 0.0f;
            #pragma unroll
            for (int j = 0; j < 2; ++j) {
                int n = n0 + wn * 32 + j * 16 + lm;
                float a_ = accA[i][j][r] + bav[j];
                float g_ = accG[i][j][r] + bgv[j];
                float xv = x[(size_t)m * 512 + n];
                float ov = fmaf(a_, sigmoidf_(g_), xv);
                out[(size_t)m * 512 + n] = f2b(ov);
                s += ov; sq = fmaf(ov, ov, sq);
            }
            #pragma unroll
            for (int msk = 1; msk < 16; msk <<= 1) {
                s  += __shfl_xor(s, msk, 64);
                sq += __shfl_xor(sq, msk, 64);
            }
            if (lm == 0) { float2 p; p.x = s; p.y = sq; red1[row][wn] = p; }
        }
    }
    __syncthreads();
    if (t < 128) {
        float s = 0.0f, sq = 0.0f;
        #pragma unroll
        for (int w = 0; w < 4; ++w) { float2 p = red1[t][w]; s += p.x; sq += p.y; }
        float2 o; o.x = s; o.y = sq;
        Pstats[(size_t)(m0 + t) * 4 + blockIdx.y] = o;
    }
}

// ---------------------------------------------------------------------------
// 6) GEMM (W1*g1 folded) + LN1 epilogue + ReLU.  BK=64 (8 K-iterations,
//    half the vmcnt(0) drains of BK=32).  chunk^(row&7) swizzle.
// ---------------------------------------------------------------------------
__global__ __launch_bounds__(512, 4) void gemm_relu_kernel(
    const u16* __restrict__ A, const u16* __restrict__ Bw,
    const float* __restrict__ bias, const float2* __restrict__ Pstats,
    const float* __restrict__ c1, const float* __restrict__ c2,
    u16* __restrict__ C)
{
    __shared__ u16 As[2][128 * 64];
    __shared__ u16 Bs[2][128 * 64];
    __shared__ float musig[128][2];
    const int t    = threadIdx.x;
    const int lane = t & 63;
    const int wv   = t >> 6;
    const int wm   = wv >> 2, wn = wv & 3;
    const int lm   = lane & 15, lq = lane >> 4;
    const int kc0  = (lq ^ (lm & 7)) * 8;          // ks=0 swizzled chunk col
    const int kc1  = ((4 + lq) ^ (lm & 7)) * 8;    // ks=1
    const int m0   = blockIdx.x * 128, n0 = blockIdx.y * 128;
    floatx4 acc[4][2] = {};

    if (t < 128) {
        float s = 0.0f, sq = 0.0f;
        #pragma unroll
        for (int w = 0; w < 4; ++w) {
            float2 p = Pstats[(size_t)(m0 + t) * 4 + w];
            s += p.x; sq += p.y;
        }
        float mu  = s * (1.0f / 512.0f);
        float var = sq * (1.0f / 512.0f) - mu * mu;
        musig[t][0] = mu;
        musig[t][1] = rsqrtf(var + 1e-5f);
    }
    stage_tile64_512(A, As[0], m0, 0);
    stage_tile64_512(Bw, Bs[0], n0, 0);
    __syncthreads();

    int cur = 0;
    for (int k0 = 64; k0 < 512; k0 += 64) {
        const int nx = cur ^ 1;
        stage_tile64_512(A, As[nx], m0, k0);
        stage_tile64_512(Bw, Bs[nx], n0, k0);

        #pragma unroll
        for (int ks = 0; ks < 2; ++ks) {
            const int kc = ks ? kc1 : kc0;
            bf16x8 af[4], bfr[2];
            #pragma unroll
            for (int i = 0; i < 4; ++i)
                af[i] = *(const bf16x8*)&As[cur][(wm * 64 + i * 16 + lm) * 64 + kc];
            #pragma unroll
            for (int j = 0; j < 2; ++j)
                bfr[j] = *(const bf16x8*)&Bs[cur][(wn * 32 + j * 16 + lm) * 64 + kc];
            #pragma unroll
            for (int i = 0; i < 4; ++i) {
                #pragma unroll
                for (int j = 0; j < 2; ++j)
                    acc[i][j] = __builtin_amdgcn_mfma_f32_16x16x32_bf16(af[i], bfr[j], acc[i][j], 0, 0, 0);
            }
        }
        __syncthreads();
        cur = nx;
    }
    // final K-tile
    #pragma unroll
    for (int ks = 0; ks < 2; ++ks) {
        const int kc = ks ? kc1 : kc0;
        bf16x8 af[4], bfr[2];
        #pragma unroll
        for (int i = 0; i < 4; ++i)
            af[i] = *(const bf16x8*)&As[cur][(wm * 64 + i * 16 + lm) * 64 + kc];
        #pragma unroll
        for (int j = 0; j < 2; ++j)
            bfr[j] = *(const bf16x8*)&Bs[cur][(wn * 32 + j * 16 + lm) * 64 + kc];
        #pragma unroll
        for (int i = 0; i < 4; ++i) {
            #pragma unroll
            for (int j = 0; j < 2; ++j)
                acc[i][j] = __builtin_amdgcn_mfma_f32_16x16x32_bf16(af[i], bfr[j], acc[i][j], 0, 0, 0);
        }
    }
    float c1v[2], c2v[2];
    #pragma unroll
    for (int j = 0; j < 2; ++j) {
        int n = n0 + wn * 32 + j * 16 + lm;
        c1v[j] = c1[n];
        c2v[j] = c2[n] + bias[n];
    }
    #pragma unroll
    for (int i = 0; i < 4; ++i) {
        #pragma unroll
        for (int r = 0; r < 4; ++r) {
            int row = wm * 64 + i * 16 + lq * 4 + r;
            float mu = musig[row][0], rs = musig[row][1];
            float nmr = -rs * mu;
            #pragma unroll
            for (int j = 0; j < 2; ++j) {
                int n = n0 + wn * 32 + j * 16 + lm;
                float v = fmaf(rs, acc[i][j][r], fmaf(nmr, c1v[j], c2v[j]));
                C[(size_t)(m0 + row) * 512 + n] = f2b(fmaxf(v, 0.0f));
            }
        }
    }
}

// ---------------------------------------------------------------------------
// 7) GEMM2 (128x128 tile) + LN1'd residual epilogue.  BK=64.
//    z = W2·h1 + bc2 + LN1(res);  writes z bf16 + LN2 row-partials.
// ---------------------------------------------------------------------------
__global__ __launch_bounds__(512, 4) void gemm2_tile_kernel(
    const u16* __restrict__ A, const u16* __restrict__ Bw,
    const float* __restrict__ bias, const u16* __restrict__ res,
    const float2* __restrict__ Pstats,
    const float* __restrict__ g1, const float* __restrict__ beta1,
    u16* __restrict__ Z, float2* __restrict__ Pstats2)
{
    __shared__ u16 As[2][128 * 64];
    __shared__ u16 Bs[2][128 * 64];
    __shared__ float musig[128][2];
    __shared__ float2 red2[128][4];
    const int t    = threadIdx.x;
    const int lane = t & 63;
    const int wv   = t >> 6;
    const int wm   = wv >> 2, wn = wv & 3;
    const int lm   = lane & 15, lq = lane >> 4;
    const int kc0  = (lq ^ (lm & 7)) * 8;
    const int kc1  = ((4 + lq) ^ (lm & 7)) * 8;
    const int m0   = blockIdx.x * 128, n0 = blockIdx.y * 128;
    floatx4 acc[4][2] = {};

    if (t < 128) {
        float s = 0.0f, sq = 0.0f;
        #pragma unroll
        for (int w = 0; w < 4; ++w) {
            float2 p = Pstats[(size_t)(m0 + t) * 4 + w];
            s += p.x; sq += p.y;
        }
        float mu  = s * (1.0f / 512.0f);
        float var = sq * (1.0f / 512.0f) - mu * mu;
        musig[t][0] = mu;
        musig[t][1] = rsqrtf(var + 1e-5f);
    }
    stage_tile64_512(A, As[0], m0, 0);
    stage_tile64_512(Bw, Bs[0], n0, 0);
    __syncthreads();

    int cur = 0;
    for (int k0 = 64; k0 < 512; k0 += 64) {
        const int nx = cur ^ 1;
        stage_tile64_512(A, As[nx], m0, k0);
        stage_tile64_512(Bw, Bs[nx], n0, k0);

        #pragma unroll
        for (int ks = 0; ks < 2; ++ks) {
            const int kc = ks ? kc1 : kc0;
            bf16x8 af[4], bfr[2];
            #pragma unroll
            for (int i = 0; i < 4; ++i)
                af[i] = *(const bf16x8*)&As[cur][(wm * 64 + i * 16 + lm) * 64 + kc];
            #pragma unroll
            for (int j = 0; j < 2; ++j)
                bfr[j] = *(const bf16x8*)&Bs[cur][(wn * 32 + j * 16 + lm) * 64 + kc];
            #pragma unroll
            for (int i = 0; i < 4; ++i) {
                #pragma unroll
                for (int j = 0; j < 2; ++j)
                    acc[i][j] = __builtin_amdgcn_mfma_f32_16x16x32_bf16(af[i], bfr[j], acc[i][j], 0, 0, 0);
            }
        }
        __syncthreads();
        cur = nx;
    }
    #pragma unroll
    for (int ks = 0; ks < 2; ++ks) {
        const int kc = ks ? kc1 : kc0;
        bf16x8 af[4], bfr[2];
        #pragma unroll
        for (int i = 0; i < 4; ++i)
            af[i] = *(const bf16x8*)&As[cur][(wm * 64 + i * 16 + lm) * 64 + kc];
        #pragma unroll
        for (int j = 0; j < 2; ++j)
            bfr[j] = *(const bf16x8*)&Bs[cur][(wn * 32 + j * 16 + lm) * 64 + kc];
        #pragma unroll
        for (int i = 0; i < 4; ++i) {
            #pragma unroll
            for (int j = 0; j < 2; ++j)
                acc[i][j] = __builtin_amdgcn_mfma_f32_16x16x32_bf16(af[i], bfr[j], acc[i][j], 0, 0, 0);
        }
    }

    // epilogue: z = acc + bias + LN1(res); write z bf16; LN2 row partials
    float bv[2], gv1[2], bt1[2];
    #pragma unroll
    for (int j = 0; j < 2; ++j) {
        int n = n0 + wn * 32 + j * 16 + lm;
        bv[j]  = bias[n];
        gv1[j] = g1[n];
        bt1[j] = beta1[n];
    }
    #pragma unroll
    for (int i = 0; i < 4; ++i) {
        #pragma unroll
        for (int r = 0; r < 4; ++r) {
            int row = wm * 64 + i * 16 + lq * 4 + r;
            int m = m0 + row;
            float mu1 = musig[row][0], rs1 = musig[row][1];
            float s = 0.0f, sq = 0.0f;
            #pragma unroll
            for (int j = 0; j < 2; ++j) {
                int n = n0 + wn * 32 + j * 16 + lm;
                float zl = fmaf((b2f(res[(size_t)m * 512 + n]) - mu1) * rs1, gv1[j], bt1[j]);
                float v = acc[i][j][r] + bv[j] + zl;
                Z[(size_t)m * 512 + n] = f2b(v);
                s += v; sq = fmaf(v, v, sq);
            }
            #pragma unroll
            for (int msk = 1; msk < 16; msk <<= 1) {
                s  += __shfl_xor(s, msk, 64);
                sq += __shfl_xor(sq, msk, 64);
            }
            if (lm == 0) { float2 p; p.x = s; p.y = sq; red2[row][wn] = p; }
        }
    }
    __syncthreads();
    if (t < 128) {
        float s = 0.0f, sq = 0.0f;
        #pragma unroll
        for (int w = 0; w < 4; ++w) { float2 p = red2[t][w]; s += p.x; sq += p.y; }
        float2 o; o.x = s; o.y = sq;
        Pstats2[(size_t)(m0 + t) * 4 + blockIdx.y] = o;
    }
}

// ---------------------------------------------------------------------------
// 8) LN2 finish: out = (z - mu)*rs*g2 + b2, fp32. Memory-bound streaming.
// ---------------------------------------------------------------------------
__global__ __launch_bounds__(256) void ln2_finish_kernel(
    const u16* __restrict__ Z, const float2* __restrict__ Pstats2,
    const float* __restrict__ gamma, const float* __restrict__ beta,
    float* __restrict__ out)
{
    int w    = threadIdx.x >> 6;
    int lane = threadIdx.x & 63;
    size_t row  = (size_t)blockIdx.x * 4 + w;
    float s = 0.0f, sq = 0.0f;
    #pragma unroll
    for (int w4 = 0; w4 < 4; ++w4) {
        float2 p = Pstats2[row * 4 + w4];
        s += p.x; sq += p.y;
    }
    float mu  = s * (1.0f / 512.0f);
    float var = sq * (1.0f / 512.0f) - mu * mu;
    float rs  = rsqrtf(var + 1e-5f);
    size_t base = row * 512 + lane * 8;
    uint4 raw = *(const uint4*)(Z + base);
    float v[8];
    unpack2(raw.x, v[0], v[1]); unpack2(raw.y, v[2], v[3]);
    unpack2(raw.z, v[4], v[5]); unpack2(raw.w, v[6], v[7]);
    float g[8], bt[8];
    *(float4*)&g[0]  = *(const float4*)(gamma + lane * 8);
    *(float4*)&g[4]  = *(const float4*)(gamma + lane * 8 + 4);
    *(float4*)&bt[0] = *(const float4*)(beta + lane * 8);
    *(float4*)&bt[4] = *(const float4*)(beta + lane * 8 + 4);
    float o[8];
    #pragma unroll
    for (int i = 0; i < 8; ++i)
        o[i] = fmaf((v[i] - mu) * rs, g[i], bt[i]);
    *(float4*)(out + base)     = *(float4*)&o[0];
    *(float4*)(out + base + 4) = *(float4*)&o[4];
}

// ---------------------------------------------------------------------------
extern "C" void kernel_launch(void* const* d_in, const int* in_sizes, int n_in,
                              void* d_out, int out_size, void* d_ws, size_t ws_size,
                              hipStream_t stream)
{
    (void)in_sizes; (void)n_in; (void)out_size; (void)ws_size;
    const float* x      = (const float*)d_in[0];
    const float* log_dt = (const float*)d_in[1];
    const float* A_re   = (const float*)d_in[2];
    const float* A_im   = (const float*)d_in[3];
    const float* C_re   = (const float*)d_in[4];
    const float* C_im   = (const float*)d_in[5];
    const float* D_skip = (const float*)d_in[6];
    const float* W_out  = (const float*)d_in[7];
    const float* b_out  = (const float*)d_in[8];
    const float* g1     = (const float*)d_in[9];
    const float* beta1  = (const float*)d_in[10];
    const float* g2     = (const float*)d_in[11];
    const float* beta2  = (const float*)d_in[12];
    const float* W1     = (const float*)d_in[13];
    const float* bc1    = (const float*)d_in[14];
    const float* W2     = (const float*)d_in[15];
    const float* bc2    = (const float*)d_in[16];
    float* out = (float*)d_out;

    // workspace: P 512K | hole | Toep 4M | weights 2M | r1/r2/r3 | Pstats | c1 c2 | Pstats2
    char*   wsb    = (char*)d_ws;
    float*  P      = (float*)wsb;
    u16*    Toep   = (u16*)(wsb + 4 * HN * 4 + 512 * 64 * 4);
    u16*    Wobf   = Toep + 512 * 4096;
    u16*    W1bf   = Wobf + 1024 * 512;
    u16*    W2bf   = W1bf + 512 * 512;
    u16*    r1     = W2bf + 512 * 512;   // XT -> h1_bf
    u16*    r2     = r1 + BLH;           // YT -> z2_bf
    u16*    r3     = r2 + BLH;           // x1pre_bf
    float2* Pstats = (float2*)(r3 + BLH);
    float*  c1     = (float*)(Pstats + (size_t)M_DIM * 4);
    float*  c2     = c1 + 512;
    float2* Pstats2 = (float2*)(c2 + 512);

    setup_kernel<<<9472, 256, 0, stream>>>(x, W_out, W1, W2, log_dt, A_re, A_im,
                                           C_re, C_im, g1, beta1,
                                           r1, Wobf, W1bf, W2bf, P, Toep, c1, c2);
    ssm_chunk_kernel<<<dim3(H_DIM, 2), 256, 0, stream>>>(r1, P, Toep, D_skip, r2);
    gemm1_glu_kernel<<<dim3(M_DIM / 128, 4), 512, 0, stream>>>(r2, Wobf, b_out, x, r3, Pstats);
    gemm_relu_kernel<<<dim3(M_DIM / 128, 4), 512, 0, stream>>>(r3, W1bf, bc1, Pstats, c1, c2, r1);
    gemm2_tile_kernel<<<dim3(M_DIM / 128, 4), 512, 0, stream>>>(r1, W2bf, bc2, r3, Pstats, g1, beta1, r2, Pstats2);
    ln2_finish_kernel<<<M_DIM / 4, 256, 0, stream>>>(r2, Pstats2, g2, beta2, out);
}

// Round 9
// 231.909 us; speedup vs baseline: 1.0614x; 1.0111x over previous
//
#include <hip/hip_runtime.h>
#include <cstddef>
#include <cstdint>

#define B_DIM 8
#define L_DIM 2048
#define H_DIM 512
#define N_DIM 64
#define HN (H_DIM * N_DIM)          // 32768
#define BLH (B_DIM * L_DIM * H_DIM) // 8388608
#define M_DIM (B_DIM * L_DIM)       // 16384

typedef unsigned short u16;
typedef short bf16x8 __attribute__((ext_vector_type(8)));
typedef float floatx4 __attribute__((ext_vector_type(4)));

__device__ __forceinline__ float sigmoidf_(float v) {
    return 1.0f / (1.0f + __expf(-v));
}

// jax.nn.gelu default: approximate=True (tanh form)
__device__ __forceinline__ float gelu_tanh_(float x) {
    float x3 = x * x * x;
    float z = 0.7978845608028654f * fmaf(0.044715f, x3, x);
    float e = __expf(-2.0f * fabsf(z));
    float th = (1.0f - e) / (1.0f + e);
    th = copysignf(th, z);
    return 0.5f * x * (1.0f + th);
}

__device__ __forceinline__ u16 f2b(float f) {
    unsigned u = __float_as_uint(f);
    unsigned r = (u + 0x7fffu + ((u >> 16) & 1u)) >> 16;
    return (u16)r;
}
__device__ __forceinline__ float b2f(u16 u) {
    return __uint_as_float(((unsigned)u) << 16);
}
__device__ __forceinline__ void unpack2(unsigned u, float& a, float& b) {
    a = __uint_as_float(u << 16);
    b = __uint_as_float(u & 0xffff0000u);
}
__device__ __forceinline__ unsigned pack2(float a, float b) {
    return (unsigned)f2b(a) | ((unsigned)f2b(b) << 16);
}

// complex helpers
__device__ __forceinline__ void csq(float& r, float& i) {
    float nr = r * r - i * i;
    i = 2.0f * r * i;
    r = nr;
}

// ---------------------------------------------------------------------------
// 0) SETUP (one launch, block-partitioned):
//    [0,8192)     xtrans: x (B,L,H) fp32 -> XT (B,H,L) bf16
//    [8192,9216)  weight casts: Wo->bf16, W1*g1->bf16 (LN1 fold), W2->bf16
//    [9216,9344)  SSM params P + Ktab(LDS) + Toeplitz fill
//    [9344,9472)  LN1-fold column sums: c1[f]=sum_n W1[f][n]g1[n], c2=..beta1
// ---------------------------------------------------------------------------
__global__ __launch_bounds__(256) void setup_kernel(
    const float* __restrict__ x, const float* __restrict__ W_out,
    const float* __restrict__ W1, const float* __restrict__ W2,
    const float* __restrict__ log_dt, const float* __restrict__ A_re,
    const float* __restrict__ A_im, const float* __restrict__ C_re,
    const float* __restrict__ C_im, const float* __restrict__ g1,
    const float* __restrict__ beta1,
    u16* __restrict__ XT, u16* __restrict__ Wobf, u16* __restrict__ W1gbf,
    u16* __restrict__ W2bf, float* __restrict__ P, u16* __restrict__ Toep_bf,
    float* __restrict__ c1, float* __restrict__ c2)
{
    __shared__ float tile[32][33];
    __shared__ float ktab_s[4][64];
    const int bid = blockIdx.x;
    const int t   = threadIdx.x;

    if (bid < 8192) {
        // ---- xtrans
        int b  = bid >> 10;
        int hy = (bid >> 6) & 15;
        int lx = bid & 63;
        int l0 = lx * 32, h0 = hy * 32;
        int tx = t & 31, ty = t >> 5;
        #pragma unroll
        for (int r = 0; r < 4; ++r)
            tile[ty + r * 8][tx] = x[((size_t)b * L_DIM + l0 + ty + r * 8) * H_DIM + h0 + tx];
        __syncthreads();
        #pragma unroll
        for (int r = 0; r < 4; ++r)
            XT[(((size_t)b * H_DIM + h0 + ty + r * 8) << 11) + l0 + tx] = f2b(tile[tx][ty + r * 8]);
    } else if (bid < 9216) {
        // ---- weight casts
        int off = bid - 8192;
        if (off < 512) {
            int i = off * 256 + t;
            float4 v = *(const float4*)(W_out + (size_t)i * 4);
            uint2 p; p.x = pack2(v.x, v.y); p.y = pack2(v.z, v.w);
            *(uint2*)(Wobf + (size_t)i * 4) = p;
        } else if (off < 768) {
            int i = (off - 512) * 256 + t;
            float4 v = *(const float4*)(W1 + (size_t)i * 4);
            int n = (i * 4) & 511;
            float4 g = *(const float4*)(g1 + n);
            uint2 p; p.x = pack2(v.x * g.x, v.y * g.y);
            p.y = pack2(v.z * g.z, v.w * g.w);
            *(uint2*)(W1gbf + (size_t)i * 4) = p;
        } else {
            int i = (off - 768) * 256 + t;
            float4 v = *(const float4*)(W2 + (size_t)i * 4);
            uint2 p; p.x = pack2(v.x, v.y); p.y = pack2(v.z, v.w);
            *(uint2*)(W2bf + (size_t)i * 4) = p;
        }
    } else if (bid < 9344) {
        // ---- SSM params + Ktab + Toeplitz
        const int wv = t >> 6, lane = t & 63;
        const int i = (bid - 9216) * 256 + t;
        const int h = i >> 6;
        float dt = expf(log_dt[h]);
        float Ar = A_re[i], Ai = A_im[i];
        float ar = dt * Ar, ai = dt * Ai;
        float e = expf(ar);
        float wr = e * cosf(ai);
        float wi = e * sinf(ai);
        float em1r = wr - 1.0f, em1i = wi;
        float inv = 1.0f / fmaf(Ar, Ar, Ai * Ai);
        float qr = fmaf(em1r, Ar, em1i * Ai) * inv;
        float qi = fmaf(em1i, Ar, -(em1r * Ai)) * inv;
        float Cr = C_re[i], Ci = C_im[i];
        float c2r = 2.0f * (Cr * qr - Ci * qi);
        float c2i = 2.0f * (Cr * qi + Ci * qr);
        P[i]          = wr;
        P[HN + i]     = wi;
        P[2 * HN + i] = c2r;
        P[3 * HN + i] = c2i;

        float pr = 1.0f, pi = 0.0f;
        for (int tau = 0; tau < 64; ++tau) {
            float term = c2r * pr - c2i * pi;
            #pragma unroll
            for (int m = 32; m > 0; m >>= 1) term += __shfl_xor(term, m, 64);
            if (lane == 0) ktab_s[wv][tau] = term;
            float nr = pr * wr - pi * wi, ni = pr * wi + pi * wr;
            pr = nr; pi = ni;
        }
        __syncthreads();

        const int h0 = (bid - 9216) * 4;
        #pragma unroll
        for (int r = 0; r < 8; ++r) {
            int c = t + r * 256;
            int hh = c >> 9, rem = c & 511;
            int tt = rem >> 3, j0 = (rem & 7) * 8;
            u16 vv[8];
            #pragma unroll
            for (int jj = 0; jj < 8; ++jj) {
                int j = j0 + jj;
                vv[jj] = (j <= tt) ? f2b(ktab_s[hh][tt - j]) : (u16)0;
            }
            *(uint4*)&Toep_bf[((size_t)(h0 + hh) << 12) + (tt << 6) + j0] = *(uint4*)vv;
        }
    } else {
        // ---- LN1-fold column sums over n for W1 row f
        int f = (bid - 9344) * 4 + (t >> 6);
        int lane = t & 63;
        int n = lane * 8;
        float4 w0 = *(const float4*)(W1 + (size_t)f * 512 + n);
        float4 w1v = *(const float4*)(W1 + (size_t)f * 512 + n + 4);
        float4 ga = *(const float4*)(g1 + n);
        float4 gb = *(const float4*)(g1 + n + 4);
        float4 b0 = *(const float4*)(beta1 + n);
        float4 b1 = *(const float4*)(beta1 + n + 4);
        float s1 = w0.x * ga.x + w0.y * ga.y + w0.z * ga.z + w0.w * ga.w
                 + w1v.x * gb.x + w1v.y * gb.y + w1v.z * gb.z + w1v.w * gb.w;
        float s2 = w0.x * b0.x + w0.y * b0.y + w0.z * b0.z + w0.w * b0.w
                 + w1v.x * b1.x + w1v.y * b1.y + w1v.z * b1.z + w1v.w * b1.w;
        #pragma unroll
        for (int m = 32; m > 0; m >>= 1) {
            s1 += __shfl_xor(s1, m, 64);
            s2 += __shfl_xor(s2, m, 64);
        }
        if (lane == 0) { c1[f] = s1; c2[f] = s2; }
    }
}

// ---------------------------------------------------------------------------
// 3) Chunked SSM via MFMA. One workgroup = (h, half of b). T=64, 32 chunks.
// ---------------------------------------------------------------------------
__global__ __launch_bounds__(256) void ssm_chunk_kernel(
    const u16* __restrict__ XT, const float* __restrict__ P,
    const u16* __restrict__ Toep_bf, const float* __restrict__ D_skip,
    u16* __restrict__ YT)
{
    __shared__ u16 U[128 * 72];      // [ncol][j], pad 72
    __shared__ u16 S[128 * 136];     // [ncol][2n], pad 136
    __shared__ u16 EVT[13312];       // union: E[128*72]=9216 | Toep[64*72]=4608 + V[64*136]=8704
    u16* E  = EVT;
    u16* Tp = EVT;
    u16* V  = EVT + 4608;

    const int h    = blockIdx.x;
    const int b0   = blockIdx.y * 4;
    const int t    = threadIdx.x;
    const int lane = t & 63;
    const int wv   = t >> 6;
    const int lm   = lane & 15, lq = lane >> 4;

    const int pidx = (h << 6) + lane;
    const float wr  = P[pidx],          wi  = P[HN + pidx];
    const float c2r = P[2 * HN + pidx], c2i = P[3 * HN + pidx];

    // stage U: 128 rows x 64 bf16, 16B chunks (coalesced), padded LDS rows
    #pragma unroll
    for (int r = 0; r < 4; ++r) {
        int idx = t + r * 256;
        int row = idx >> 3, ch = idx & 7;
        const u16* gp = XT + (((size_t)(b0 + (row >> 5)) * H_DIM + h) << 11)
                           + ((row & 31) << 6) + (ch << 3);
        *(uint4*)&U[row * 72 + ch * 8] = *(const uint4*)gp;
    }

    // base power w^(16*wv) for this wave
    float bwr, bwi;
    {
        float g16r = wr, g16i = wi;
        csq(g16r, g16i); csq(g16r, g16i); csq(g16r, g16i); csq(g16r, g16i); // w^16
        if (wv == 0)      { bwr = 1.0f; bwi = 0.0f; }
        else if (wv == 1) { bwr = g16r; bwi = g16i; }
        else if (wv == 2) { bwr = g16r; bwi = g16i; csq(bwr, bwi); }
        else {
            float g32r = g16r, g32i = g16i; csq(g32r, g32i);
            bwr = g32r * g16r - g32i * g16i;
            bwi = g32r * g16i + g32i * g16r;
        }
    }

    // fill E: E[2n][j]=Re(w^(63-j)), E[2n+1][j]=Im(w^(63-j))
    {
        float pr = bwr, pi = bwi;
        #pragma unroll
        for (int jk = 0; jk < 16; ++jk) {
            int k = (wv << 4) + jk;
            int j = 63 - k;
            E[(2 * lane) * 72 + j]     = f2b(pr);
            E[(2 * lane + 1) * 72 + j] = f2b(pi);
            float nr = pr * wr - pi * wi, ni = pr * wi + pi * wr;
            pr = nr; pi = ni;
        }
    }
    __syncthreads();

    // Phase A
    {
        const int wm = wv >> 1, wn = wv & 1;
        floatx4 acc[4][4] = {};
        #pragma unroll
        for (int ks = 0; ks < 2; ++ks) {
            bf16x8 af[4], bfv[4];
            #pragma unroll
            for (int i = 0; i < 4; ++i)
                af[i] = *(const bf16x8*)&E[(wm * 64 + i * 16 + lm) * 72 + ks * 32 + lq * 8];
            #pragma unroll
            for (int j = 0; j < 4; ++j)
                bfv[j] = *(const bf16x8*)&U[(wn * 64 + j * 16 + lm) * 72 + ks * 32 + lq * 8];
            #pragma unroll
            for (int i = 0; i < 4; ++i) {
                #pragma unroll
                for (int j = 0; j < 4; ++j)
                    acc[i][j] = __builtin_amdgcn_mfma_f32_16x16x32_bf16(af[i], bfv[j], acc[i][j], 0, 0, 0);
            }
        }
        #pragma unroll
        for (int i = 0; i < 4; ++i) {
            #pragma unroll
            for (int j = 0; j < 4; ++j) {
                int ncol = wn * 64 + j * 16 + lm;
                int m0   = wm * 64 + i * 16 + lq * 4;
                u16 pk[4];
                #pragma unroll
                for (int r = 0; r < 4; ++r) pk[r] = f2b(acc[i][j][r]);
                *(uint2*)&S[ncol * 136 + m0] = *(uint2*)pk;
            }
        }
    }
    __syncthreads();

    // fill V + stage Toep + chunk scan
    {
        float pr = bwr, pi = bwi;
        {
            float nr = pr * wr - pi * wi, ni = pr * wi + pi * wr;
            pr = nr; pi = ni;
        }
        #pragma unroll
        for (int jk = 1; jk <= 16; ++jk) {
            int tr = (wv << 4) + jk - 1;
            float qr = c2r * pr - c2i * pi;
            float qi = c2r * pi + c2i * pr;
            V[tr * 136 + 2 * lane]     = f2b(qr);
            V[tr * 136 + 2 * lane + 1] = f2b(-qi);
            float nr = pr * wr - pi * wi, ni = pr * wi + pi * wr;
            pr = nr; pi = ni;
        }
        #pragma unroll
        for (int r = 0; r < 2; ++r) {
            int idx = t + r * 256;
            int row = idx >> 3, ch = idx & 7;
            *(uint4*)&Tp[row * 72 + ch * 8] =
                *(const uint4*)&Toep_bf[((size_t)h << 12) + (row << 6) + (ch << 3)];
        }
        float wTr = wr, wTi = wi;
        csq(wTr, wTi); csq(wTr, wTi); csq(wTr, wTi);
        csq(wTr, wTi); csq(wTr, wTi); csq(wTr, wTi);   // w^64
        float Sr = 0.0f, Si = 0.0f;
        const int n2 = lane * 2;
        for (int c = 0; c < 32; ++c) {
            int base = (wv * 32 + c) * 136 + n2;
            unsigned lv = *(unsigned*)&S[base];
            float lr, li;
            unpack2(lv, lr, li);
            *(unsigned*)&S[base] = pack2(Sr, Si);
            float nSr = wTr * Sr - wTi * Si + lr;
            Si = wTr * Si + wTi * Sr + li;
            Sr = nSr;
        }
    }
    __syncthreads();

    // Phase C
    {
        const float Dh = D_skip[h];
        floatx4 acc[4][2] = {};
        #pragma unroll
        for (int ks = 0; ks < 6; ++ks) {
            bf16x8 af[4], bfv[2];
            if (ks < 2) {
                #pragma unroll
                for (int i = 0; i < 4; ++i)
                    af[i] = *(const bf16x8*)&Tp[(i * 16 + lm) * 72 + ks * 32 + lq * 8];
                #pragma unroll
                for (int j = 0; j < 2; ++j)
                    bfv[j] = *(const bf16x8*)&U[(wv * 32 + j * 16 + lm) * 72 + ks * 32 + lq * 8];
            } else {
                #pragma unroll
                for (int i = 0; i < 4; ++i)
                    af[i] = *(const bf16x8*)&V[(i * 16 + lm) * 136 + (ks - 2) * 32 + lq * 8];
                #pragma unroll
                for (int j = 0; j < 2; ++j)
                    bfv[j] = *(const bf16x8*)&S[(wv * 32 + j * 16 + lm) * 136 + (ks - 2) * 32 + lq * 8];
            }
            #pragma unroll
            for (int i = 0; i < 4; ++i) {
                #pragma unroll
                for (int j = 0; j < 2; ++j)
                    acc[i][j] = __builtin_amdgcn_mfma_f32_16x16x32_bf16(af[i], bfv[j], acc[i][j], 0, 0, 0);
            }
        }
        #pragma unroll
        for (int j = 0; j < 2; ++j) {
            int ncol = wv * 32 + j * 16 + lm;
            int bloc = ncol >> 5, c = ncol & 31;
            size_t gbase = (((size_t)(b0 + bloc) * H_DIM + h) << 11) + (c << 6);
            #pragma unroll
            for (int i = 0; i < 4; ++i) {
                int t0 = i * 16 + lq * 4;
                u16 upk[4];
                *(uint2*)upk = *(const uint2*)&U[ncol * 72 + t0];
                u16 opk[4];
                #pragma unroll
                for (int r = 0; r < 4; ++r) {
                    float uvv = b2f(upk[r]);
                    float yv = gelu_tanh_(fmaf(Dh, uvv, acc[i][j][r]));
                    opk[r] = f2b(yv);
                }
                *(uint2*)&YT[gbase + t0] = *(uint2*)opk;
            }
        }
    }
}

// ---------------------------------------------------------------------------
// stage a 128x32 bf16 tile into LDS via global_load_lds, 512 threads.
// LDS dest LINEAR; bank-swizzle via permuted GLOBAL source chunk
// (chunk' = chunk ^ ((row>>1)&3)); readers XOR the same way.
// ---------------------------------------------------------------------------
__device__ __forceinline__ void stage_tile_512(
    const u16* __restrict__ g, u16* lds, int row0, int k0)
{
    const int t = threadIdx.x;           // 0..511, one 16B chunk each
    const int row  = t >> 2;             // 0..127
    const int csrc = (t & 3) ^ ((t >> 3) & 3);
    const u16* gp = g + (size_t)(row0 + row) * 512 + k0 + csrc * 8;
    __builtin_amdgcn_global_load_lds(
        (const __attribute__((address_space(1))) unsigned int*)gp,
        (__attribute__((address_space(3))) unsigned int*)(lds + (size_t)t * 8),
        16, 0, 0);
}

// stage a 128x64 bf16 tile (BK=64) into LDS, 512 threads x 2 chunks.
// Row = 8 chunks of 16B; bank = chunk-only at 128B row stride, so swizzle
// chunk' = chunk ^ (row&7) on the GLOBAL source; readers XOR identically.
// Each thread issues exactly 2 global_load_lds (vmcnt accounting relies on it).
__device__ __forceinline__ void stage_tile64_512(
    const u16* __restrict__ g, u16* lds, int row0, int k0)
{
    const int t = threadIdx.x;
    #pragma unroll
    for (int r = 0; r < 2; ++r) {
        int c   = t + r * 512;           // chunk id 0..1023
        int row = c >> 3, cc = c & 7;
        int csrc = cc ^ (row & 7);
        const u16* gp = g + (size_t)(row0 + row) * 512 + k0 + csrc * 8;
        __builtin_amdgcn_global_load_lds(
            (const __attribute__((address_space(1))) unsigned int*)gp,
            (__attribute__((address_space(3))) unsigned int*)(lds + (size_t)c * 8),
            16, 0, 0);
    }
}

// A-tile from YT (B,H,L): thread reads 8 consecutive l for one h(=k), then
// transposes into As[l][k] via 8 offset-immediate ds_write_b16.
// Swizzle on chunk: c_store = kc ^ ((row>>3)&3)  (row>>3 == lc here).
__device__ __forceinline__ uint4 ldA_yt(
    const u16* __restrict__ YT, int b, int l0, int k0)
{
    const int k  = threadIdx.x >> 4;
    const int lc = threadIdx.x & 15;
    return *(const uint4*)(YT + (((size_t)(b * 512 + k0 + k)) << 11) + l0 + lc * 8);
}
__device__ __forceinline__ void dswA(u16* lds, uint4 av)
{
    const int k  = threadIdx.x >> 4;
    const int lc = threadIdx.x & 15;
    u16* p = lds + (lc * 8) * 32 + (((k >> 3) ^ (lc & 3)) << 3) + (k & 7);
    const u16* s = (const u16*)&av;
    #pragma unroll
    for (int j = 0; j < 8; ++j) p[j * 32] = s[j];
}

// ---------------------------------------------------------------------------
// 5) GEMM1 + GLU + residual (dual-B) reading A DIRECTLY from YT (ytrans
//    eliminated), plus LN1 row-stats (sum, sumsq) side-output per n0-block.
//    512 threads (8 waves, 2m x 4n), double-buffered 2-phase pipeline.
// ---------------------------------------------------------------------------
__global__ __launch_bounds__(512) void gemm1_glu_kernel(
    const u16* __restrict__ YT, const u16* __restrict__ Wo,
    const float* __restrict__ bo, const float* __restrict__ x,
    u16* __restrict__ out, float2* __restrict__ Pstats)
{
    __shared__ u16 As[2][128 * 32];
    __shared__ u16 Ba[2][128 * 32];
    __shared__ u16 Bg[2][128 * 32];
    __shared__ float2 red1[128][4];
    const int t    = threadIdx.x;
    const int lane = t & 63;
    const int wv   = t >> 6;             // 0..7
    const int wm   = wv >> 2, wn = wv & 3;
    const int lm   = lane & 15, lq = lane >> 4;
    const int sw   = (lq ^ ((lm >> 1) & 3)) * 8;   // B-side read swizzle
    const int m0   = blockIdx.x * 128, n0 = blockIdx.y * 128;
    const int b    = m0 >> 11;
    const int l0   = m0 & 2047;
    floatx4 accA[4][2] = {};
    floatx4 accG[4][2] = {};

    // A-side read swizzle per i (row>>3 bits reduce to lane bits)
    int swA[4];
    #pragma unroll
    for (int i = 0; i < 4; ++i)
        swA[i] = (lq ^ ((i * 2 + (lm >> 3)) & 3)) * 8;

    // prologue: tile 0
    uint4 av = ldA_yt(YT, b, l0, 0);
    stage_tile_512(Wo, Ba[0], n0, 0);
    stage_tile_512(Wo, Bg[0], 512 + n0, 0);
    dswA(As[0], av);
    __syncthreads();

    int cur = 0;
    for (int k0 = 32; k0 < 512; k0 += 32) {
        const int nx = cur ^ 1;
        uint4 avn = ldA_yt(YT, b, l0, k0);            // issue early (T14)
        stage_tile_512(Wo, Ba[nx], n0, k0);
        stage_tile_512(Wo, Bg[nx], 512 + n0, k0);

        bf16x8 af[4], ba[2], bg[2];
        #pragma unroll
        for (int i = 0; i < 4; ++i)
            af[i] = *(const bf16x8*)&As[cur][(wm * 64 + i * 16 + lm) * 32 + swA[i]];
        #pragma unroll
        for (int j = 0; j < 2; ++j) {
            ba[j] = *(const bf16x8*)&Ba[cur][(wn * 32 + j * 16 + lm) * 32 + sw];
            bg[j] = *(const bf16x8*)&Bg[cur][(wn * 32 + j * 16 + lm) * 32 + sw];
        }
        #pragma unroll
        for (int i = 0; i < 4; ++i) {
            #pragma unroll
            for (int j = 0; j < 2; ++j) {
                accA[i][j] = __builtin_amdgcn_mfma_f32_16x16x32_bf16(af[i], ba[j], accA[i][j], 0, 0, 0);
                accG[i][j] = __builtin_amdgcn_mfma_f32_16x16x32_bf16(af[i], bg[j], accG[i][j], 0, 0, 0);
            }
        }
        dswA(As[nx], avn);                            // write late, under MFMA-covered latency
        __syncthreads();
        cur = nx;
    }
    // final K-tile (no prefetch)
    {
        bf16x8 af[4], ba[2], bg[2];
        #pragma unroll
        for (int i = 0; i < 4; ++i)
            af[i] = *(const bf16x8*)&As[cur][(wm * 64 + i * 16 + lm) * 32 + swA[i]];
        #pragma unroll
        for (int j = 0; j < 2; ++j) {
            ba[j] = *(const bf16x8*)&Ba[cur][(wn * 32 + j * 16 + lm) * 32 + sw];
            bg[j] = *(const bf16x8*)&Bg[cur][(wn * 32 + j * 16 + lm) * 32 + sw];
        }
        #pragma unroll
        for (int i = 0; i < 4; ++i) {
            #pragma unroll
            for (int j = 0; j < 2; ++j) {
                accA[i][j] = __builtin_amdgcn_mfma_f32_16x16x32_bf16(af[i], ba[j], accA[i][j], 0, 0, 0);
                accG[i][j] = __builtin_amdgcn_mfma_f32_16x16x32_bf16(af[i], bg[j], accG[i][j], 0, 0, 0);
            }
        }
    }

    // epilogue: GLU + residual, accumulate LN1 row partials
    float bav[2], bgv[2];
    #pragma unroll
    for (int j = 0; j < 2; ++j) {
        int n = n0 + wn * 32 + j * 16 + lm;
        bav[j] = bo[n]; bgv[j] = bo[512 + n];
    }
    #pragma unroll
    for (int i = 0; i < 4; ++i) {
        #pragma unroll
        for (int r = 0; r < 4; ++r) {
            int row = wm * 64 + i * 16 + lq * 4 + r;
            int m = m0 + row;
            float s = 0.0f, sq = 0.0f;
            #pragma unroll
            for (int j = 0; j < 2; ++j) {
                int n = n0 + wn * 32 + j * 16 + lm;
                float a_ = accA[i][j][r] + bav[j];
                float g_ = accG[i][j][r] + bgv[j];
                float xv = x[(size_t)m * 512 + n];
                float ov = fmaf(a_, sigmoidf_(g_), xv);
                out[(size_t)m * 512 + n] = f2b(ov);
                s += ov; sq = fmaf(ov, ov, sq);
            }
            #pragma unroll
            for (int msk = 1; msk < 16; msk <<= 1) {
                s  += __shfl_xor(s, msk, 64);
                sq += __shfl_xor(sq, msk, 64);
            }
            if (lm == 0) { float2 p; p.x = s; p.y = sq; red1[row][wn] = p; }
        }
    }
    __syncthreads();
    if (t < 128) {
        float s = 0.0f, sq = 0.0f;
        #pragma unroll
        for (int w = 0; w < 4; ++w) { float2 p = red1[t][w]; s += p.x; sq += p.y; }
        float2 o; o.x = s; o.y = sq;
        Pstats[(size_t)(m0 + t) * 4 + blockIdx.y] = o;
    }
}

// ---------------------------------------------------------------------------
// 6) GEMM (W1*g1 folded) + LN1 epilogue + ReLU.  BK=64, double-buffered with
//    COUNTED vmcnt (T4): tile k+2 issued at end of iter k, waited at top of
//    iter k+2 -> ~1.5 iterations of latency cover (vs same-iter drain).
//    Raw s_barrier pair per iter; sched_barrier(0) pins ds_reads (rule 18).
// ---------------------------------------------------------------------------
__global__ __launch_bounds__(512, 4) void gemm_relu_kernel(
    const u16* __restrict__ A, const u16* __restrict__ Bw,
    const float* __restrict__ bias, const float2* __restrict__ Pstats,
    const float* __restrict__ c1, const float* __restrict__ c2,
    u16* __restrict__ C)
{
    __shared__ u16 As[2][128 * 64];
    __shared__ u16 Bs[2][128 * 64];
    __shared__ float musig[128][2];
    const int t    = threadIdx.x;
    const int lane = t & 63;
    const int wv   = t >> 6;
    const int wm   = wv >> 2, wn = wv & 3;
    const int lm   = lane & 15, lq = lane >> 4;
    const int kc0  = (lq ^ (lm & 7)) * 8;          // ks=0 swizzled chunk col
    const int kc1  = ((4 + lq) ^ (lm & 7)) * 8;    // ks=1
    const int m0   = blockIdx.x * 128, n0 = blockIdx.y * 128;
    floatx4 acc[4][2] = {};

    if (t < 128) {
        float s = 0.0f, sq = 0.0f;
        #pragma unroll
        for (int w = 0; w < 4; ++w) {
            float2 p = Pstats[(size_t)(m0 + t) * 4 + w];
            s += p.x; sq += p.y;
        }
        float mu  = s * (1.0f / 512.0f);
        float var = sq * (1.0f / 512.0f) - mu * mu;
        musig[t][0] = mu;
        musig[t][1] = rsqrtf(var + 1e-5f);
    }
    // drain musig's vector loads so the staged-load vmcnt accounting is exact
    asm volatile("s_waitcnt vmcnt(0)" ::: "memory");

    // prologue: tiles k0, k1 in flight (8 loads/thread outstanding)
    stage_tile64_512(A,  As[0], m0, 0);
    stage_tile64_512(Bw, Bs[0], n0, 0);
    stage_tile64_512(A,  As[1], m0, 64);
    stage_tile64_512(Bw, Bs[1], n0, 64);

    #pragma unroll 1
    for (int it = 0; it < 7; ++it) {
        // wait for THIS tile's 4 loads (next tile's 4 stay in flight)
        asm volatile("s_waitcnt vmcnt(4)" ::: "memory");
        __builtin_amdgcn_s_barrier();
        __builtin_amdgcn_sched_barrier(0);
        const int cur = it & 1;
        #pragma unroll
        for (int ks = 0; ks < 2; ++ks) {
            const int kc = ks ? kc1 : kc0;
            bf16x8 af[4], bfr[2];
            #pragma unroll
            for (int i = 0; i < 4; ++i)
                af[i] = *(const bf16x8*)&As[cur][(wm * 64 + i * 16 + lm) * 64 + kc];
            #pragma unroll
            for (int j = 0; j < 2; ++j)
                bfr[j] = *(const bf16x8*)&Bs[cur][(wn * 32 + j * 16 + lm) * 64 + kc];
            #pragma unroll
            for (int i = 0; i < 4; ++i) {
                #pragma unroll
                for (int j = 0; j < 2; ++j)
                    acc[i][j] = __builtin_amdgcn_mfma_f32_16x16x32_bf16(af[i], bfr[j], acc[i][j], 0, 0, 0);
            }
        }
        // all waves done reading buf[cur] (MFMAs consumed every ds_read)
        __builtin_amdgcn_s_barrier();
        __builtin_amdgcn_sched_barrier(0);
        if (it < 6) {
            stage_tile64_512(A,  As[cur], m0, (it + 2) * 64);
            stage_tile64_512(Bw, Bs[cur], n0, (it + 2) * 64);
        }
    }
    // peeled final tile (k7 in buf[1]); full drain
    asm volatile("s_waitcnt vmcnt(0)" ::: "memory");
    __builtin_amdgcn_s_barrier();
    __builtin_amdgcn_sched_barrier(0);
    #pragma unroll
    for (int ks = 0; ks < 2; ++ks) {
        const int kc = ks ? kc1 : kc0;
        bf16x8 af[4], bfr[2];
        #pragma unroll
        for (int i = 0; i < 4; ++i)
            af[i] = *(const bf16x8*)&As[1][(wm * 64 + i * 16 + lm) * 64 + kc];
        #pragma unroll
        for (int j = 0; j < 2; ++j)
            bfr[j] = *(const bf16x8*)&Bs[1][(wn * 32 + j * 16 + lm) * 64 + kc];
        #pragma unroll
        for (int i = 0; i < 4; ++i) {
            #pragma unroll
            for (int j = 0; j < 2; ++j)
                acc[i][j] = __builtin_amdgcn_mfma_f32_16x16x32_bf16(af[i], bfr[j], acc[i][j], 0, 0, 0);
        }
    }
    float c1v[2], c2v[2];
    #pragma unroll
    for (int j = 0; j < 2; ++j) {
        int n = n0 + wn * 32 + j * 16 + lm;
        c1v[j] = c1[n];
        c2v[j] = c2[n] + bias[n];
    }
    #pragma unroll
    for (int i = 0; i < 4; ++i) {
        #pragma unroll
        for (int r = 0; r < 4; ++r) {
            int row = wm * 64 + i * 16 + lq * 4 + r;
            float mu = musig[row][0], rs = musig[row][1];
            float nmr = -rs * mu;
            #pragma unroll
            for (int j = 0; j < 2; ++j) {
                int n = n0 + wn * 32 + j * 16 + lm;
                float v = fmaf(rs, acc[i][j][r], fmaf(nmr, c1v[j], c2v[j]));
                C[(size_t)(m0 + row) * 512 + n] = f2b(fmaxf(v, 0.0f));
            }
        }
    }
}

// ---------------------------------------------------------------------------
// 7) GEMM2 (128x128 tile) + LN1'd residual epilogue.  BK=64, counted-vmcnt
//    pipeline identical to gemm_relu.  Writes z bf16 + LN2 row-partials.
// ---------------------------------------------------------------------------
__global__ __launch_bounds__(512, 4) void gemm2_tile_kernel(
    const u16* __restrict__ A, const u16* __restrict__ Bw,
    const float* __restrict__ bias, const u16* __restrict__ res,
    const float2* __restrict__ Pstats,
    const float* __restrict__ g1, const float* __restrict__ beta1,
    u16* __restrict__ Z, float2* __restrict__ Pstats2)
{
    __shared__ u16 As[2][128 * 64];
    __shared__ u16 Bs[2][128 * 64];
    __shared__ float musig[128][2];
    __shared__ float2 red2[128][4];
    const int t    = threadIdx.x;
    const int lane = t & 63;
    const int wv   = t >> 6;
    const int wm   = wv >> 2, wn = wv & 3;
    const int lm   = lane & 15, lq = lane >> 4;
    const int kc0  = (lq ^ (lm & 7)) * 8;
    const int kc1  = ((4 + lq) ^ (lm & 7)) * 8;
    const int m0   = blockIdx.x * 128, n0 = blockIdx.y * 128;
    floatx4 acc[4][2] = {};

    if (t < 128) {
        float s = 0.0f, sq = 0.0f;
        #pragma unroll
        for (int w = 0; w < 4; ++w) {
            float2 p = Pstats[(size_t)(m0 + t) * 4 + w];
            s += p.x; sq += p.y;
        }
        float mu  = s * (1.0f / 512.0f);
        float var = sq * (1.0f / 512.0f) - mu * mu;
        musig[t][0] = mu;
        musig[t][1] = rsqrtf(var + 1e-5f);
    }
    asm volatile("s_waitcnt vmcnt(0)" ::: "memory");

    stage_tile64_512(A,  As[0], m0, 0);
    stage_tile64_512(Bw, Bs[0], n0, 0);
    stage_tile64_512(A,  As[1], m0, 64);
    stage_tile64_512(Bw, Bs[1], n0, 64);

    #pragma unroll 1
    for (int it = 0; it < 7; ++it) {
        asm volatile("s_waitcnt vmcnt(4)" ::: "memory");
        __builtin_amdgcn_s_barrier();
        __builtin_amdgcn_sched_barrier(0);
        const int cur = it & 1;
        #pragma unroll
        for (int ks = 0; ks < 2; ++ks) {
            const int kc = ks ? kc1 : kc0;
            bf16x8 af[4], bfr[2];
            #pragma unroll
            for (int i = 0; i < 4; ++i)
                af[i] = *(const bf16x8*)&As[cur][(wm * 64 + i * 16 + lm) * 64 + kc];
            #pragma unroll
            for (int j = 0; j < 2; ++j)
                bfr[j] = *(const bf16x8*)&Bs[cur][(wn * 32 + j * 16 + lm) * 64 + kc];
            #pragma unroll
            for (int i = 0; i < 4; ++i) {
                #pragma unroll
                for (int j = 0; j < 2; ++j)
                    acc[i][j] = __builtin_amdgcn_mfma_f32_16x16x32_bf16(af[i], bfr[j], acc[i][j], 0, 0, 0);
            }
        }
        __builtin_amdgcn_s_barrier();
        __builtin_amdgcn_sched_barrier(0);
        if (it < 6) {
            stage_tile64_512(A,  As[cur], m0, (it + 2) * 64);
            stage_tile64_512(Bw, Bs[cur], n0, (it + 2) * 64);
        }
    }
    asm volatile("s_waitcnt vmcnt(0)" ::: "memory");
    __builtin_amdgcn_s_barrier();
    __builtin_amdgcn_sched_barrier(0);
    #pragma unroll
    for (int ks = 0; ks < 2; ++ks) {
        const int kc = ks ? kc1 : kc0;
        bf16x8 af[4], bfr[2];
        #pragma unroll
        for (int i = 0; i < 4; ++i)
            af[i] = *(const bf16x8*)&As[1][(wm * 64 + i * 16 + lm) * 64 + kc];
        #pragma unroll
        for (int j = 0; j < 2; ++j)
            bfr[j] = *(const bf16x8*)&Bs[1][(wn * 32 + j * 16 + lm) * 64 + kc];
        #pragma unroll
        for (int i = 0; i < 4; ++i) {
            #pragma unroll
            for (int j = 0; j < 2; ++j)
                acc[i][j] = __builtin_amdgcn_mfma_f32_16x16x32_bf16(af[i], bfr[j], acc[i][j], 0, 0, 0);
        }
    }

    // epilogue: z = acc + bias + LN1(res); write z bf16; LN2 row partials
    float bv[2], gv1[2], bt1[2];
    #pragma unroll
    for (int j = 0; j < 2; ++j) {
        int n = n0 + wn * 32 + j * 16 + lm;
        bv[j]  = bias[n];
        gv1[j] = g1[n];
        bt1[j] = beta1[n];
    }
    #pragma unroll
    for (int i = 0; i < 4; ++i) {
        #pragma unroll
        for (int r = 0; r < 4; ++r) {
            int row = wm * 64 + i * 16 + lq * 4 + r;
            int m = m0 + row;
            float mu1 = musig[row][0], rs1 = musig[row][1];
            float s = 0.0f, sq = 0.0f;
            #pragma unroll
            for (int j = 0; j < 2; ++j) {
                int n = n0 + wn * 32 + j * 16 + lm;
                float zl = fmaf((b2f(res[(size_t)m * 512 + n]) - mu1) * rs1, gv1[j], bt1[j]);
                float v = acc[i][j][r] + bv[j] + zl;
                Z[(size_t)m * 512 + n] = f2b(v);
                s += v; sq = fmaf(v, v, sq);
            }
            #pragma unroll
            for (int msk = 1; msk < 16; msk <<= 1) {
                s  += __shfl_xor(s, msk, 64);
                sq += __shfl_xor(sq, msk, 64);
            }
            if (lm == 0) { float2 p; p.x = s; p.y = sq; red2[row][wn] = p; }
        }
    }
    __syncthreads();
    if (t < 128) {
        float s = 0.0f, sq = 0.0f;
        #pragma unroll
        for (int w = 0; w < 4; ++w) { float2 p = red2[t][w]; s += p.x; sq += p.y; }
        float2 o; o.x = s; o.y = sq;
        Pstats2[(size_t)(m0 + t) * 4 + blockIdx.y] = o;
    }
}

// ---------------------------------------------------------------------------
// 8) LN2 finish: out = (z - mu)*rs*g2 + b2, fp32. Memory-bound streaming.
// ---------------------------------------------------------------------------
__global__ __launch_bounds__(256) void ln2_finish_kernel(
    const u16* __restrict__ Z, const float2* __restrict__ Pstats2,
    const float* __restrict__ gamma, const float* __restrict__ beta,
    float* __restrict__ out)
{
    int w    = threadIdx.x >> 6;
    int lane = threadIdx.x & 63;
    size_t row  = (size_t)blockIdx.x * 4 + w;
    float s = 0.0f, sq = 0.0f;
    #pragma unroll
    for (int w4 = 0; w4 < 4; ++w4) {
        float2 p = Pstats2[row * 4 + w4];
        s += p.x; sq += p.y;
    }
    float mu  = s * (1.0f / 512.0f);
    float var = sq * (1.0f / 512.0f) - mu * mu;
    float rs  = rsqrtf(var + 1e-5f);
    size_t base = row * 512 + lane * 8;
    uint4 raw = *(const uint4*)(Z + base);
    float v[8];
    unpack2(raw.x, v[0], v[1]); unpack2(raw.y, v[2], v[3]);
    unpack2(raw.z, v[4], v[5]); unpack2(raw.w, v[6], v[7]);
    float g[8], bt[8];
    *(float4*)&g[0]  = *(const float4*)(gamma + lane * 8);
    *(float4*)&g[4]  = *(const float4*)(gamma + lane * 8 + 4);
    *(float4*)&bt[0] = *(const float4*)(beta + lane * 8);
    *(float4*)&bt[4] = *(const float4*)(beta + lane * 8 + 4);
    float o[8];
    #pragma unroll
    for (int i = 0; i < 8; ++i)
        o[i] = fmaf((v[i] - mu) * rs, g[i], bt[i]);
    *(float4*)(out + base)     = *(float4*)&o[0];
    *(float4*)(out + base + 4) = *(float4*)&o[4];
}

// ---------------------------------------------------------------------------
extern "C" void kernel_launch(void* const* d_in, const int* in_sizes, int n_in,
                              void* d_out, int out_size, void* d_ws, size_t ws_size,
                              hipStream_t stream)
{
    (void)in_sizes; (void)n_in; (void)out_size; (void)ws_size;
    const float* x      = (const float*)d_in[0];
    const float* log_dt = (const float*)d_in[1];
    const float* A_re   = (const float*)d_in[2];
    const float* A_im   = (const float*)d_in[3];
    const float* C_re   = (const float*)d_in[4];
    const float* C_im   = (const float*)d_in[5];
    const float* D_skip = (const float*)d_in[6];
    const float* W_out  = (const float*)d_in[7];
    const float* b_out  = (const float*)d_in[8];
    const float* g1     = (const float*)d_in[9];
    const float* beta1  = (const float*)d_in[10];
    const float* g2     = (const float*)d_in[11];
    const float* beta2  = (const float*)d_in[12];
    const float* W1     = (const float*)d_in[13];
    const float* bc1    = (const float*)d_in[14];
    const float* W2     = (const float*)d_in[15];
    const float* bc2    = (const float*)d_in[16];
    float* out = (float*)d_out;

    // workspace: P 512K | hole | Toep 4M | weights 2M | r1/r2/r3 | Pstats | c1 c2 | Pstats2
    char*   wsb    = (char*)d_ws;
    float*  P      = (float*)wsb;
    u16*    Toep   = (u16*)(wsb + 4 * HN * 4 + 512 * 64 * 4);
    u16*    Wobf   = Toep + 512 * 4096;
    u16*    W1bf   = Wobf + 1024 * 512;
    u16*    W2bf   = W1bf + 512 * 512;
    u16*    r1     = W2bf + 512 * 512;   // XT -> h1_bf
    u16*    r2     = r1 + BLH;           // YT -> z2_bf
    u16*    r3     = r2 + BLH;           // x1pre_bf
    float2* Pstats = (float2*)(r3 + BLH);
    float*  c1     = (float*)(Pstats + (size_t)M_DIM * 4);
    float*  c2     = c1 + 512;
    float2* Pstats2 = (float2*)(c2 + 512);

    setup_kernel<<<9472, 256, 0, stream>>>(x, W_out, W1, W2, log_dt, A_re, A_im,
                                           C_re, C_im, g1, beta1,
                                           r1, Wobf, W1bf, W2bf, P, Toep, c1, c2);
    ssm_chunk_kernel<<<dim3(H_DIM, 2), 256, 0, stream>>>(r1, P, Toep, D_skip, r2);
    gemm1_glu_kernel<<<dim3(M_DIM / 128, 4), 512, 0, stream>>>(r2, Wobf, b_out, x, r3, Pstats);
    gemm_relu_kernel<<<dim3(M_DIM / 128, 4), 512, 0, stream>>>(r3, W1bf, bc1, Pstats, c1, c2, r1);
    gemm2_tile_kernel<<<dim3(M_DIM / 128, 4), 512, 0, stream>>>(r1, W2bf, bc2, r3, Pstats, g1, beta1, r2, Pstats2);
    ln2_finish_kernel<<<M_DIM / 4, 256, 0, stream>>>(r2, Pstats2, g2, beta2, out);
}

// Round 10
// 230.672 us; speedup vs baseline: 1.0671x; 1.0054x over previous
//
#include <hip/hip_runtime.h>
#include <cstddef>
#include <cstdint>

#define B_DIM 8
#define L_DIM 2048
#define H_DIM 512
#define N_DIM 64
#define HN (H_DIM * N_DIM)          // 32768
#define BLH (B_DIM * L_DIM * H_DIM) // 8388608
#define M_DIM (B_DIM * L_DIM)       // 16384

typedef unsigned short u16;
typedef short bf16x8 __attribute__((ext_vector_type(8)));
typedef float floatx4 __attribute__((ext_vector_type(4)));

__device__ __forceinline__ float sigmoidf_(float v) {
    return 1.0f / (1.0f + __expf(-v));
}

// jax.nn.gelu default: approximate=True (tanh form)
__device__ __forceinline__ float gelu_tanh_(float x) {
    float x3 = x * x * x;
    float z = 0.7978845608028654f * fmaf(0.044715f, x3, x);
    float e = __expf(-2.0f * fabsf(z));
    float th = (1.0f - e) / (1.0f + e);
    th = copysignf(th, z);
    return 0.5f * x * (1.0f + th);
}

__device__ __forceinline__ u16 f2b(float f) {
    unsigned u = __float_as_uint(f);
    unsigned r = (u + 0x7fffu + ((u >> 16) & 1u)) >> 16;
    return (u16)r;
}
__device__ __forceinline__ float b2f(u16 u) {
    return __uint_as_float(((unsigned)u) << 16);
}
__device__ __forceinline__ void unpack2(unsigned u, float& a, float& b) {
    a = __uint_as_float(u << 16);
    b = __uint_as_float(u & 0xffff0000u);
}
__device__ __forceinline__ unsigned pack2(float a, float b) {
    return (unsigned)f2b(a) | ((unsigned)f2b(b) << 16);
}

// complex helpers
__device__ __forceinline__ void csq(float& r, float& i) {
    float nr = r * r - i * i;
    i = 2.0f * r * i;
    r = nr;
}

// ---------------------------------------------------------------------------
// 0) SETUP (one launch, block-partitioned):
//    [0,8192)     xtrans: x (B,L,H) fp32 -> XT (B,H,L) bf16
//    [8192,9216)  weight casts: Wo->bf16, W1*g1->bf16 (LN1 fold), W2->bf16
//    [9216,9344)  SSM params P + Ktab(LDS) + Toeplitz fill
//    [9344,9472)  LN1-fold column sums: c1[f]=sum_n W1[f][n]g1[n], c2=..beta1
// ---------------------------------------------------------------------------
__global__ __launch_bounds__(256) void setup_kernel(
    const float* __restrict__ x, const float* __restrict__ W_out,
    const float* __restrict__ W1, const float* __restrict__ W2,
    const float* __restrict__ log_dt, const float* __restrict__ A_re,
    const float* __restrict__ A_im, const float* __restrict__ C_re,
    const float* __restrict__ C_im, const float* __restrict__ g1,
    const float* __restrict__ beta1,
    u16* __restrict__ XT, u16* __restrict__ Wobf, u16* __restrict__ W1gbf,
    u16* __restrict__ W2bf, float* __restrict__ P, u16* __restrict__ Toep_bf,
    float* __restrict__ c1, float* __restrict__ c2)
{
    __shared__ float tile[32][33];
    __shared__ float ktab_s[4][64];
    const int bid = blockIdx.x;
    const int t   = threadIdx.x;

    if (bid < 8192) {
        // ---- xtrans
        int b  = bid >> 10;
        int hy = (bid >> 6) & 15;
        int lx = bid & 63;
        int l0 = lx * 32, h0 = hy * 32;
        int tx = t & 31, ty = t >> 5;
        #pragma unroll
        for (int r = 0; r < 4; ++r)
            tile[ty + r * 8][tx] = x[((size_t)b * L_DIM + l0 + ty + r * 8) * H_DIM + h0 + tx];
        __syncthreads();
        #pragma unroll
        for (int r = 0; r < 4; ++r)
            XT[(((size_t)b * H_DIM + h0 + ty + r * 8) << 11) + l0 + tx] = f2b(tile[tx][ty + r * 8]);
    } else if (bid < 9216) {
        // ---- weight casts
        int off = bid - 8192;
        if (off < 512) {
            int i = off * 256 + t;
            float4 v = *(const float4*)(W_out + (size_t)i * 4);
            uint2 p; p.x = pack2(v.x, v.y); p.y = pack2(v.z, v.w);
            *(uint2*)(Wobf + (size_t)i * 4) = p;
        } else if (off < 768) {
            int i = (off - 512) * 256 + t;
            float4 v = *(const float4*)(W1 + (size_t)i * 4);
            int n = (i * 4) & 511;
            float4 g = *(const float4*)(g1 + n);
            uint2 p; p.x = pack2(v.x * g.x, v.y * g.y);
            p.y = pack2(v.z * g.z, v.w * g.w);
            *(uint2*)(W1gbf + (size_t)i * 4) = p;
        } else {
            int i = (off - 768) * 256 + t;
            float4 v = *(const float4*)(W2 + (size_t)i * 4);
            uint2 p; p.x = pack2(v.x, v.y); p.y = pack2(v.z, v.w);
            *(uint2*)(W2bf + (size_t)i * 4) = p;
        }
    } else if (bid < 9344) {
        // ---- SSM params + Ktab + Toeplitz
        const int wv = t >> 6, lane = t & 63;
        const int i = (bid - 9216) * 256 + t;
        const int h = i >> 6;
        float dt = expf(log_dt[h]);
        float Ar = A_re[i], Ai = A_im[i];
        float ar = dt * Ar, ai = dt * Ai;
        float e = expf(ar);
        float wr = e * cosf(ai);
        float wi = e * sinf(ai);
        float em1r = wr - 1.0f, em1i = wi;
        float inv = 1.0f / fmaf(Ar, Ar, Ai * Ai);
        float qr = fmaf(em1r, Ar, em1i * Ai) * inv;
        float qi = fmaf(em1i, Ar, -(em1r * Ai)) * inv;
        float Cr = C_re[i], Ci = C_im[i];
        float c2r = 2.0f * (Cr * qr - Ci * qi);
        float c2i = 2.0f * (Cr * qi + Ci * qr);
        P[i]          = wr;
        P[HN + i]     = wi;
        P[2 * HN + i] = c2r;
        P[3 * HN + i] = c2i;

        float pr = 1.0f, pi = 0.0f;
        for (int tau = 0; tau < 64; ++tau) {
            float term = c2r * pr - c2i * pi;
            #pragma unroll
            for (int m = 32; m > 0; m >>= 1) term += __shfl_xor(term, m, 64);
            if (lane == 0) ktab_s[wv][tau] = term;
            float nr = pr * wr - pi * wi, ni = pr * wi + pi * wr;
            pr = nr; pi = ni;
        }
        __syncthreads();

        const int h0 = (bid - 9216) * 4;
        #pragma unroll
        for (int r = 0; r < 8; ++r) {
            int c = t + r * 256;
            int hh = c >> 9, rem = c & 511;
            int tt = rem >> 3, j0 = (rem & 7) * 8;
            u16 vv[8];
            #pragma unroll
            for (int jj = 0; jj < 8; ++jj) {
                int j = j0 + jj;
                vv[jj] = (j <= tt) ? f2b(ktab_s[hh][tt - j]) : (u16)0;
            }
            *(uint4*)&Toep_bf[((size_t)(h0 + hh) << 12) + (tt << 6) + j0] = *(uint4*)vv;
        }
    } else {
        // ---- LN1-fold column sums over n for W1 row f
        int f = (bid - 9344) * 4 + (t >> 6);
        int lane = t & 63;
        int n = lane * 8;
        float4 w0 = *(const float4*)(W1 + (size_t)f * 512 + n);
        float4 w1v = *(const float4*)(W1 + (size_t)f * 512 + n + 4);
        float4 ga = *(const float4*)(g1 + n);
        float4 gb = *(const float4*)(g1 + n + 4);
        float4 b0 = *(const float4*)(beta1 + n);
        float4 b1 = *(const float4*)(beta1 + n + 4);
        float s1 = w0.x * ga.x + w0.y * ga.y + w0.z * ga.z + w0.w * ga.w
                 + w1v.x * gb.x + w1v.y * gb.y + w1v.z * gb.z + w1v.w * gb.w;
        float s2 = w0.x * b0.x + w0.y * b0.y + w0.z * b0.z + w0.w * b0.w
                 + w1v.x * b1.x + w1v.y * b1.y + w1v.z * b1.z + w1v.w * b1.w;
        #pragma unroll
        for (int m = 32; m > 0; m >>= 1) {
            s1 += __shfl_xor(s1, m, 64);
            s2 += __shfl_xor(s2, m, 64);
        }
        if (lane == 0) { c1[f] = s1; c2[f] = s2; }
    }
}

// ---------------------------------------------------------------------------
// 3) Chunked SSM via MFMA. One workgroup = (h, half of b). T=64, 32 chunks.
// ---------------------------------------------------------------------------
__global__ __launch_bounds__(256) void ssm_chunk_kernel(
    const u16* __restrict__ XT, const float* __restrict__ P,
    const u16* __restrict__ Toep_bf, const float* __restrict__ D_skip,
    u16* __restrict__ YT)
{
    __shared__ u16 U[128 * 72];      // [ncol][j], pad 72
    __shared__ u16 S[128 * 136];     // [ncol][2n], pad 136
    __shared__ u16 EVT[13312];       // union: E[128*72]=9216 | Toep[64*72]=4608 + V[64*136]=8704
    u16* E  = EVT;
    u16* Tp = EVT;
    u16* V  = EVT + 4608;

    const int h    = blockIdx.x;
    const int b0   = blockIdx.y * 4;
    const int t    = threadIdx.x;
    const int lane = t & 63;
    const int wv   = t >> 6;
    const int lm   = lane & 15, lq = lane >> 4;

    const int pidx = (h << 6) + lane;
    const float wr  = P[pidx],          wi  = P[HN + pidx];
    const float c2r = P[2 * HN + pidx], c2i = P[3 * HN + pidx];

    // stage U: 128 rows x 64 bf16, 16B chunks (coalesced), padded LDS rows
    #pragma unroll
    for (int r = 0; r < 4; ++r) {
        int idx = t + r * 256;
        int row = idx >> 3, ch = idx & 7;
        const u16* gp = XT + (((size_t)(b0 + (row >> 5)) * H_DIM + h) << 11)
                           + ((row & 31) << 6) + (ch << 3);
        *(uint4*)&U[row * 72 + ch * 8] = *(const uint4*)gp;
    }

    // base power w^(16*wv) for this wave
    float bwr, bwi;
    {
        float g16r = wr, g16i = wi;
        csq(g16r, g16i); csq(g16r, g16i); csq(g16r, g16i); csq(g16r, g16i); // w^16
        if (wv == 0)      { bwr = 1.0f; bwi = 0.0f; }
        else if (wv == 1) { bwr = g16r; bwi = g16i; }
        else if (wv == 2) { bwr = g16r; bwi = g16i; csq(bwr, bwi); }
        else {
            float g32r = g16r, g32i = g16i; csq(g32r, g32i);
            bwr = g32r * g16r - g32i * g16i;
            bwi = g32r * g16i + g32i * g16r;
        }
    }

    // fill E: E[2n][j]=Re(w^(63-j)), E[2n+1][j]=Im(w^(63-j))
    {
        float pr = bwr, pi = bwi;
        #pragma unroll
        for (int jk = 0; jk < 16; ++jk) {
            int k = (wv << 4) + jk;
            int j = 63 - k;
            E[(2 * lane) * 72 + j]     = f2b(pr);
            E[(2 * lane + 1) * 72 + j] = f2b(pi);
            float nr = pr * wr - pi * wi, ni = pr * wi + pi * wr;
            pr = nr; pi = ni;
        }
    }
    __syncthreads();

    // Phase A
    {
        const int wm = wv >> 1, wn = wv & 1;
        floatx4 acc[4][4] = {};
        #pragma unroll
        for (int ks = 0; ks < 2; ++ks) {
            bf16x8 af[4], bfv[4];
            #pragma unroll
            for (int i = 0; i < 4; ++i)
                af[i] = *(const bf16x8*)&E[(wm * 64 + i * 16 + lm) * 72 + ks * 32 + lq * 8];
            #pragma unroll
            for (int j = 0; j < 4; ++j)
                bfv[j] = *(const bf16x8*)&U[(wn * 64 + j * 16 + lm) * 72 + ks * 32 + lq * 8];
            #pragma unroll
            for (int i = 0; i < 4; ++i) {
                #pragma unroll
                for (int j = 0; j < 4; ++j)
                    acc[i][j] = __builtin_amdgcn_mfma_f32_16x16x32_bf16(af[i], bfv[j], acc[i][j], 0, 0, 0);
            }
        }
        #pragma unroll
        for (int i = 0; i < 4; ++i) {
            #pragma unroll
            for (int j = 0; j < 4; ++j) {
                int ncol = wn * 64 + j * 16 + lm;
                int m0   = wm * 64 + i * 16 + lq * 4;
                u16 pk[4];
                #pragma unroll
                for (int r = 0; r < 4; ++r) pk[r] = f2b(acc[i][j][r]);
                *(uint2*)&S[ncol * 136 + m0] = *(uint2*)pk;
            }
        }
    }
    __syncthreads();

    // fill V + stage Toep + chunk scan
    {
        float pr = bwr, pi = bwi;
        {
            float nr = pr * wr - pi * wi, ni = pr * wi + pi * wr;
            pr = nr; pi = ni;
        }
        #pragma unroll
        for (int jk = 1; jk <= 16; ++jk) {
            int tr = (wv << 4) + jk - 1;
            float qr = c2r * pr - c2i * pi;
            float qi = c2r * pi + c2i * pr;
            V[tr * 136 + 2 * lane]     = f2b(qr);
            V[tr * 136 + 2 * lane + 1] = f2b(-qi);
            float nr = pr * wr - pi * wi, ni = pr * wi + pi * wr;
            pr = nr; pi = ni;
        }
        #pragma unroll
        for (int r = 0; r < 2; ++r) {
            int idx = t + r * 256;
            int row = idx >> 3, ch = idx & 7;
            *(uint4*)&Tp[row * 72 + ch * 8] =
                *(const uint4*)&Toep_bf[((size_t)h << 12) + (row << 6) + (ch << 3)];
        }
        float wTr = wr, wTi = wi;
        csq(wTr, wTi); csq(wTr, wTi); csq(wTr, wTi);
        csq(wTr, wTi); csq(wTr, wTi); csq(wTr, wTi);   // w^64
        float Sr = 0.0f, Si = 0.0f;
        const int n2 = lane * 2;
        for (int c = 0; c < 32; ++c) {
            int base = (wv * 32 + c) * 136 + n2;
            unsigned lv = *(unsigned*)&S[base];
            float lr, li;
            unpack2(lv, lr, li);
            *(unsigned*)&S[base] = pack2(Sr, Si);
            float nSr = wTr * Sr - wTi * Si + lr;
            Si = wTr * Si + wTi * Sr + li;
            Sr = nSr;
        }
    }
    __syncthreads();

    // Phase C
    {
        const float Dh = D_skip[h];
        floatx4 acc[4][2] = {};
        #pragma unroll
        for (int ks = 0; ks < 6; ++ks) {
            bf16x8 af[4], bfv[2];
            if (ks < 2) {
                #pragma unroll
                for (int i = 0; i < 4; ++i)
                    af[i] = *(const bf16x8*)&Tp[(i * 16 + lm) * 72 + ks * 32 + lq * 8];
                #pragma unroll
                for (int j = 0; j < 2; ++j)
                    bfv[j] = *(const bf16x8*)&U[(wv * 32 + j * 16 + lm) * 72 + ks * 32 + lq * 8];
            } else {
                #pragma unroll
                for (int i = 0; i < 4; ++i)
                    af[i] = *(const bf16x8*)&V[(i * 16 + lm) * 136 + (ks - 2) * 32 + lq * 8];
                #pragma unroll
                for (int j = 0; j < 2; ++j)
                    bfv[j] = *(const bf16x8*)&S[(wv * 32 + j * 16 + lm) * 136 + (ks - 2) * 32 + lq * 8];
            }
            #pragma unroll
            for (int i = 0; i < 4; ++i) {
                #pragma unroll
                for (int j = 0; j < 2; ++j)
                    acc[i][j] = __builtin_amdgcn_mfma_f32_16x16x32_bf16(af[i], bfv[j], acc[i][j], 0, 0, 0);
            }
        }
        #pragma unroll
        for (int j = 0; j < 2; ++j) {
            int ncol = wv * 32 + j * 16 + lm;
            int bloc = ncol >> 5, c = ncol & 31;
            size_t gbase = (((size_t)(b0 + bloc) * H_DIM + h) << 11) + (c << 6);
            #pragma unroll
            for (int i = 0; i < 4; ++i) {
                int t0 = i * 16 + lq * 4;
                u16 upk[4];
                *(uint2*)upk = *(const uint2*)&U[ncol * 72 + t0];
                u16 opk[4];
                #pragma unroll
                for (int r = 0; r < 4; ++r) {
                    float uvv = b2f(upk[r]);
                    float yv = gelu_tanh_(fmaf(Dh, uvv, acc[i][j][r]));
                    opk[r] = f2b(yv);
                }
                *(uint2*)&YT[gbase + t0] = *(uint2*)opk;
            }
        }
    }
}

// ---------------------------------------------------------------------------
// stage a 128x32 bf16 tile into LDS via global_load_lds, 512 threads.
// LDS dest LINEAR; bank-swizzle via permuted GLOBAL source chunk
// (chunk' = chunk ^ ((row>>1)&3)); readers XOR the same way.
// Exactly 1 global_load_lds per thread (vmcnt accounting relies on it).
// ---------------------------------------------------------------------------
__device__ __forceinline__ void stage_tile_512(
    const u16* __restrict__ g, u16* lds, int row0, int k0)
{
    const int t = threadIdx.x;           // 0..511, one 16B chunk each
    const int row  = t >> 2;             // 0..127
    const int csrc = (t & 3) ^ ((t >> 3) & 3);
    const u16* gp = g + (size_t)(row0 + row) * 512 + k0 + csrc * 8;
    __builtin_amdgcn_global_load_lds(
        (const __attribute__((address_space(1))) unsigned int*)gp,
        (__attribute__((address_space(3))) unsigned int*)(lds + (size_t)t * 8),
        16, 0, 0);
}

// stage a 128x64 bf16 tile (BK=64) into LDS, 512 threads x 2 chunks.
// Row = 8 chunks of 16B; bank = chunk-only at 128B row stride, so swizzle
// chunk' = chunk ^ (row&7) on the GLOBAL source; readers XOR identically.
// Each thread issues exactly 2 global_load_lds (vmcnt accounting relies on it).
__device__ __forceinline__ void stage_tile64_512(
    const u16* __restrict__ g, u16* lds, int row0, int k0)
{
    const int t = threadIdx.x;
    #pragma unroll
    for (int r = 0; r < 2; ++r) {
        int c   = t + r * 512;           // chunk id 0..1023
        int row = c >> 3, cc = c & 7;
        int csrc = cc ^ (row & 7);
        const u16* gp = g + (size_t)(row0 + row) * 512 + k0 + csrc * 8;
        __builtin_amdgcn_global_load_lds(
            (const __attribute__((address_space(1))) unsigned int*)gp,
            (__attribute__((address_space(3))) unsigned int*)(lds + (size_t)c * 8),
            16, 0, 0);
    }
}

// A-tile from YT (B,H,L): thread reads 8 consecutive l for one h(=k), then
// transposes into As[l][k] via 8 offset-immediate ds_write_b16.
// Swizzle on chunk: c_store = kc ^ ((row>>3)&3)  (row>>3 == lc here).
__device__ __forceinline__ uint4 ldA_yt(
    const u16* __restrict__ YT, int b, int l0, int k0)
{
    const int k  = threadIdx.x >> 4;
    const int lc = threadIdx.x & 15;
    return *(const uint4*)(YT + (((size_t)(b * 512 + k0 + k)) << 11) + l0 + lc * 8);
}
__device__ __forceinline__ void dswA(u16* lds, uint4 av)
{
    const int k  = threadIdx.x >> 4;
    const int lc = threadIdx.x & 15;
    u16* p = lds + (lc * 8) * 32 + (((k >> 3) ^ (lc & 3)) << 3) + (k & 7);
    const u16* s = (const u16*)&av;
    #pragma unroll
    for (int j = 0; j < 8; ++j) p[j * 32] = s[j];
}

// ---------------------------------------------------------------------------
// 5) GEMM1 + GLU + residual (dual-B), A read DIRECTLY from YT (reg-staged
//    transpose), LN1 row-stats side-output.  COUNTED-vmcnt T4 pipeline:
//    per iter the thread issues exactly 3 VMEM ops (ldA reg + Ba + Bg for
//    tile it+2); top-of-iter wait = vmcnt(3) (tile it+1's 3 stay in flight).
//    Bottom barrier = lgkmcnt(0)+s_barrier (publishes dswA's ds_writes).
//    A-value ping-pongs between named regs avA/avB (rule #20).
// ---------------------------------------------------------------------------
__global__ __launch_bounds__(512) void gemm1_glu_kernel(
    const u16* __restrict__ YT, const u16* __restrict__ Wo,
    const float* __restrict__ bo, const float* __restrict__ x,
    u16* __restrict__ out, float2* __restrict__ Pstats)
{
    __shared__ u16 As[2][128 * 32];
    __shared__ u16 Ba[2][128 * 32];
    __shared__ u16 Bg[2][128 * 32];
    __shared__ float2 red1[128][4];
    const int t    = threadIdx.x;
    const int lane = t & 63;
    const int wv   = t >> 6;             // 0..7
    const int wm   = wv >> 2, wn = wv & 3;
    const int lm   = lane & 15, lq = lane >> 4;
    const int sw   = (lq ^ ((lm >> 1) & 3)) * 8;   // B-side read swizzle
    const int m0   = blockIdx.x * 128, n0 = blockIdx.y * 128;
    const int b    = m0 >> 11;
    const int l0   = m0 & 2047;
    floatx4 accA[4][2] = {};
    floatx4 accG[4][2] = {};

    // A-side read swizzle per i (row>>3 bits reduce to lane bits)
    int swA[4];
    #pragma unroll
    for (int i = 0; i < 4; ++i)
        swA[i] = (lq ^ ((i * 2 + (lm >> 3)) & 3)) * 8;

    // prologue: issue tiles 0 and 1 (6 VMEM ops), publish As[0]
    uint4 avA = ldA_yt(YT, b, l0, 0);        // tile 0
    stage_tile_512(Wo, Ba[0], n0, 0);
    stage_tile_512(Wo, Bg[0], 512 + n0, 0);
    uint4 avB = ldA_yt(YT, b, l0, 32);       // tile 1
    stage_tile_512(Wo, Ba[1], n0, 32);
    stage_tile_512(Wo, Bg[1], 512 + n0, 32);
    dswA(As[0], avA);                         // compiler waits avA's load

    #pragma unroll 1
    for (int it = 0; it < 15; ++it) {
        // top: tile it's Ba/Bg complete (3 newest = tile it+1's stay in
        // flight); lgkmcnt(0) covers prologue/previous dswA publication.
        asm volatile("s_waitcnt vmcnt(3) lgkmcnt(0)" ::: "memory");
        __builtin_amdgcn_s_barrier();
        __builtin_amdgcn_sched_barrier(0);
        const int cur = it & 1, nx = cur ^ 1;
        // publish A-tile (it+1) into the freed buffer (reads of As[nx]
        // finished before bottom barrier of it-1)
        dswA(As[nx], (it & 1) ? avA : avB);
        // issue A reg-load for tile it+2
        if (it < 14) {
            uint4 tmp = ldA_yt(YT, b, l0, (it + 2) * 32);
            if (it & 1) avB = tmp; else avA = tmp;
        }
        // MFMA on tile it
        bf16x8 af[4], ba[2], bg[2];
        #pragma unroll
        for (int i = 0; i < 4; ++i)
            af[i] = *(const bf16x8*)&As[cur][(wm * 64 + i * 16 + lm) * 32 + swA[i]];
        #pragma unroll
        for (int j = 0; j < 2; ++j) {
            ba[j] = *(const bf16x8*)&Ba[cur][(wn * 32 + j * 16 + lm) * 32 + sw];
            bg[j] = *(const bf16x8*)&Bg[cur][(wn * 32 + j * 16 + lm) * 32 + sw];
        }
        #pragma unroll
        for (int i = 0; i < 4; ++i) {
            #pragma unroll
            for (int j = 0; j < 2; ++j) {
                accA[i][j] = __builtin_amdgcn_mfma_f32_16x16x32_bf16(af[i], ba[j], accA[i][j], 0, 0, 0);
                accG[i][j] = __builtin_amdgcn_mfma_f32_16x16x32_bf16(af[i], bg[j], accG[i][j], 0, 0, 0);
            }
        }
        // bottom: ds_writes drained + all waves done reading buf[cur]
        asm volatile("s_waitcnt lgkmcnt(0)" ::: "memory");
        __builtin_amdgcn_s_barrier();
        __builtin_amdgcn_sched_barrier(0);
        // issue B loads for tile it+2 into the freed buffer
        if (it < 14) {
            stage_tile_512(Wo, Ba[cur], n0, (it + 2) * 32);
            stage_tile_512(Wo, Bg[cur], 512 + n0, (it + 2) * 32);
        }
    }
    // peeled tile 15 (in buf[1]); full drain
    asm volatile("s_waitcnt vmcnt(0) lgkmcnt(0)" ::: "memory");
    __builtin_amdgcn_s_barrier();
    __builtin_amdgcn_sched_barrier(0);
    {
        bf16x8 af[4], ba[2], bg[2];
        #pragma unroll
        for (int i = 0; i < 4; ++i)
            af[i] = *(const bf16x8*)&As[1][(wm * 64 + i * 16 + lm) * 32 + swA[i]];
        #pragma unroll
        for (int j = 0; j < 2; ++j) {
            ba[j] = *(const bf16x8*)&Ba[1][(wn * 32 + j * 16 + lm) * 32 + sw];
            bg[j] = *(const bf16x8*)&Bg[1][(wn * 32 + j * 16 + lm) * 32 + sw];
        }
        #pragma unroll
        for (int i = 0; i < 4; ++i) {
            #pragma unroll
            for (int j = 0; j < 2; ++j) {
                accA[i][j] = __builtin_amdgcn_mfma_f32_16x16x32_bf16(af[i], ba[j], accA[i][j], 0, 0, 0);
                accG[i][j] = __builtin_amdgcn_mfma_f32_16x16x32_bf16(af[i], bg[j], accG[i][j], 0, 0, 0);
            }
        }
    }

    // epilogue: GLU + residual, accumulate LN1 row partials
    float bav[2], bgv[2];
    #pragma unroll
    for (int j = 0; j < 2; ++j) {
        int n = n0 + wn * 32 + j * 16 + lm;
        bav[j] = bo[n]; bgv[j] = bo[512 + n];
    }
    #pragma unroll
    for (int i = 0; i < 4; ++i) {
        #pragma unroll
        for (int r = 0; r < 4; ++r) {
            int row = wm * 64 + i * 16 + lq * 4 + r;
            int m = m0 + row;
            float s = 0.0f, sq = 0.0f;
            #pragma unroll
            for (int j = 0; j < 2; ++j) {
                int n = n0 + wn * 32 + j * 16 + lm;
                float a_ = accA[i][j][r] + bav[j];
                float g_ = accG[i][j][r] + bgv[j];
                float xv = x[(size_t)m * 512 + n];
                float ov = fmaf(a_, sigmoidf_(g_), xv);
                out[(size_t)m * 512 + n] = f2b(ov);
                s += ov; sq = fmaf(ov, ov, sq);
            }
            #pragma unroll
            for (int msk = 1; msk < 16; msk <<= 1) {
                s  += __shfl_xor(s, msk, 64);
                sq += __shfl_xor(sq, msk, 64);
            }
            if (lm == 0) { float2 p; p.x = s; p.y = sq; red1[row][wn] = p; }
        }
    }
    __syncthreads();
    if (t < 128) {
        float s = 0.0f, sq = 0.0f;
        #pragma unroll
        for (int w = 0; w < 4; ++w) { float2 p = red1[t][w]; s += p.x; sq += p.y; }
        float2 o; o.x = s; o.y = sq;
        Pstats[(size_t)(m0 + t) * 4 + blockIdx.y] = o;
    }
}

// ---------------------------------------------------------------------------
// 6) GEMM (W1*g1 folded) + LN1 epilogue + ReLU.  BK=64, double-buffered with
//    COUNTED vmcnt (T4): tile k+2 issued at end of iter k, waited at top of
//    iter k+2 -> ~1.5 iterations of latency cover (vs same-iter drain).
//    Raw s_barrier pair per iter; sched_barrier(0) pins ds_reads (rule 18).
// ---------------------------------------------------------------------------
__global__ __launch_bounds__(512, 4) void gemm_relu_kernel(
    const u16* __restrict__ A, const u16* __restrict__ Bw,
    const float* __restrict__ bias, const float2* __restrict__ Pstats,
    const float* __restrict__ c1, const float* __restrict__ c2,
    u16* __restrict__ C)
{
    __shared__ u16 As[2][128 * 64];
    __shared__ u16 Bs[2][128 * 64];
    __shared__ float musig[128][2];
    const int t    = threadIdx.x;
    const int lane = t & 63;
    const int wv   = t >> 6;
    const int wm   = wv >> 2, wn = wv & 3;
    const int lm   = lane & 15, lq = lane >> 4;
    const int kc0  = (lq ^ (lm & 7)) * 8;          // ks=0 swizzled chunk col
    const int kc1  = ((4 + lq) ^ (lm & 7)) * 8;    // ks=1
    const int m0   = blockIdx.x * 128, n0 = blockIdx.y * 128;
    floatx4 acc[4][2] = {};

    if (t < 128) {
        float s = 0.0f, sq = 0.0f;
        #pragma unroll
        for (int w = 0; w < 4; ++w) {
            float2 p = Pstats[(size_t)(m0 + t) * 4 + w];
            s += p.x; sq += p.y;
        }
        float mu  = s * (1.0f / 512.0f);
        float var = sq * (1.0f / 512.0f) - mu * mu;
        musig[t][0] = mu;
        musig[t][1] = rsqrtf(var + 1e-5f);
    }
    // drain musig's vector loads so the staged-load vmcnt accounting is exact
    asm volatile("s_waitcnt vmcnt(0)" ::: "memory");

    // prologue: tiles k0, k1 in flight (8 loads/thread outstanding)
    stage_tile64_512(A,  As[0], m0, 0);
    stage_tile64_512(Bw, Bs[0], n0, 0);
    stage_tile64_512(A,  As[1], m0, 64);
    stage_tile64_512(Bw, Bs[1], n0, 64);

    #pragma unroll 1
    for (int it = 0; it < 7; ++it) {
        // wait for THIS tile's 4 loads (next tile's 4 stay in flight)
        asm volatile("s_waitcnt vmcnt(4)" ::: "memory");
        __builtin_amdgcn_s_barrier();
        __builtin_amdgcn_sched_barrier(0);
        const int cur = it & 1;
        #pragma unroll
        for (int ks = 0; ks < 2; ++ks) {
            const int kc = ks ? kc1 : kc0;
            bf16x8 af[4], bfr[2];
            #pragma unroll
            for (int i = 0; i < 4; ++i)
                af[i] = *(const bf16x8*)&As[cur][(wm * 64 + i * 16 + lm) * 64 + kc];
            #pragma unroll
            for (int j = 0; j < 2; ++j)
                bfr[j] = *(const bf16x8*)&Bs[cur][(wn * 32 + j * 16 + lm) * 64 + kc];
            #pragma unroll
            for (int i = 0; i < 4; ++i) {
                #pragma unroll
                for (int j = 0; j < 2; ++j)
                    acc[i][j] = __builtin_amdgcn_mfma_f32_16x16x32_bf16(af[i], bfr[j], acc[i][j], 0, 0, 0);
            }
        }
        // all waves done reading buf[cur] (MFMAs consumed every ds_read)
        __builtin_amdgcn_s_barrier();
        __builtin_amdgcn_sched_barrier(0);
        if (it < 6) {
            stage_tile64_512(A,  As[cur], m0, (it + 2) * 64);
            stage_tile64_512(Bw, Bs[cur], n0, (it + 2) * 64);
        }
    }
    // peeled final tile (k7 in buf[1]); full drain
    asm volatile("s_waitcnt vmcnt(0)" ::: "memory");
    __builtin_amdgcn_s_barrier();
    __builtin_amdgcn_sched_barrier(0);
    #pragma unroll
    for (int ks = 0; ks < 2; ++ks) {
        const int kc = ks ? kc1 : kc0;
        bf16x8 af[4], bfr[2];
        #pragma unroll
        for (int i = 0; i < 4; ++i)
            af[i] = *(const bf16x8*)&As[1][(wm * 64 + i * 16 + lm) * 64 + kc];
        #pragma unroll
        for (int j = 0; j < 2; ++j)
            bfr[j] = *(const bf16x8*)&Bs[1][(wn * 32 + j * 16 + lm) * 64 + kc];
        #pragma unroll
        for (int i = 0; i < 4; ++i) {
            #pragma unroll
            for (int j = 0; j < 2; ++j)
                acc[i][j] = __builtin_amdgcn_mfma_f32_16x16x32_bf16(af[i], bfr[j], acc[i][j], 0, 0, 0);
        }
    }
    float c1v[2], c2v[2];
    #pragma unroll
    for (int j = 0; j < 2; ++j) {
        int n = n0 + wn * 32 + j * 16 + lm;
        c1v[j] = c1[n];
        c2v[j] = c2[n] + bias[n];
    }
    #pragma unroll
    for (int i = 0; i < 4; ++i) {
        #pragma unroll
        for (int r = 0; r < 4; ++r) {
            int row = wm * 64 + i * 16 + lq * 4 + r;
            float mu = musig[row][0], rs = musig[row][1];
            float nmr = -rs * mu;
            #pragma unroll
            for (int j = 0; j < 2; ++j) {
                int n = n0 + wn * 32 + j * 16 + lm;
                float v = fmaf(rs, acc[i][j][r], fmaf(nmr, c1v[j], c2v[j]));
                C[(size_t)(m0 + row) * 512 + n] = f2b(fmaxf(v, 0.0f));
            }
        }
    }
}

// ---------------------------------------------------------------------------
// 7) GEMM2 (128x128 tile) + LN1'd residual epilogue.  BK=64, counted-vmcnt
//    pipeline identical to gemm_relu.  Writes z bf16 + LN2 row-partials.
// ---------------------------------------------------------------------------
__global__ __launch_bounds__(512, 4) void gemm2_tile_kernel(
    const u16* __restrict__ A, const u16* __restrict__ Bw,
    const float* __restrict__ bias, const u16* __restrict__ res,
    const float2* __restrict__ Pstats,
    const float* __restrict__ g1, const float* __restrict__ beta1,
    u16* __restrict__ Z, float2* __restrict__ Pstats2)
{
    __shared__ u16 As[2][128 * 64];
    __shared__ u16 Bs[2][128 * 64];
    __shared__ float musig[128][2];
    __shared__ float2 red2[128][4];
    const int t    = threadIdx.x;
    const int lane = t & 63;
    const int wv   = t >> 6;
    const int wm   = wv >> 2, wn = wv & 3;
    const int lm   = lane & 15, lq = lane >> 4;
    const int kc0  = (lq ^ (lm & 7)) * 8;
    const int kc1  = ((4 + lq) ^ (lm & 7)) * 8;
    const int m0   = blockIdx.x * 128, n0 = blockIdx.y * 128;
    floatx4 acc[4][2] = {};

    if (t < 128) {
        float s = 0.0f, sq = 0.0f;
        #pragma unroll
        for (int w = 0; w < 4; ++w) {
            float2 p = Pstats[(size_t)(m0 + t) * 4 + w];
            s += p.x; sq += p.y;
        }
        float mu  = s * (1.0f / 512.0f);
        float var = sq * (1.0f / 512.0f) - mu * mu;
        musig[t][0] = mu;
        musig[t][1] = rsqrtf(var + 1e-5f);
    }
    asm volatile("s_waitcnt vmcnt(0)" ::: "memory");

    stage_tile64_512(A,  As[0], m0, 0);
    stage_tile64_512(Bw, Bs[0], n0, 0);
    stage_tile64_512(A,  As[1], m0, 64);
    stage_tile64_512(Bw, Bs[1], n0, 64);

    #pragma unroll 1
    for (int it = 0; it < 7; ++it) {
        asm volatile("s_waitcnt vmcnt(4)" ::: "memory");
        __builtin_amdgcn_s_barrier();
        __builtin_amdgcn_sched_barrier(0);
        const int cur = it & 1;
        #pragma unroll
        for (int ks = 0; ks < 2; ++ks) {
            const int kc = ks ? kc1 : kc0;
            bf16x8 af[4], bfr[2];
            #pragma unroll
            for (int i = 0; i < 4; ++i)
                af[i] = *(const bf16x8*)&As[cur][(wm * 64 + i * 16 + lm) * 64 + kc];
            #pragma unroll
            for (int j = 0; j < 2; ++j)
                bfr[j] = *(const bf16x8*)&Bs[cur][(wn * 32 + j * 16 + lm) * 64 + kc];
            #pragma unroll
            for (int i = 0; i < 4; ++i) {
                #pragma unroll
                for (int j = 0; j < 2; ++j)
                    acc[i][j] = __builtin_amdgcn_mfma_f32_16x16x32_bf16(af[i], bfr[j], acc[i][j], 0, 0, 0);
            }
        }
        __builtin_amdgcn_s_barrier();
        __builtin_amdgcn_sched_barrier(0);
        if (it < 6) {
            stage_tile64_512(A,  As[cur], m0, (it + 2) * 64);
            stage_tile64_512(Bw, Bs[cur], n0, (it + 2) * 64);
        }
    }
    asm volatile("s_waitcnt vmcnt(0)" ::: "memory");
    __builtin_amdgcn_s_barrier();
    __builtin_amdgcn_sched_barrier(0);
    #pragma unroll
    for (int ks = 0; ks < 2; ++ks) {
        const int kc = ks ? kc1 : kc0;
        bf16x8 af[4], bfr[2];
        #pragma unroll
        for (int i = 0; i < 4; ++i)
            af[i] = *(const bf16x8*)&As[1][(wm * 64 + i * 16 + lm) * 64 + kc];
        #pragma unroll
        for (int j = 0; j < 2; ++j)
            bfr[j] = *(const bf16x8*)&Bs[1][(wn * 32 + j * 16 + lm) * 64 + kc];
        #pragma unroll
        for (int i = 0; i < 4; ++i) {
            #pragma unroll
            for (int j = 0; j < 2; ++j)
                acc[i][j] = __builtin_amdgcn_mfma_f32_16x16x32_bf16(af[i], bfr[j], acc[i][j], 0, 0, 0);
        }
    }

    // epilogue: z = acc + bias + LN1(res); write z bf16; LN2 row partials
    float bv[2], gv1[2], bt1[2];
    #pragma unroll
    for (int j = 0; j < 2; ++j) {
        int n = n0 + wn * 32 + j * 16 + lm;
        bv[j]  = bias[n];
        gv1[j] = g1[n];
        bt1[j] = beta1[n];
    }
    #pragma unroll
    for (int i = 0; i < 4; ++i) {
        #pragma unroll
        for (int r = 0; r < 4; ++r) {
            int row = wm * 64 + i * 16 + lq * 4 + r;
            int m = m0 + row;
            float mu1 = musig[row][0], rs1 = musig[row][1];
            float s = 0.0f, sq = 0.0f;
            #pragma unroll
            for (int j = 0; j < 2; ++j) {
                int n = n0 + wn * 32 + j * 16 + lm;
                float zl = fmaf((b2f(res[(size_t)m * 512 + n]) - mu1) * rs1, gv1[j], bt1[j]);
                float v = acc[i][j][r] + bv[j] + zl;
                Z[(size_t)m * 512 + n] = f2b(v);
                s += v; sq = fmaf(v, v, sq);
            }
            #pragma unroll
            for (int msk = 1; msk < 16; msk <<= 1) {
                s  += __shfl_xor(s, msk, 64);
                sq += __shfl_xor(sq, msk, 64);
            }
            if (lm == 0) { float2 p; p.x = s; p.y = sq; red2[row][wn] = p; }
        }
    }
    __syncthreads();
    if (t < 128) {
        float s = 0.0f, sq = 0.0f;
        #pragma unroll
        for (int w = 0; w < 4; ++w) { float2 p = red2[t][w]; s += p.x; sq += p.y; }
        float2 o; o.x = s; o.y = sq;
        Pstats2[(size_t)(m0 + t) * 4 + blockIdx.y] = o;
    }
}

// ---------------------------------------------------------------------------
// 8) LN2 finish: out = (z - mu)*rs*g2 + b2, fp32. Memory-bound streaming.
// ---------------------------------------------------------------------------
__global__ __launch_bounds__(256) void ln2_finish_kernel(
    const u16* __restrict__ Z, const float2* __restrict__ Pstats2,
    const float* __restrict__ gamma, const float* __restrict__ beta,
    float* __restrict__ out)
{
    int w    = threadIdx.x >> 6;
    int lane = threadIdx.x & 63;
    size_t row  = (size_t)blockIdx.x * 4 + w;
    float s = 0.0f, sq = 0.0f;
    #pragma unroll
    for (int w4 = 0; w4 < 4; ++w4) {
        float2 p = Pstats2[row * 4 + w4];
        s += p.x; sq += p.y;
    }
    float mu  = s * (1.0f / 512.0f);
    float var = sq * (1.0f / 512.0f) - mu * mu;
    float rs  = rsqrtf(var + 1e-5f);
    size_t base = row * 512 + lane * 8;
    uint4 raw = *(const uint4*)(Z + base);
    float v[8];
    unpack2(raw.x, v[0], v[1]); unpack2(raw.y, v[2], v[3]);
    unpack2(raw.z, v[4], v[5]); unpack2(raw.w, v[6], v[7]);
    float g[8], bt[8];
    *(float4*)&g[0]  = *(const float4*)(gamma + lane * 8);
    *(float4*)&g[4]  = *(const float4*)(gamma + lane * 8 + 4);
    *(float4*)&bt[0] = *(const float4*)(beta + lane * 8);
    *(float4*)&bt[4] = *(const float4*)(beta + lane * 8 + 4);
    float o[8];
    #pragma unroll
    for (int i = 0; i < 8; ++i)
        o[i] = fmaf((v[i] - mu) * rs, g[i], bt[i]);
    *(float4*)(out + base)     = *(float4*)&o[0];
    *(float4*)(out + base + 4) = *(float4*)&o[4];
}

// ---------------------------------------------------------------------------
extern "C" void kernel_launch(void* const* d_in, const int* in_sizes, int n_in,
                              void* d_out, int out_size, void* d_ws, size_t ws_size,
                              hipStream_t stream)
{
    (void)in_sizes; (void)n_in; (void)out_size; (void)ws_size;
    const float* x      = (const float*)d_in[0];
    const float* log_dt = (const float*)d_in[1];
    const float* A_re   = (const float*)d_in[2];
    const float* A_im   = (const float*)d_in[3];
    const float* C_re   = (const float*)d_in[4];
    const float* C_im   = (const float*)d_in[5];
    const float* D_skip = (const float*)d_in[6];
    const float* W_out  = (const float*)d_in[7];
    const float* b_out  = (const float*)d_in[8];
    const float* g1     = (const float*)d_in[9];
    const float* beta1  = (const float*)d_in[10];
    const float* g2     = (const float*)d_in[11];
    const float* beta2  = (const float*)d_in[12];
    const float* W1     = (const float*)d_in[13];
    const float* bc1    = (const float*)d_in[14];
    const float* W2     = (const float*)d_in[15];
    const float* bc2    = (const float*)d_in[16];
    float* out = (float*)d_out;

    // workspace: P 512K | hole | Toep 4M | weights 2M | r1/r2/r3 | Pstats | c1 c2 | Pstats2
    char*   wsb    = (char*)d_ws;
    float*  P      = (float*)wsb;
    u16*    Toep   = (u16*)(wsb + 4 * HN * 4 + 512 * 64 * 4);
    u16*    Wobf   = Toep + 512 * 4096;
    u16*    W1bf   = Wobf + 1024 * 512;
    u16*    W2bf   = W1bf + 512 * 512;
    u16*    r1     = W2bf + 512 * 512;   // XT -> h1_bf
    u16*    r2     = r1 + BLH;           // YT -> z2_bf
    u16*    r3     = r2 + BLH;           // x1pre_bf
    float2* Pstats = (float2*)(r3 + BLH);
    float*  c1     = (float*)(Pstats + (size_t)M_DIM * 4);
    float*  c2     = c1 + 512;
    float2* Pstats2 = (float2*)(c2 + 512);

    setup_kernel<<<9472, 256, 0, stream>>>(x, W_out, W1, W2, log_dt, A_re, A_im,
                                           C_re, C_im, g1, beta1,
                                           r1, Wobf, W1bf, W2bf, P, Toep, c1, c2);
    ssm_chunk_kernel<<<dim3(H_DIM, 2), 256, 0, stream>>>(r1, P, Toep, D_skip, r2);
    gemm1_glu_kernel<<<dim3(M_DIM / 128, 4), 512, 0, stream>>>(r2, Wobf, b_out, x, r3, Pstats);
    gemm_relu_kernel<<<dim3(M_DIM / 128, 4), 512, 0, stream>>>(r3, W1bf, bc1, Pstats, c1, c2, r1);
    gemm2_tile_kernel<<<dim3(M_DIM / 128, 4), 512, 0, stream>>>(r1, W2bf, bc2, r3, Pstats, g1, beta1, r2, Pstats2);
    ln2_finish_kernel<<<M_DIM / 4, 256, 0, stream>>>(r2, Pstats2, g2, beta2, out);
}

// Round 11
// 229.075 us; speedup vs baseline: 1.0745x; 1.0070x over previous
//
#include <hip/hip_runtime.h>
#include <cstddef>
#include <cstdint>

#define B_DIM 8
#define L_DIM 2048
#define H_DIM 512
#define N_DIM 64
#define HN (H_DIM * N_DIM)          // 32768
#define BLH (B_DIM * L_DIM * H_DIM) // 8388608
#define M_DIM (B_DIM * L_DIM)       // 16384

typedef unsigned short u16;
typedef short bf16x8 __attribute__((ext_vector_type(8)));
typedef float floatx4 __attribute__((ext_vector_type(4)));

__device__ __forceinline__ float sigmoidf_(float v) {
    return 1.0f / (1.0f + __expf(-v));
}

// jax.nn.gelu default: approximate=True (tanh form)
__device__ __forceinline__ float gelu_tanh_(float x) {
    float x3 = x * x * x;
    float z = 0.7978845608028654f * fmaf(0.044715f, x3, x);
    float e = __expf(-2.0f * fabsf(z));
    float th = (1.0f - e) / (1.0f + e);
    th = copysignf(th, z);
    return 0.5f * x * (1.0f + th);
}

__device__ __forceinline__ u16 f2b(float f) {
    unsigned u = __float_as_uint(f);
    unsigned r = (u + 0x7fffu + ((u >> 16) & 1u)) >> 16;
    return (u16)r;
}
__device__ __forceinline__ float b2f(u16 u) {
    return __uint_as_float(((unsigned)u) << 16);
}
__device__ __forceinline__ void unpack2(unsigned u, float& a, float& b) {
    a = __uint_as_float(u << 16);
    b = __uint_as_float(u & 0xffff0000u);
}
__device__ __forceinline__ unsigned pack2(float a, float b) {
    return (unsigned)f2b(a) | ((unsigned)f2b(b) << 16);
}

// complex helpers
__device__ __forceinline__ void csq(float& r, float& i) {
    float nr = r * r - i * i;
    i = 2.0f * r * i;
    r = nr;
}
__device__ __forceinline__ void cmul(float& ar, float& ai, float br, float bi) {
    float nr = ar * br - ai * bi;
    ai = ar * bi + ai * br;
    ar = nr;
}

// ---------------------------------------------------------------------------
// 0) SETUP (one launch, block-partitioned):
//    [0,8192)     xtrans: x (B,L,H) fp32 -> XT (B,H,L) bf16
//    [8192,9216)  weight casts: Wo->bf16, W1*g1->bf16 (LN1 fold), W2->bf16
//    [9216,9344)  SSM params P + Ktab(LDS) + Toeplitz fill
//    [9344,9472)  LN1-fold column sums: c1[f]=sum_n W1[f][n]g1[n], c2=..beta1
// ---------------------------------------------------------------------------
__global__ __launch_bounds__(256) void setup_kernel(
    const float* __restrict__ x, const float* __restrict__ W_out,
    const float* __restrict__ W1, const float* __restrict__ W2,
    const float* __restrict__ log_dt, const float* __restrict__ A_re,
    const float* __restrict__ A_im, const float* __restrict__ C_re,
    const float* __restrict__ C_im, const float* __restrict__ g1,
    const float* __restrict__ beta1,
    u16* __restrict__ XT, u16* __restrict__ Wobf, u16* __restrict__ W1gbf,
    u16* __restrict__ W2bf, float* __restrict__ P, u16* __restrict__ Toep_bf,
    float* __restrict__ c1, float* __restrict__ c2)
{
    __shared__ float tile[32][33];
    __shared__ float ktab_s[4][64];
    const int bid = blockIdx.x;
    const int t   = threadIdx.x;

    if (bid < 8192) {
        // ---- xtrans
        int b  = bid >> 10;
        int hy = (bid >> 6) & 15;
        int lx = bid & 63;
        int l0 = lx * 32, h0 = hy * 32;
        int tx = t & 31, ty = t >> 5;
        #pragma unroll
        for (int r = 0; r < 4; ++r)
            tile[ty + r * 8][tx] = x[((size_t)b * L_DIM + l0 + ty + r * 8) * H_DIM + h0 + tx];
        __syncthreads();
        #pragma unroll
        for (int r = 0; r < 4; ++r)
            XT[(((size_t)b * H_DIM + h0 + ty + r * 8) << 11) + l0 + tx] = f2b(tile[tx][ty + r * 8]);
    } else if (bid < 9216) {
        // ---- weight casts
        int off = bid - 8192;
        if (off < 512) {
            int i = off * 256 + t;
            float4 v = *(const float4*)(W_out + (size_t)i * 4);
            uint2 p; p.x = pack2(v.x, v.y); p.y = pack2(v.z, v.w);
            *(uint2*)(Wobf + (size_t)i * 4) = p;
        } else if (off < 768) {
            int i = (off - 512) * 256 + t;
            float4 v = *(const float4*)(W1 + (size_t)i * 4);
            int n = (i * 4) & 511;
            float4 g = *(const float4*)(g1 + n);
            uint2 p; p.x = pack2(v.x * g.x, v.y * g.y);
            p.y = pack2(v.z * g.z, v.w * g.w);
            *(uint2*)(W1gbf + (size_t)i * 4) = p;
        } else {
            int i = (off - 768) * 256 + t;
            float4 v = *(const float4*)(W2 + (size_t)i * 4);
            uint2 p; p.x = pack2(v.x, v.y); p.y = pack2(v.z, v.w);
            *(uint2*)(W2bf + (size_t)i * 4) = p;
        }
    } else if (bid < 9344) {
        // ---- SSM params + Ktab + Toeplitz
        const int wv = t >> 6, lane = t & 63;
        const int i = (bid - 9216) * 256 + t;
        const int h = i >> 6;
        float dt = expf(log_dt[h]);
        float Ar = A_re[i], Ai = A_im[i];
        float ar = dt * Ar, ai = dt * Ai;
        float e = expf(ar);
        float wr = e * cosf(ai);
        float wi = e * sinf(ai);
        float em1r = wr - 1.0f, em1i = wi;
        float inv = 1.0f / fmaf(Ar, Ar, Ai * Ai);
        float qr = fmaf(em1r, Ar, em1i * Ai) * inv;
        float qi = fmaf(em1i, Ar, -(em1r * Ai)) * inv;
        float Cr = C_re[i], Ci = C_im[i];
        float c2r = 2.0f * (Cr * qr - Ci * qi);
        float c2i = 2.0f * (Cr * qi + Ci * qr);
        P[i]          = wr;
        P[HN + i]     = wi;
        P[2 * HN + i] = c2r;
        P[3 * HN + i] = c2i;

        float pr = 1.0f, pi = 0.0f;
        for (int tau = 0; tau < 64; ++tau) {
            float term = c2r * pr - c2i * pi;
            #pragma unroll
            for (int m = 32; m > 0; m >>= 1) term += __shfl_xor(term, m, 64);
            if (lane == 0) ktab_s[wv][tau] = term;
            float nr = pr * wr - pi * wi, ni = pr * wi + pi * wr;
            pr = nr; pi = ni;
        }
        __syncthreads();

        const int h0 = (bid - 9216) * 4;
        #pragma unroll
        for (int r = 0; r < 8; ++r) {
            int c = t + r * 256;
            int hh = c >> 9, rem = c & 511;
            int tt = rem >> 3, j0 = (rem & 7) * 8;
            u16 vv[8];
            #pragma unroll
            for (int jj = 0; jj < 8; ++jj) {
                int j = j0 + jj;
                vv[jj] = (j <= tt) ? f2b(ktab_s[hh][tt - j]) : (u16)0;
            }
            *(uint4*)&Toep_bf[((size_t)(h0 + hh) << 12) + (tt << 6) + j0] = *(uint4*)vv;
        }
    } else {
        // ---- LN1-fold column sums over n for W1 row f
        int f = (bid - 9344) * 4 + (t >> 6);
        int lane = t & 63;
        int n = lane * 8;
        float4 w0 = *(const float4*)(W1 + (size_t)f * 512 + n);
        float4 w1v = *(const float4*)(W1 + (size_t)f * 512 + n + 4);
        float4 ga = *(const float4*)(g1 + n);
        float4 gb = *(const float4*)(g1 + n + 4);
        float4 b0 = *(const float4*)(beta1 + n);
        float4 b1 = *(const float4*)(beta1 + n + 4);
        float s1 = w0.x * ga.x + w0.y * ga.y + w0.z * ga.z + w0.w * ga.w
                 + w1v.x * gb.x + w1v.y * gb.y + w1v.z * gb.z + w1v.w * gb.w;
        float s2 = w0.x * b0.x + w0.y * b0.y + w0.z * b0.z + w0.w * b0.w
                 + w1v.x * b1.x + w1v.y * b1.y + w1v.z * b1.z + w1v.w * b1.w;
        #pragma unroll
        for (int m = 32; m > 0; m >>= 1) {
            s1 += __shfl_xor(s1, m, 64);
            s2 += __shfl_xor(s2, m, 64);
        }
        if (lane == 0) { c1[f] = s1; c2[f] = s2; }
    }
}

// ---------------------------------------------------------------------------
// 3) Chunked SSM via MFMA. One workgroup = (h, half of b). T=64, 32 chunks.
//    512 threads (8 waves): 2x occupancy vs 256t, half the serial work/wave.
//    U/E/Tp linear [rows][64] with chunk^(row&7) swizzle; U,Tp staged via
//    global_load_lds (source-swizzled); E written as 2x b128 per thread.
// ---------------------------------------------------------------------------
__global__ __launch_bounds__(512) void ssm_chunk_kernel(
    const u16* __restrict__ XT, const float* __restrict__ P,
    const u16* __restrict__ Toep_bf, const float* __restrict__ D_skip,
    u16* __restrict__ YT)
{
    __shared__ u16 U[128 * 64];      // [ncol][j] linear, swizzled chunks
    __shared__ u16 S[128 * 136];     // [ncol][2n], pad 136
    __shared__ u16 EVT[12800];       // union: E[128*64]=8192 | Tp[64*64]=4096 + V[64*136]=8704
    u16* E  = EVT;
    u16* Tp = EVT;
    u16* V  = EVT + 4096;

    const int h    = blockIdx.x;
    const int b0   = blockIdx.y * 4;
    const int t    = threadIdx.x;        // 0..511
    const int lane = t & 63;
    const int wv   = t >> 6;             // 0..7
    const int lm   = lane & 15, lq = lane >> 4;
    const int kc0  = (lq ^ (lm & 7)) * 8;
    const int kc1  = ((4 + lq) ^ (lm & 7)) * 8;

    const int pidx = (h << 6) + lane;
    const float wr  = P[pidx],          wi  = P[HN + pidx];
    const float c2r = P[2 * HN + pidx], c2i = P[3 * HN + pidx];

    // stage U via global_load_lds: 1024 16B chunks, 2/thread, src-swizzled
    #pragma unroll
    for (int r = 0; r < 2; ++r) {
        int c   = t + r * 512;
        int row = c >> 3, cc = c & 7;
        int csrc = cc ^ (row & 7);
        const u16* gp = XT + (((size_t)(b0 + (row >> 5)) * H_DIM + h) << 11)
                           + ((row & 31) << 6) + (csrc << 3);
        __builtin_amdgcn_global_load_lds(
            (const __attribute__((address_space(1))) unsigned int*)gp,
            (__attribute__((address_space(3))) unsigned int*)(U + (size_t)c * 8),
            16, 0, 0);
    }

    // powers of w
    float w8r = wr, w8i = wi;
    csq(w8r, w8i); csq(w8r, w8i); csq(w8r, w8i);       // w^8
    float w16r = w8r, w16i = w8i;   csq(w16r, w16i);   // w^16
    float w32r = w16r, w32i = w16i; csq(w32r, w32i);   // w^32
    float w64r = w32r, w64i = w32i; csq(w64r, w64i);   // w^64

    // bw = w^(8*wv)
    float bwr = 1.0f, bwi = 0.0f;
    if (wv & 1) cmul(bwr, bwi, w8r, w8i);
    if (wv & 2) cmul(bwr, bwi, w16r, w16i);
    if (wv & 4) cmul(bwr, bwi, w32r, w32i);

    // fill E: rows 2*lane (Re), 2*lane+1 (Im); this wave owns j-chunk 7-wv
    // (j = 56-8wv .. 63-8wv, value at j is w^(63-j)); 2x b128 swizzled writes
    {
        alignas(16) u16 re16[8];
        alignas(16) u16 im16[8];
        float pr = bwr, pi = bwi;            // w^(8wv + jk)
        #pragma unroll
        for (int jk = 0; jk < 8; ++jk) {
            re16[7 - jk] = f2b(pr);
            im16[7 - jk] = f2b(pi);
            float nr = pr * wr - pi * wi, ni = pr * wi + pi * wr;
            pr = nr; pi = ni;
        }
        int row0 = 2 * lane, row1 = row0 + 1;
        *(uint4*)&E[row0 * 64 + (((7 - wv) ^ (row0 & 7)) << 3)] = *(const uint4*)re16;
        *(uint4*)&E[row1 * 64 + (((7 - wv) ^ (row1 & 7)) << 3)] = *(const uint4*)im16;
    }
    __syncthreads();   // drains U DMA + publishes E

    // Phase A: S_local[m][ncol] = E[m][:] · U[ncol][:]   (8 waves: 2m x 4n)
    {
        const int wm = wv >> 2, wn = wv & 3;
        floatx4 acc[4][2] = {};
        #pragma unroll
        for (int ks = 0; ks < 2; ++ks) {
            const int kc = ks ? kc1 : kc0;
            bf16x8 af[4], bfv[2];
            #pragma unroll
            for (int i = 0; i < 4; ++i)
                af[i] = *(const bf16x8*)&E[(wm * 64 + i * 16 + lm) * 64 + kc];
            #pragma unroll
            for (int j = 0; j < 2; ++j)
                bfv[j] = *(const bf16x8*)&U[(wn * 32 + j * 16 + lm) * 64 + kc];
            #pragma unroll
            for (int i = 0; i < 4; ++i) {
                #pragma unroll
                for (int j = 0; j < 2; ++j)
                    acc[i][j] = __builtin_amdgcn_mfma_f32_16x16x32_bf16(af[i], bfv[j], acc[i][j], 0, 0, 0);
            }
        }
        #pragma unroll
        for (int i = 0; i < 4; ++i) {
            #pragma unroll
            for (int j = 0; j < 2; ++j) {
                int ncol = wn * 32 + j * 16 + lm;
                int m0   = wm * 64 + i * 16 + lq * 4;
                u16 pk[4];
                #pragma unroll
                for (int r = 0; r < 4; ++r) pk[r] = f2b(acc[i][j][r]);
                *(uint2*)&S[ncol * 136 + m0] = *(uint2*)pk;
            }
        }
    }
    __syncthreads();   // E reads + S_local writes complete

    // Toep DMA (into dead-E region) + V fill + chunk scan
    {
        // stage Toeplitz 64x64 via global_load_lds, 512 chunks / 512 threads
        {
            int row = t >> 3, cc = t & 7;
            int csrc = cc ^ (row & 7);
            const u16* gp = Toep_bf + ((size_t)h << 12) + (row << 6) + (csrc << 3);
            __builtin_amdgcn_global_load_lds(
                (const __attribute__((address_space(1))) unsigned int*)gp,
                (__attribute__((address_space(3))) unsigned int*)(Tp + (size_t)t * 8),
                16, 0, 0);
        }
        // V: wave wv covers tr = 8wv .. 8wv+7; V[tr][2n]=Re(Ct2 w^(tr+1)), -Im
        float pr = bwr, pi = bwi;
        cmul(pr, pi, wr, wi);                 // w^(8wv+1)
        #pragma unroll
        for (int jk = 1; jk <= 8; ++jk) {
            int tr = (wv << 3) + jk - 1;
            float qr = c2r * pr - c2i * pi;
            float qi = c2r * pi + c2i * pr;
            V[tr * 136 + 2 * lane]     = f2b(qr);
            V[tr * 136 + 2 * lane + 1] = f2b(-qi);
            float nr = pr * wr - pi * wi, ni = pr * wi + pi * wr;
            pr = nr; pi = ni;
        }
        // chunk scan on first 256 threads: thread = (bloc=sv, n=sl)
        if (t < 256) {
            const int sv = t >> 6;
            const int sl = t & 63;
            float Sr = 0.0f, Si = 0.0f;
            const int n2 = sl * 2;
            for (int c = 0; c < 32; ++c) {
                int base = (sv * 32 + c) * 136 + n2;
                unsigned lv = *(unsigned*)&S[base];
                float lr, li;
                unpack2(lv, lr, li);
                *(unsigned*)&S[base] = pack2(Sr, Si);
                float nSr = w64r * Sr - w64i * Si + lr;
                Si = w64r * Si + w64i * Sr + li;
                Sr = nSr;
            }
        }
    }
    __syncthreads();   // drains Toep DMA + publishes V + S_in

    // Phase C: Y[t][ncol] = Toep@U + V@S_in; one 16-ncol stripe per wave
    {
        const float Dh = D_skip[h];
        const int ncol = (wv << 4) + lm;    // 0..127
        floatx4 acc[4] = {};
        #pragma unroll
        for (int ks = 0; ks < 6; ++ks) {
            bf16x8 af[4], bfv;
            if (ks < 2) {
                const int kc = ks ? kc1 : kc0;
                #pragma unroll
                for (int i = 0; i < 4; ++i)
                    af[i] = *(const bf16x8*)&Tp[(i * 16 + lm) * 64 + kc];
                bfv = *(const bf16x8*)&U[ncol * 64 + kc];
            } else {
                #pragma unroll
                for (int i = 0; i < 4; ++i)
                    af[i] = *(const bf16x8*)&V[(i * 16 + lm) * 136 + (ks - 2) * 32 + lq * 8];
                bfv = *(const bf16x8*)&S[ncol * 136 + (ks - 2) * 32 + lq * 8];
            }
            #pragma unroll
            for (int i = 0; i < 4; ++i)
                acc[i] = __builtin_amdgcn_mfma_f32_16x16x32_bf16(af[i], bfv, acc[i], 0, 0, 0);
        }
        const int bloc = ncol >> 5, cc = ncol & 31;
        size_t gbase = (((size_t)(b0 + bloc) * H_DIM + h) << 11) + (cc << 6);
        #pragma unroll
        for (int i = 0; i < 4; ++i) {
            int t0 = i * 16 + lq * 4;
            u16 upk[4];
            int uoff = ncol * 64 + ((((t0 >> 3) ^ (lm & 7))) << 3) + (t0 & 7);
            *(uint2*)upk = *(const uint2*)&U[uoff];
            u16 opk[4];
            #pragma unroll
            for (int r = 0; r < 4; ++r) {
                float uvv = b2f(upk[r]);
                float yv = gelu_tanh_(fmaf(Dh, uvv, acc[i][r]));
                opk[r] = f2b(yv);
            }
            *(uint2*)&YT[gbase + t0] = *(uint2*)opk;
        }
    }
}

// ---------------------------------------------------------------------------
// stage a 128x32 bf16 tile into LDS via global_load_lds, 512 threads.
// LDS dest LINEAR; bank-swizzle via permuted GLOBAL source chunk
// (chunk' = chunk ^ ((row>>1)&3)); readers XOR the same way.
// Exactly 1 global_load_lds per thread (vmcnt accounting relies on it).
// ---------------------------------------------------------------------------
__device__ __forceinline__ void stage_tile_512(
    const u16* __restrict__ g, u16* lds, int row0, int k0)
{
    const int t = threadIdx.x;           // 0..511, one 16B chunk each
    const int row  = t >> 2;             // 0..127
    const int csrc = (t & 3) ^ ((t >> 3) & 3);
    const u16* gp = g + (size_t)(row0 + row) * 512 + k0 + csrc * 8;
    __builtin_amdgcn_global_load_lds(
        (const __attribute__((address_space(1))) unsigned int*)gp,
        (__attribute__((address_space(3))) unsigned int*)(lds + (size_t)t * 8),
        16, 0, 0);
}

// stage a 128x64 bf16 tile (BK=64) into LDS, 512 threads x 2 chunks.
// Row = 8 chunks of 16B; bank = chunk-only at 128B row stride, so swizzle
// chunk' = chunk ^ (row&7) on the GLOBAL source; readers XOR identically.
// Each thread issues exactly 2 global_load_lds (vmcnt accounting relies on it).
__device__ __forceinline__ void stage_tile64_512(
    const u16* __restrict__ g, u16* lds, int row0, int k0)
{
    const int t = threadIdx.x;
    #pragma unroll
    for (int r = 0; r < 2; ++r) {
        int c   = t + r * 512;           // chunk id 0..1023
        int row = c >> 3, cc = c & 7;
        int csrc = cc ^ (row & 7);
        const u16* gp = g + (size_t)(row0 + row) * 512 + k0 + csrc * 8;
        __builtin_amdgcn_global_load_lds(
            (const __attribute__((address_space(1))) unsigned int*)gp,
            (__attribute__((address_space(3))) unsigned int*)(lds + (size_t)c * 8),
            16, 0, 0);
    }
}

// A-tile from YT (B,H,L): thread reads 8 consecutive l for one h(=k), then
// transposes into As[l][k] via 8 offset-immediate ds_write_b16.
// Swizzle on chunk: c_store = kc ^ ((row>>3)&3)  (row>>3 == lc here).
__device__ __forceinline__ uint4 ldA_yt(
    const u16* __restrict__ YT, int b, int l0, int k0)
{
    const int k  = threadIdx.x >> 4;
    const int lc = threadIdx.x & 15;
    return *(const uint4*)(YT + (((size_t)(b * 512 + k0 + k)) << 11) + l0 + lc * 8);
}
__device__ __forceinline__ void dswA(u16* lds, uint4 av)
{
    const int k  = threadIdx.x >> 4;
    const int lc = threadIdx.x & 15;
    u16* p = lds + (lc * 8) * 32 + (((k >> 3) ^ (lc & 3)) << 3) + (k & 7);
    const u16* s = (const u16*)&av;
    #pragma unroll
    for (int j = 0; j < 8; ++j) p[j * 32] = s[j];
}

// ---------------------------------------------------------------------------
// 5) GEMM1 + GLU + residual (dual-B), A read DIRECTLY from YT (reg-staged
//    transpose), LN1 row-stats side-output.  COUNTED-vmcnt T4 pipeline:
//    per iter the thread issues exactly 3 VMEM ops (ldA reg + Ba + Bg for
//    tile it+2); top-of-iter wait = vmcnt(3) (tile it+1's 3 stay in flight).
//    Bottom barrier = lgkmcnt(0)+s_barrier (publishes dswA's ds_writes).
//    A-value ping-pongs between named regs avA/avB (rule #20).
// ---------------------------------------------------------------------------
__global__ __launch_bounds__(512) void gemm1_glu_kernel(
    const u16* __restrict__ YT, const u16* __restrict__ Wo,
    const float* __restrict__ bo, const float* __restrict__ x,
    u16* __restrict__ out, float2* __restrict__ Pstats)
{
    __shared__ u16 As[2][128 * 32];
    __shared__ u16 Ba[2][128 * 32];
    __shared__ u16 Bg[2][128 * 32];
    __shared__ float2 red1[128][4];
    const int t    = threadIdx.x;
    const int lane = t & 63;
    const int wv   = t >> 6;             // 0..7
    const int wm   = wv >> 2, wn = wv & 3;
    const int lm   = lane & 15, lq = lane >> 4;
    const int sw   = (lq ^ ((lm >> 1) & 3)) * 8;   // B-side read swizzle
    const int m0   = blockIdx.x * 128, n0 = blockIdx.y * 128;
    const int b    = m0 >> 11;
    const int l0   = m0 & 2047;
    floatx4 accA[4][2] = {};
    floatx4 accG[4][2] = {};

    // A-side read swizzle per i (row>>3 bits reduce to lane bits)
    int swA[4];
    #pragma unroll
    for (int i = 0; i < 4; ++i)
        swA[i] = (lq ^ ((i * 2 + (lm >> 3)) & 3)) * 8;

    // prologue: issue tiles 0 and 1 (6 VMEM ops), publish As[0]
    uint4 avA = ldA_yt(YT, b, l0, 0);        // tile 0
    stage_tile_512(Wo, Ba[0], n0, 0);
    stage_tile_512(Wo, Bg[0], 512 + n0, 0);
    uint4 avB = ldA_yt(YT, b, l0, 32);       // tile 1
    stage_tile_512(Wo, Ba[1], n0, 32);
    stage_tile_512(Wo, Bg[1], 512 + n0, 32);
    dswA(As[0], avA);                         // compiler waits avA's load

    #pragma unroll 1
    for (int it = 0; it < 15; ++it) {
        // top: tile it's Ba/Bg complete (3 newest = tile it+1's stay in
        // flight); lgkmcnt(0) covers prologue/previous dswA publication.
        asm volatile("s_waitcnt vmcnt(3) lgkmcnt(0)" ::: "memory");
        __builtin_amdgcn_s_barrier();
        __builtin_amdgcn_sched_barrier(0);
        const int cur = it & 1, nx = cur ^ 1;
        // publish A-tile (it+1) into the freed buffer (reads of As[nx]
        // finished before bottom barrier of it-1)
        dswA(As[nx], (it & 1) ? avA : avB);
        // issue A reg-load for tile it+2
        if (it < 14) {
            uint4 tmp = ldA_yt(YT, b, l0, (it + 2) * 32);
            if (it & 1) avB = tmp; else avA = tmp;
        }
        // MFMA on tile it
        bf16x8 af[4], ba[2], bg[2];
        #pragma unroll
        for (int i = 0; i < 4; ++i)
            af[i] = *(const bf16x8*)&As[cur][(wm * 64 + i * 16 + lm) * 32 + swA[i]];
        #pragma unroll
        for (int j = 0; j < 2; ++j) {
            ba[j] = *(const bf16x8*)&Ba[cur][(wn * 32 + j * 16 + lm) * 32 + sw];
            bg[j] = *(const bf16x8*)&Bg[cur][(wn * 32 + j * 16 + lm) * 32 + sw];
        }
        #pragma unroll
        for (int i = 0; i < 4; ++i) {
            #pragma unroll
            for (int j = 0; j < 2; ++j) {
                accA[i][j] = __builtin_amdgcn_mfma_f32_16x16x32_bf16(af[i], ba[j], accA[i][j], 0, 0, 0);
                accG[i][j] = __builtin_amdgcn_mfma_f32_16x16x32_bf16(af[i], bg[j], accG[i][j], 0, 0, 0);
            }
        }
        // bottom: ds_writes drained + all waves done reading buf[cur]
        asm volatile("s_waitcnt lgkmcnt(0)" ::: "memory");
        __builtin_amdgcn_s_barrier();
        __builtin_amdgcn_sched_barrier(0);
        // issue B loads for tile it+2 into the freed buffer
        if (it < 14) {
            stage_tile_512(Wo, Ba[cur], n0, (it + 2) * 32);
            stage_tile_512(Wo, Bg[cur], 512 + n0, (it + 2) * 32);
        }
    }
    // peeled tile 15 (in buf[1]); full drain
    asm volatile("s_waitcnt vmcnt(0) lgkmcnt(0)" ::: "memory");
    __builtin_amdgcn_s_barrier();
    __builtin_amdgcn_sched_barrier(0);
    {
        bf16x8 af[4], ba[2], bg[2];
        #pragma unroll
        for (int i = 0; i < 4; ++i)
            af[i] = *(const bf16x8*)&As[1][(wm * 64 + i * 16 + lm) * 32 + swA[i]];
        #pragma unroll
        for (int j = 0; j < 2; ++j) {
            ba[j] = *(const bf16x8*)&Ba[1][(wn * 32 + j * 16 + lm) * 32 + sw];
            bg[j] = *(const bf16x8*)&Bg[1][(wn * 32 + j * 16 + lm) * 32 + sw];
        }
        #pragma unroll
        for (int i = 0; i < 4; ++i) {
            #pragma unroll
            for (int j = 0; j < 2; ++j) {
                accA[i][j] = __builtin_amdgcn_mfma_f32_16x16x32_bf16(af[i], ba[j], accA[i][j], 0, 0, 0);
                accG[i][j] = __builtin_amdgcn_mfma_f32_16x16x32_bf16(af[i], bg[j], accG[i][j], 0, 0, 0);
            }
        }
    }

    // epilogue: GLU + residual, accumulate LN1 row partials
    float bav[2], bgv[2];
    #pragma unroll
    for (int j = 0; j < 2; ++j) {
        int n = n0 + wn * 32 + j * 16 + lm;
        bav[j] = bo[n]; bgv[j] = bo[512 + n];
    }
    #pragma unroll
    for (int i = 0; i < 4; ++i) {
        #pragma unroll
        for (int r = 0; r < 4; ++r) {
            int row = wm * 64 + i * 16 + lq * 4 + r;
            int m = m0 + row;
            float s = 0.0f, sq = 0.0f;
            #pragma unroll
            for (int j = 0; j < 2; ++j) {
                int n = n0 + wn * 32 + j * 16 + lm;
                float a_ = accA[i][j][r] + bav[j];
                float g_ = accG[i][j][r] + bgv[j];
                float xv = x[(size_t)m * 512 + n];
                float ov = fmaf(a_, sigmoidf_(g_), xv);
                out[(size_t)m * 512 + n] = f2b(ov);
                s += ov; sq = fmaf(ov, ov, sq);
            }
            #pragma unroll
            for (int msk = 1; msk < 16; msk <<= 1) {
                s  += __shfl_xor(s, msk, 64);
                sq += __shfl_xor(sq, msk, 64);
            }
            if (lm == 0) { float2 p; p.x = s; p.y = sq; red1[row][wn] = p; }
        }
    }
    __syncthreads();
    if (t < 128) {
        float s = 0.0f, sq = 0.0f;
        #pragma unroll
        for (int w = 0; w < 4; ++w) { float2 p = red1[t][w]; s += p.x; sq += p.y; }
        float2 o; o.x = s; o.y = sq;
        Pstats[(size_t)(m0 + t) * 4 + blockIdx.y] = o;
    }
}

// ---------------------------------------------------------------------------
// 6) GEMM (W1*g1 folded) + LN1 epilogue + ReLU.  BK=64, double-buffered with
//    COUNTED vmcnt (T4): tile k+2 issued at end of iter k, waited at top of
//    iter k+2 -> ~1.5 iterations of latency cover (vs same-iter drain).
//    Raw s_barrier pair per iter; sched_barrier(0) pins ds_reads (rule 18).
// ---------------------------------------------------------------------------
__global__ __launch_bounds__(512, 4) void gemm_relu_kernel(
    const u16* __restrict__ A, const u16* __restrict__ Bw,
    const float* __restrict__ bias, const float2* __restrict__ Pstats,
    const float* __restrict__ c1, const float* __restrict__ c2,
    u16* __restrict__ C)
{
    __shared__ u16 As[2][128 * 64];
    __shared__ u16 Bs[2][128 * 64];
    __shared__ float musig[128][2];
    const int t    = threadIdx.x;
    const int lane = t & 63;
    const int wv   = t >> 6;
    const int wm   = wv >> 2, wn = wv & 3;
    const int lm   = lane & 15, lq = lane >> 4;
    const int kc0  = (lq ^ (lm & 7)) * 8;          // ks=0 swizzled chunk col
    const int kc1  = ((4 + lq) ^ (lm & 7)) * 8;    // ks=1
    const int m0   = blockIdx.x * 128, n0 = blockIdx.y * 128;
    floatx4 acc[4][2] = {};

    if (t < 128) {
        float s = 0.0f, sq = 0.0f;
        #pragma unroll
        for (int w = 0; w < 4; ++w) {
            float2 p = Pstats[(size_t)(m0 + t) * 4 + w];
            s += p.x; sq += p.y;
        }
        float mu  = s * (1.0f / 512.0f);
        float var = sq * (1.0f / 512.0f) - mu * mu;
        musig[t][0] = mu;
        musig[t][1] = rsqrtf(var + 1e-5f);
    }
    // drain musig's vector loads so the staged-load vmcnt accounting is exact
    asm volatile("s_waitcnt vmcnt(0)" ::: "memory");

    // prologue: tiles k0, k1 in flight (8 loads/thread outstanding)
    stage_tile64_512(A,  As[0], m0, 0);
    stage_tile64_512(Bw, Bs[0], n0, 0);
    stage_tile64_512(A,  As[1], m0, 64);
    stage_tile64_512(Bw, Bs[1], n0, 64);

    #pragma unroll 1
    for (int it = 0; it < 7; ++it) {
        // wait for THIS tile's 4 loads (next tile's 4 stay in flight)
        asm volatile("s_waitcnt vmcnt(4)" ::: "memory");
        __builtin_amdgcn_s_barrier();
        __builtin_amdgcn_sched_barrier(0);
        const int cur = it & 1;
        #pragma unroll
        for (int ks = 0; ks < 2; ++ks) {
            const int kc = ks ? kc1 : kc0;
            bf16x8 af[4], bfr[2];
            #pragma unroll
            for (int i = 0; i < 4; ++i)
                af[i] = *(const bf16x8*)&As[cur][(wm * 64 + i * 16 + lm) * 64 + kc];
            #pragma unroll
            for (int j = 0; j < 2; ++j)
                bfr[j] = *(const bf16x8*)&Bs[cur][(wn * 32 + j * 16 + lm) * 64 + kc];
            #pragma unroll
            for (int i = 0; i < 4; ++i) {
                #pragma unroll
                for (int j = 0; j < 2; ++j)
                    acc[i][j] = __builtin_amdgcn_mfma_f32_16x16x32_bf16(af[i], bfr[j], acc[i][j], 0, 0, 0);
            }
        }
        // all waves done reading buf[cur] (MFMAs consumed every ds_read)
        __builtin_amdgcn_s_barrier();
        __builtin_amdgcn_sched_barrier(0);
        if (it < 6) {
            stage_tile64_512(A,  As[cur], m0, (it + 2) * 64);
            stage_tile64_512(Bw, Bs[cur], n0, (it + 2) * 64);
        }
    }
    // peeled final tile (k7 in buf[1]); full drain
    asm volatile("s_waitcnt vmcnt(0)" ::: "memory");
    __builtin_amdgcn_s_barrier();
    __builtin_amdgcn_sched_barrier(0);
    #pragma unroll
    for (int ks = 0; ks < 2; ++ks) {
        const int kc = ks ? kc1 : kc0;
        bf16x8 af[4], bfr[2];
        #pragma unroll
        for (int i = 0; i < 4; ++i)
            af[i] = *(const bf16x8*)&As[1][(wm * 64 + i * 16 + lm) * 64 + kc];
        #pragma unroll
        for (int j = 0; j < 2; ++j)
            bfr[j] = *(const bf16x8*)&Bs[1][(wn * 32 + j * 16 + lm) * 64 + kc];
        #pragma unroll
        for (int i = 0; i < 4; ++i) {
            #pragma unroll
            for (int j = 0; j < 2; ++j)
                acc[i][j] = __builtin_amdgcn_mfma_f32_16x16x32_bf16(af[i], bfr[j], acc[i][j], 0, 0, 0);
        }
    }
    float c1v[2], c2v[2];
    #pragma unroll
    for (int j = 0; j < 2; ++j) {
        int n = n0 + wn * 32 + j * 16 + lm;
        c1v[j] = c1[n];
        c2v[j] = c2[n] + bias[n];
    }
    #pragma unroll
    for (int i = 0; i < 4; ++i) {
        #pragma unroll
        for (int r = 0; r < 4; ++r) {
            int row = wm * 64 + i * 16 + lq * 4 + r;
            float mu = musig[row][0], rs = musig[row][1];
            float nmr = -rs * mu;
            #pragma unroll
            for (int j = 0; j < 2; ++j) {
                int n = n0 + wn * 32 + j * 16 + lm;
                float v = fmaf(rs, acc[i][j][r], fmaf(nmr, c1v[j], c2v[j]));
                C[(size_t)(m0 + row) * 512 + n] = f2b(fmaxf(v, 0.0f));
            }
        }
    }
}

// ---------------------------------------------------------------------------
// 7) GEMM2 (128x128 tile) + LN1'd residual epilogue.  BK=64, counted-vmcnt
//    pipeline identical to gemm_relu.  Writes z bf16 + LN2 row-partials.
// ---------------------------------------------------------------------------
__global__ __launch_bounds__(512, 4) void gemm2_tile_kernel(
    const u16* __restrict__ A, const u16* __restrict__ Bw,
    const float* __restrict__ bias, const u16* __restrict__ res,
    const float2* __restrict__ Pstats,
    const float* __restrict__ g1, const float* __restrict__ beta1,
    u16* __restrict__ Z, float2* __restrict__ Pstats2)
{
    __shared__ u16 As[2][128 * 64];
    __shared__ u16 Bs[2][128 * 64];
    __shared__ float musig[128][2];
    __shared__ float2 red2[128][4];
    const int t    = threadIdx.x;
    const int lane = t & 63;
    const int wv   = t >> 6;
    const int wm   = wv >> 2, wn = wv & 3;
    const int lm   = lane & 15, lq = lane >> 4;
    const int kc0  = (lq ^ (lm & 7)) * 8;
    const int kc1  = ((4 + lq) ^ (lm & 7)) * 8;
    const int m0   = blockIdx.x * 128, n0 = blockIdx.y * 128;
    floatx4 acc[4][2] = {};

    if (t < 128) {
        float s = 0.0f, sq = 0.0f;
        #pragma unroll
        for (int w = 0; w < 4; ++w) {
            float2 p = Pstats[(size_t)(m0 + t) * 4 + w];
            s += p.x; sq += p.y;
        }
        float mu  = s * (1.0f / 512.0f);
        float var = sq * (1.0f / 512.0f) - mu * mu;
        musig[t][0] = mu;
        musig[t][1] = rsqrtf(var + 1e-5f);
    }
    asm volatile("s_waitcnt vmcnt(0)" ::: "memory");

    stage_tile64_512(A,  As[0], m0, 0);
    stage_tile64_512(Bw, Bs[0], n0, 0);
    stage_tile64_512(A,  As[1], m0, 64);
    stage_tile64_512(Bw, Bs[1], n0, 64);

    #pragma unroll 1
    for (int it = 0; it < 7; ++it) {
        asm volatile("s_waitcnt vmcnt(4)" ::: "memory");
        __builtin_amdgcn_s_barrier();
        __builtin_amdgcn_sched_barrier(0);
        const int cur = it & 1;
        #pragma unroll
        for (int ks = 0; ks < 2; ++ks) {
            const int kc = ks ? kc1 : kc0;
            bf16x8 af[4], bfr[2];
            #pragma unroll
            for (int i = 0; i < 4; ++i)
                af[i] = *(const bf16x8*)&As[cur][(wm * 64 + i * 16 + lm) * 64 + kc];
            #pragma unroll
            for (int j = 0; j < 2; ++j)
                bfr[j] = *(const bf16x8*)&Bs[cur][(wn * 32 + j * 16 + lm) * 64 + kc];
            #pragma unroll
            for (int i = 0; i < 4; ++i) {
                #pragma unroll
                for (int j = 0; j < 2; ++j)
                    acc[i][j] = __builtin_amdgcn_mfma_f32_16x16x32_bf16(af[i], bfr[j], acc[i][j], 0, 0, 0);
            }
        }
        __builtin_amdgcn_s_barrier();
        __builtin_amdgcn_sched_barrier(0);
        if (it < 6) {
            stage_tile64_512(A,  As[cur], m0, (it + 2) * 64);
            stage_tile64_512(Bw, Bs[cur], n0, (it + 2) * 64);
        }
    }
    asm volatile("s_waitcnt vmcnt(0)" ::: "memory");
    __builtin_amdgcn_s_barrier();
    __builtin_amdgcn_sched_barrier(0);
    #pragma unroll
    for (int ks = 0; ks < 2; ++ks) {
        const int kc = ks ? kc1 : kc0;
        bf16x8 af[4], bfr[2];
        #pragma unroll
        for (int i = 0; i < 4; ++i)
            af[i] = *(const bf16x8*)&As[1][(wm * 64 + i * 16 + lm) * 64 + kc];
        #pragma unroll
        for (int j = 0; j < 2; ++j)
            bfr[j] = *(const bf16x8*)&Bs[1][(wn * 32 + j * 16 + lm) * 64 + kc];
        #pragma unroll
        for (int i = 0; i < 4; ++i) {
            #pragma unroll
            for (int j = 0; j < 2; ++j)
                acc[i][j] = __builtin_amdgcn_mfma_f32_16x16x32_bf16(af[i], bfr[j], acc[i][j], 0, 0, 0);
        }
    }

    // epilogue: z = acc + bias + LN1(res); write z bf16; LN2 row partials
    float bv[2], gv1[2], bt1[2];
    #pragma unroll
    for (int j = 0; j < 2; ++j) {
        int n = n0 + wn * 32 + j * 16 + lm;
        bv[j]  = bias[n];
        gv1[j] = g1[n];
        bt1[j] = beta1[n];
    }
    #pragma unroll
    for (int i = 0; i < 4; ++i) {
        #pragma unroll
        for (int r = 0; r < 4; ++r) {
            int row = wm * 64 + i * 16 + lq * 4 + r;
            int m = m0 + row;
            float mu1 = musig[row][0], rs1 = musig[row][1];
            float s = 0.0f, sq = 0.0f;
            #pragma unroll
            for (int j = 0; j < 2; ++j) {
                int n = n0 + wn * 32 + j * 16 + lm;
                float zl = fmaf((b2f(res[(size_t)m * 512 + n]) - mu1) * rs1, gv1[j], bt1[j]);
                float v = acc[i][j][r] + bv[j] + zl;
                Z[(size_t)m * 512 + n] = f2b(v);
                s += v; sq = fmaf(v, v, sq);
            }
            #pragma unroll
            for (int msk = 1; msk < 16; msk <<= 1) {
                s  += __shfl_xor(s, msk, 64);
                sq += __shfl_xor(sq, msk, 64);
            }
            if (lm == 0) { float2 p; p.x = s; p.y = sq; red2[row][wn] = p; }
        }
    }
    __syncthreads();
    if (t < 128) {
        float s = 0.0f, sq = 0.0f;
        #pragma unroll
        for (int w = 0; w < 4; ++w) { float2 p = red2[t][w]; s += p.x; sq += p.y; }
        float2 o; o.x = s; o.y = sq;
        Pstats2[(size_t)(m0 + t) * 4 + blockIdx.y] = o;
    }
}

// ---------------------------------------------------------------------------
// 8) LN2 finish: out = (z - mu)*rs*g2 + b2, fp32. Memory-bound streaming.
// ---------------------------------------------------------------------------
__global__ __launch_bounds__(256) void ln2_finish_kernel(
    const u16* __restrict__ Z, const float2* __restrict__ Pstats2,
    const float* __restrict__ gamma, const float* __restrict__ beta,
    float* __restrict__ out)
{
    int w    = threadIdx.x >> 6;
    int lane = threadIdx.x & 63;
    size_t row  = (size_t)blockIdx.x * 4 + w;
    float s = 0.0f, sq = 0.0f;
    #pragma unroll
    for (int w4 = 0; w4 < 4; ++w4) {
        float2 p = Pstats2[row * 4 + w4];
        s += p.x; sq += p.y;
    }
    float mu  = s * (1.0f / 512.0f);
    float var = sq * (1.0f / 512.0f) - mu * mu;
    float rs  = rsqrtf(var + 1e-5f);
    size_t base = row * 512 + lane * 8;
    uint4 raw = *(const uint4*)(Z + base);
    float v[8];
    unpack2(raw.x, v[0], v[1]); unpack2(raw.y, v[2], v[3]);
    unpack2(raw.z, v[4], v[5]); unpack2(raw.w, v[6], v[7]);
    float g[8], bt[8];
    *(float4*)&g[0]  = *(const float4*)(gamma + lane * 8);
    *(float4*)&g[4]  = *(const float4*)(gamma + lane * 8 + 4);
    *(float4*)&bt[0] = *(const float4*)(beta + lane * 8);
    *(float4*)&bt[4] = *(const float4*)(beta + lane * 8 + 4);
    float o[8];
    #pragma unroll
    for (int i = 0; i < 8; ++i)
        o[i] = fmaf((v[i] - mu) * rs, g[i], bt[i]);
    *(float4*)(out + base)     = *(float4*)&o[0];
    *(float4*)(out + base + 4) = *(float4*)&o[4];
}

// ---------------------------------------------------------------------------
extern "C" void kernel_launch(void* const* d_in, const int* in_sizes, int n_in,
                              void* d_out, int out_size, void* d_ws, size_t ws_size,
                              hipStream_t stream)
{
    (void)in_sizes; (void)n_in; (void)out_size; (void)ws_size;
    const float* x      = (const float*)d_in[0];
    const float* log_dt = (const float*)d_in[1];
    const float* A_re   = (const float*)d_in[2];
    const float* A_im   = (const float*)d_in[3];
    const float* C_re   = (const float*)d_in[4];
    const float* C_im   = (const float*)d_in[5];
    const float* D_skip = (const float*)d_in[6];
    const float* W_out  = (const float*)d_in[7];
    const float* b_out  = (const float*)d_in[8];
    const float* g1     = (const float*)d_in[9];
    const float* beta1  = (const float*)d_in[10];
    const float* g2     = (const float*)d_in[11];
    const float* beta2  = (const float*)d_in[12];
    const float* W1     = (const float*)d_in[13];
    const float* bc1    = (const float*)d_in[14];
    const float* W2     = (const float*)d_in[15];
    const float* bc2    = (const float*)d_in[16];
    float* out = (float*)d_out;

    // workspace: P 512K | hole | Toep 4M | weights 2M | r1/r2/r3 | Pstats | c1 c2 | Pstats2
    char*   wsb    = (char*)d_ws;
    float*  P      = (float*)wsb;
    u16*    Toep   = (u16*)(wsb + 4 * HN * 4 + 512 * 64 * 4);
    u16*    Wobf   = Toep + 512 * 4096;
    u16*    W1bf   = Wobf + 1024 * 512;
    u16*    W2bf   = W1bf + 512 * 512;
    u16*    r1     = W2bf + 512 * 512;   // XT -> h1_bf
    u16*    r2     = r1 + BLH;           // YT -> z2_bf
    u16*    r3     = r2 + BLH;           // x1pre_bf
    float2* Pstats = (float2*)(r3 + BLH);
    float*  c1     = (float*)(Pstats + (size_t)M_DIM * 4);
    float*  c2     = c1 + 512;
    float2* Pstats2 = (float2*)(c2 + 512);

    setup_kernel<<<9472, 256, 0, stream>>>(x, W_out, W1, W2, log_dt, A_re, A_im,
                                           C_re, C_im, g1, beta1,
                                           r1, Wobf, W1bf, W2bf, P, Toep, c1, c2);
    ssm_chunk_kernel<<<dim3(H_DIM, 2), 512, 0, stream>>>(r1, P, Toep, D_skip, r2);
    gemm1_glu_kernel<<<dim3(M_DIM / 128, 4), 512, 0, stream>>>(r2, Wobf, b_out, x, r3, Pstats);
    gemm_relu_kernel<<<dim3(M_DIM / 128, 4), 512, 0, stream>>>(r3, W1bf, bc1, Pstats, c1, c2, r1);
    gemm2_tile_kernel<<<dim3(M_DIM / 128, 4), 512, 0, stream>>>(r1, W2bf, bc2, r3, Pstats, g1, beta1, r2, Pstats2);
    ln2_finish_kernel<<<M_DIM / 4, 256, 0, stream>>>(r2, Pstats2, g2, beta2, out);
}